// Round 7
// baseline (596.775 us; speedup 1.0000x reference)
//
#include <hip/hip_runtime.h>
#include <hip/hip_bf16.h>
#include <math.h>

#define D_ 128
#define INV_SQRT_D 0.08838834764831845f
#define SCAN_CH 16
#define SCAN_TILE (256 * SCAN_CH)

typedef __bf16 bf16x8 __attribute__((ext_vector_type(8)));
typedef float f32x4 __attribute__((ext_vector_type(4)));

struct W4p { const float* p[4]; };

__device__ __forceinline__ void unpack8(bf16x8 v, float* f) {
    const uint32_t* u = (const uint32_t*)&v;
#pragma unroll
    for (int i = 0; i < 4; i++) {
        uint32_t w = u[i];
        f[2 * i]     = __uint_as_float(w << 16);
        f[2 * i + 1] = __uint_as_float(w & 0xffff0000u);
    }
}

__device__ __forceinline__ bf16x8 pack8(const float* f, float s) {
    bf16x8 r;
#pragma unroll
    for (int j = 0; j < 8; j++) r[j] = (__bf16)(f[j] * s);
    return r;
}

// ---------------- casts ----------------
__global__ __launch_bounds__(256) void cvt_weights4(W4p w, __bf16* __restrict__ out) {
    int idx = blockIdx.x * 256 + threadIdx.x;
    if (idx >= 4 * 16384) return;
    out[idx] = (__bf16)w.p[idx >> 14][idx & 16383];
}

__global__ __launch_bounds__(256) void cvt2(const float* __restrict__ a, const float* __restrict__ b,
                                            __bf16* __restrict__ oa, __bf16* __restrict__ ob, int n) {
    int idx = blockIdx.x * 256 + threadIdx.x;
    if (idx < n) { oa[idx] = (__bf16)a[idx]; ob[idx] = (__bf16)b[idx]; }
}

// cast u_emb and i_emb to bf16, 4 elems/thread
__global__ __launch_bounds__(256) void cvt_emb(const float* __restrict__ u, const float* __restrict__ i,
                                               __bf16* __restrict__ ub, __bf16* __restrict__ ib,
                                               size_t nue, size_t nie) {
    size_t idx4 = ((size_t)blockIdx.x * 256 + threadIdx.x) * 4;
    if (idx4 < nue) {
        float4 v = *(const float4*)(u + idx4);
        ub[idx4] = (__bf16)v.x; ub[idx4+1] = (__bf16)v.y; ub[idx4+2] = (__bf16)v.z; ub[idx4+3] = (__bf16)v.w;
    } else if (idx4 < nue + nie) {
        size_t j = idx4 - nue;
        float4 v = *(const float4*)(i + j);
        ib[j] = (__bf16)v.x; ib[j+1] = (__bf16)v.y; ib[j+2] = (__bf16)v.z; ib[j+3] = (__bf16)v.w;
    }
}

// ---------------- combined-matrix prep ----------------
// blocks 0..127: M{2,3,4}t[a][t] = sum_k W1[k][a]*W{2,3,4}[k][t]  (xINV_SQRT_D)
// blocks 128..: pVW2[r][t] = sum_a pV[r][a]*W2[a][t]; pKW1[r][t] = sum_a pK[r][a]*W1[a][t] (xINV_SQRT_D)
__global__ __launch_bounds__(128) void prep_mats(const float* __restrict__ W1, const float* __restrict__ W2,
                                                 const float* __restrict__ W3, const float* __restrict__ W4,
                                                 const float* __restrict__ pV, const float* __restrict__ pK,
                                                 __bf16* __restrict__ M2t, __bf16* __restrict__ M3t,
                                                 __bf16* __restrict__ M4t,
                                                 __bf16* __restrict__ pVW2, __bf16* __restrict__ pKW1,
                                                 int umax, int imax) {
    __shared__ float sh[256];
    int b = blockIdx.x, t = threadIdx.x;
    if (b < 128) {
        sh[t] = W1[t * 128 + b];
        __syncthreads();
        float m2 = 0.f, m3 = 0.f, m4 = 0.f;
        for (int k = 0; k < 128; k++) {
            float w = sh[k];
            m2 = fmaf(w, W2[k * 128 + t], m2);
            m3 = fmaf(w, W3[k * 128 + t], m3);
            m4 = fmaf(w, W4[k * 128 + t], m4);
        }
        M2t[b * 128 + t] = (__bf16)(m2 * INV_SQRT_D);
        M3t[b * 128 + t] = (__bf16)(m3 * INV_SQRT_D);
        M4t[b * 128 + t] = (__bf16)(m4 * INV_SQRT_D);
    } else {
        int r = b - 128;
        if (r < umax) sh[t] = pV[r * 128 + t];
        if (r < imax) sh[128 + t] = pK[r * 128 + t];
        __syncthreads();
        float q = 0.f, qk = 0.f;
        for (int a = 0; a < 128; a++) {
            if (r < umax) q  = fmaf(sh[a], W2[a * 128 + t], q);
            if (r < imax) qk = fmaf(sh[128 + a], W1[a * 128 + t], qk);
        }
        if (r < umax) pVW2[r * 128 + t] = (__bf16)(q * INV_SQRT_D);
        if (r < imax) pKW1[r * 128 + t] = (__bf16)(qk * INV_SQRT_D);
    }
}

// ---------------- user transformed vectors: um_t = u@M2t^T, li_t = lit[g]@M3t^T, lu_t = lut[g]@M4t^T ----------------
__global__ __launch_bounds__(256) void user_vecs(const float* __restrict__ u_emb,
                                                 const float* __restrict__ lit_tab, const int* __restrict__ g_li,
                                                 const float* __restrict__ lut_tab, const int* __restrict__ g_lu,
                                                 const __bf16* __restrict__ M2t, const __bf16* __restrict__ M3t,
                                                 const __bf16* __restrict__ M4t,
                                                 __bf16* __restrict__ um_t, __bf16* __restrict__ li_t,
                                                 __bf16* __restrict__ lu_t, int rows) {
    int lane = threadIdx.x & 63;
    int wave = threadIdx.x >> 6;
    int row0 = blockIdx.x * 64 + wave * 16;
    if (row0 >= rows) return;
    int l16 = lane & 15, kh = lane >> 4;
    int ar = row0 + l16;
    int arc = ar < rows ? ar : rows - 1;
    const float* rA = u_emb + (size_t)arc * D_;
    const float* rB = lit_tab + (size_t)g_li[arc] * D_;
    const float* rC = lut_tab + (size_t)g_lu[arc] * D_;

    f32x4 aA[8] = {}, aB[8] = {}, aC[8] = {};
#pragma unroll
    for (int k0 = 0; k0 < D_; k0 += 32) {
        int kk = k0 + kh * 8;
        float4 a0 = *(const float4*)(rA + kk), a1 = *(const float4*)(rA + kk + 4);
        float4 b0 = *(const float4*)(rB + kk), b1 = *(const float4*)(rB + kk + 4);
        float4 c0 = *(const float4*)(rC + kk), c1 = *(const float4*)(rC + kk + 4);
        bf16x8 fA, fB, fC;
        fA[0]=(__bf16)a0.x; fA[1]=(__bf16)a0.y; fA[2]=(__bf16)a0.z; fA[3]=(__bf16)a0.w;
        fA[4]=(__bf16)a1.x; fA[5]=(__bf16)a1.y; fA[6]=(__bf16)a1.z; fA[7]=(__bf16)a1.w;
        fB[0]=(__bf16)b0.x; fB[1]=(__bf16)b0.y; fB[2]=(__bf16)b0.z; fB[3]=(__bf16)b0.w;
        fB[4]=(__bf16)b1.x; fB[5]=(__bf16)b1.y; fB[6]=(__bf16)b1.z; fB[7]=(__bf16)b1.w;
        fC[0]=(__bf16)c0.x; fC[1]=(__bf16)c0.y; fC[2]=(__bf16)c0.z; fC[3]=(__bf16)c0.w;
        fC[4]=(__bf16)c1.x; fC[5]=(__bf16)c1.y; fC[6]=(__bf16)c1.z; fC[7]=(__bf16)c1.w;
#pragma unroll
        for (int cb = 0; cb < 8; cb++) {
            bf16x8 w2 = *(const bf16x8*)(M2t + (size_t)(cb * 16 + l16) * D_ + kk);
            aA[cb] = __builtin_amdgcn_mfma_f32_16x16x32_bf16(fA, w2, aA[cb], 0, 0, 0);
            bf16x8 w3 = *(const bf16x8*)(M3t + (size_t)(cb * 16 + l16) * D_ + kk);
            aB[cb] = __builtin_amdgcn_mfma_f32_16x16x32_bf16(fB, w3, aB[cb], 0, 0, 0);
            bf16x8 w4 = *(const bf16x8*)(M4t + (size_t)(cb * 16 + l16) * D_ + kk);
            aC[cb] = __builtin_amdgcn_mfma_f32_16x16x32_bf16(fC, w4, aC[cb], 0, 0, 0);
        }
    }
#pragma unroll
    for (int cb = 0; cb < 8; cb++) {
#pragma unroll
        for (int j = 0; j < 4; j++) {
            int r = row0 + kh * 4 + j;
            if (r < rows) {
                um_t[(size_t)r * D_ + cb * 16 + l16] = (__bf16)aA[cb][j];
                li_t[(size_t)r * D_ + cb * 16 + l16] = (__bf16)aB[cb][j];
                lu_t[(size_t)r * D_ + cb * 16 + l16] = (__bf16)aC[cb][j];
            }
        }
    }
}

// ---------------- small GEMM: Y(rows x ncols f32) = Xb @ P^T (scale prefolded in P) ----------------
__global__ __launch_bounds__(256) void gemm_pvk(const __bf16* __restrict__ Xb,
                                                const __bf16* __restrict__ Pb,
                                                float* __restrict__ Y, int rows, int ncols) {
    int lane = threadIdx.x & 63;
    int wave = threadIdx.x >> 6;
    int row0 = blockIdx.x * 64 + wave * 16;
    if (row0 >= rows) return;
    int l16 = lane & 15, kh = lane >> 4;
    int ar = row0 + l16;
    int arc = ar < rows ? ar : rows - 1;
    const __bf16* arow = Xb + (size_t)arc * D_;

    f32x4 acc[4] = {};
#pragma unroll
    for (int k0 = 0; k0 < D_; k0 += 32) {
        int kk = k0 + kh * 8;
        bf16x8 af = *(const bf16x8*)(arow + kk);
#pragma unroll
        for (int cb = 0; cb < 4; cb++) {
            int br = cb * 16 + l16;
            if (br >= ncols) br = ncols - 1;
            bf16x8 bf = *(const bf16x8*)(Pb + (size_t)br * D_ + kk);
            acc[cb] = __builtin_amdgcn_mfma_f32_16x16x32_bf16(af, bf, acc[cb], 0, 0, 0);
        }
    }
#pragma unroll
    for (int cb = 0; cb < 4; cb++) {
        int col = cb * 16 + l16;
        if (col >= ncols) continue;
#pragma unroll
        for (int j = 0; j < 4; j++) {
            int r = row0 + kh * 4 + j;
            if (r < rows) Y[(size_t)r * ncols + col] = acc[cb][j];
        }
    }
}

// ---------------- CSR build ----------------
__global__ __launch_bounds__(256) void hist2(const int* __restrict__ eu, const int* __restrict__ ei,
                                             int* __restrict__ cnt_all, int nu, int E) {
    int e = blockIdx.x * 256 + threadIdx.x;
    if (e < E) {
        atomicAdd(&cnt_all[eu[e]], 1);
        atomicAdd(&cnt_all[nu + ei[e]], 1);
    }
}

__global__ __launch_bounds__(256) void scan_phaseA(const int* __restrict__ cnt, int* __restrict__ part, int n) {
    __shared__ int wsum[4];
    int t = threadIdx.x, lane = t & 63, w = t >> 6;
    int i0 = blockIdx.x * SCAN_TILE + t * SCAN_CH;
    int tot = 0;
#pragma unroll
    for (int j = 0; j < SCAN_CH; j++) tot += (i0 + j < n) ? cnt[i0 + j] : 0;
#pragma unroll
    for (int d = 32; d; d >>= 1) tot += __shfl_xor(tot, d);
    if (lane == 0) wsum[w] = tot;
    __syncthreads();
    if (t == 0) part[blockIdx.x] = wsum[0] + wsum[1] + wsum[2] + wsum[3];
}

__global__ __launch_bounds__(1024) void scan_phaseB(int* __restrict__ part, int nb,
                                                    int* __restrict__ off, int n) {
    __shared__ int wsum[16];
    int t = threadIdx.x, lane = t & 63, w = t >> 6;
    int v = (t < nb) ? part[t] : 0;
    int x = v;
#pragma unroll
    for (int d = 1; d < 64; d <<= 1) {
        int y = __shfl_up(x, d);
        if (lane >= d) x += y;
    }
    if (lane == 63) wsum[w] = x;
    __syncthreads();
    int wbase = 0;
    for (int ww = 0; ww < w; ww++) wbase += wsum[ww];
    if (t < nb) part[t] = wbase + x - v;
    if (t == 1023) off[n] = wbase + x;
}

__global__ __launch_bounds__(256) void scan_phaseC(const int* __restrict__ cnt, const int* __restrict__ part,
                                                   int* __restrict__ off, int* __restrict__ pos, int n) {
    __shared__ int wsum[4];
    int t = threadIdx.x, lane = t & 63, w = t >> 6;
    int i0 = blockIdx.x * SCAN_TILE + t * SCAN_CH;
    int loc[SCAN_CH];
    int tot = 0;
#pragma unroll
    for (int j = 0; j < SCAN_CH; j++) {
        int v = (i0 + j < n) ? cnt[i0 + j] : 0;
        loc[j] = tot; tot += v;
    }
    int x = tot;
#pragma unroll
    for (int d = 1; d < 64; d <<= 1) {
        int y = __shfl_up(x, d);
        if (lane >= d) x += y;
    }
    if (lane == 63) wsum[w] = x;
    __syncthreads();
    int wbase = 0;
    for (int ww = 0; ww < w; ww++) wbase += wsum[ww];
    int excl = part[blockIdx.x] + wbase + x - tot;
#pragma unroll
    for (int j = 0; j < SCAN_CH; j++) {
        if (i0 + j < n) { off[i0 + j] = excl + loc[j]; pos[i0 + j] = excl + loc[j]; }
    }
}

__global__ __launch_bounds__(256) void scatter2(const int* __restrict__ eu, const int* __restrict__ ei,
                                                const int* __restrict__ rui, const int* __restrict__ riu,
                                                int* __restrict__ pos_all, int4* __restrict__ recs,
                                                int nu, int E) {
    int e = blockIdx.x * 256 + threadIdx.x;
    if (e < E) {
        int u = eu[e], it = ei[e], r1 = rui[e], r2 = riu[e];
        int pi = atomicAdd(&pos_all[nu + it], 1);
        int pu = atomicAdd(&pos_all[u], 1);
        recs[pu] = make_int4(it, r1, r2, pi);
        recs[pi] = make_int4(u, r1, r2, 0);
    }
}

// ---------------- user pass: gather i_emb only; dots vs transformed regs; accumulate raw embeddings ----------------
__global__ __launch_bounds__(256) void user_pass(const int* __restrict__ off_all, const int4* __restrict__ recs,
                                                 const __bf16* __restrict__ ib_emb,
                                                 const __bf16* __restrict__ um_t,
                                                 const __bf16* __restrict__ li_t,
                                                 const __bf16* __restrict__ lu_t,
                                                 const __bf16* __restrict__ pKb,
                                                 const float* __restrict__ upv,
                                                 float2* __restrict__ mb_val,
                                                 __bf16* __restrict__ A1n, __bf16* __restrict__ PKn,
                                                 __bf16* __restrict__ A2n, int nu, int umax) {
    int u = blockIdx.x * 4 + (threadIdx.x >> 6);
    if (u >= nu) return;
    int lane = threadIdx.x & 63;
    int g = lane >> 4, l16 = lane & 15;
    int off = off_all[u], n = off_all[u + 1] - off;
    if (n == 0) {
        if (lane < 16) {
            bf16x8 z = {};
            *(bf16x8*)(A1n + (size_t)u * D_ + l16 * 8) = z;
            *(bf16x8*)(PKn + (size_t)u * D_ + l16 * 8) = z;
            *(bf16x8*)(A2n + (size_t)u * D_ + l16 * 8) = z;
        }
        return;
    }
    float um8[8], li8[8], lu8[8];
    unpack8(((const bf16x8*)(um_t + (size_t)u * D_))[l16], um8);
    unpack8(((const bf16x8*)(li_t + (size_t)u * D_))[l16], li8);
    unpack8(((const bf16x8*)(lu_t + (size_t)u * D_))[l16], lu8);
    const float* upv_row = upv + (size_t)u * umax;

    float s1 = 0.f, s2 = 0.f, a1[8] = {}, apk[8] = {}, a2[8] = {};
    for (int i = g; i < n; i += 8) {
        int4 ra = recs[off + i];
        bool hb = (i + 4) < n;
        int4 rb = recs[off + (hb ? i + 4 : i)];
        bf16x8 vieA = ((const bf16x8*)(ib_emb + (size_t)ra.x * D_))[l16];
        bf16x8 vpkA = ((const bf16x8*)(pKb + (size_t)ra.z * D_))[l16];
        bf16x8 vieB = ((const bf16x8*)(ib_emb + (size_t)rb.x * D_))[l16];
        bf16x8 vpkB = ((const bf16x8*)(pKb + (size_t)rb.z * D_))[l16];
        float fieA[8], fpkA[8], fieB[8], fpkB[8];
        unpack8(vieA, fieA); unpack8(vpkA, fpkA);
        unpack8(vieB, fieB); unpack8(vpkB, fpkB);
        float d1a = 0.f, d2a = 0.f, d3a = 0.f, d1b = 0.f, d2b = 0.f, d3b = 0.f;
#pragma unroll
        for (int j = 0; j < 8; j++) {
            d1a = fmaf(um8[j], fieA[j], d1a);
            d2a = fmaf(li8[j], fieA[j], d2a);
            d3a = fmaf(lu8[j], fieA[j], d3a);
            d1b = fmaf(um8[j], fieB[j], d1b);
            d2b = fmaf(li8[j], fieB[j], d2b);
            d3b = fmaf(lu8[j], fieB[j], d3b);
        }
#pragma unroll
        for (int d = 1; d < 16; d <<= 1) {
            d1a += __shfl_xor(d1a, d); d2a += __shfl_xor(d2a, d); d3a += __shfl_xor(d3a, d);
            d1b += __shfl_xor(d1b, d); d2b += __shfl_xor(d2b, d); d3b += __shfl_xor(d3b, d);
        }
        if (l16 == 0) {
            mb_val[ra.w] = make_float2(d1a, d3a);
            if (hb) mb_val[rb.w] = make_float2(d1b, d3b);
        }
        float w1a = __expf(d1a + upv_row[ra.y]);
        float w2a = __expf(d2a);
        float w1b = hb ? __expf(d1b + upv_row[rb.y]) : 0.f;
        float w2b = hb ? __expf(d2b) : 0.f;
        s1 += w1a + w1b; s2 += w2a + w2b;
#pragma unroll
        for (int j = 0; j < 8; j++) {
            a1[j]  = fmaf(w1a, fieA[j], fmaf(w1b, fieB[j], a1[j]));
            apk[j] = fmaf(w1a, fpkA[j], fmaf(w1b, fpkB[j], apk[j]));
            a2[j]  = fmaf(w2a, fieA[j], fmaf(w2b, fieB[j], a2[j]));
        }
    }
#pragma unroll
    for (int d = 16; d < 64; d <<= 1) {
        s1 += __shfl_xor(s1, d); s2 += __shfl_xor(s2, d);
#pragma unroll
        for (int j = 0; j < 8; j++) {
            a1[j]  += __shfl_xor(a1[j], d);
            apk[j] += __shfl_xor(apk[j], d);
            a2[j]  += __shfl_xor(a2[j], d);
        }
    }
    if (lane < 16) {
        float inv1 = 1.f / s1, inv2 = 1.f / s2;
        *(bf16x8*)(A1n + (size_t)u * D_ + l16 * 8) = pack8(a1, inv1);
        *(bf16x8*)(PKn + (size_t)u * D_ + l16 * 8) = pack8(apk, inv1);
        *(bf16x8*)(A2n + (size_t)u * D_ + l16 * 8) = pack8(a2, inv2);
    }
}

// ---------------- item pass: no dots; logits from streamed mb_val + ipk; accumulate raw u embeddings ----------------
__global__ __launch_bounds__(256) void item_pass(const int* __restrict__ off_all, const int4* __restrict__ recs,
                                                 const __bf16* __restrict__ ub_emb,
                                                 const __bf16* __restrict__ pVb,
                                                 const float* __restrict__ ipk,
                                                 const float2* __restrict__ mb_val,
                                                 __bf16* __restrict__ B1n, __bf16* __restrict__ PVn,
                                                 __bf16* __restrict__ B2n, int nu, int ni, int imax) {
    int it = blockIdx.x * 4 + (threadIdx.x >> 6);
    if (it >= ni) return;
    int lane = threadIdx.x & 63;
    int g = lane >> 4, l16 = lane & 15;
    int off = off_all[nu + it], n = off_all[nu + it + 1] - off;
    if (n == 0) {
        if (lane < 16) {
            bf16x8 z = {};
            *(bf16x8*)(B1n + (size_t)it * D_ + l16 * 8) = z;
            *(bf16x8*)(PVn + (size_t)it * D_ + l16 * 8) = z;
            *(bf16x8*)(B2n + (size_t)it * D_ + l16 * 8) = z;
        }
        return;
    }
    const float* ipk_row = ipk + (size_t)it * imax;

    float s1 = 0.f, s2 = 0.f, b1[8] = {}, bpv[8] = {}, b2[8] = {};
    for (int i = g; i < n; i += 8) {
        int4 ra = recs[off + i];
        bool hb = (i + 4) < n;
        int4 rb = recs[off + (hb ? i + 4 : i)];
        float2 ma = mb_val[off + i];
        float2 mbv = hb ? mb_val[off + i + 4] : make_float2(0.f, 0.f);
        bf16x8 vueA = ((const bf16x8*)(ub_emb + (size_t)ra.x * D_))[l16];
        bf16x8 vpvA = ((const bf16x8*)(pVb + (size_t)ra.y * D_))[l16];
        bf16x8 vueB = ((const bf16x8*)(ub_emb + (size_t)rb.x * D_))[l16];
        bf16x8 vpvB = ((const bf16x8*)(pVb + (size_t)rb.y * D_))[l16];
        float fueA[8], fpvA[8], fueB[8], fpvB[8];
        unpack8(vueA, fueA); unpack8(vpvA, fpvA);
        unpack8(vueB, fueB); unpack8(vpvB, fpvB);
        float w1a = __expf(ma.x + ipk_row[ra.z]);
        float w2a = __expf(ma.y);
        float w1b = hb ? __expf(mbv.x + ipk_row[rb.z]) : 0.f;
        float w2b = hb ? __expf(mbv.y) : 0.f;
        s1 += w1a + w1b; s2 += w2a + w2b;
#pragma unroll
        for (int j = 0; j < 8; j++) {
            b1[j]  = fmaf(w1a, fueA[j], fmaf(w1b, fueB[j], b1[j]));
            bpv[j] = fmaf(w1a, fpvA[j], fmaf(w1b, fpvB[j], bpv[j]));
            b2[j]  = fmaf(w2a, fueA[j], fmaf(w2b, fueB[j], b2[j]));
        }
    }
#pragma unroll
    for (int d = 16; d < 64; d <<= 1) {
        s1 += __shfl_xor(s1, d); s2 += __shfl_xor(s2, d);
#pragma unroll
        for (int j = 0; j < 8; j++) {
            b1[j]  += __shfl_xor(b1[j], d);
            bpv[j] += __shfl_xor(bpv[j], d);
            b2[j]  += __shfl_xor(b2[j], d);
        }
    }
    if (lane < 16) {
        float inv1 = 1.f / s1, inv2 = 1.f / s2;
        *(bf16x8*)(B1n + (size_t)it * D_ + l16 * 8) = pack8(b1, inv1);
        *(bf16x8*)(PVn + (size_t)it * D_ + l16 * 8) = pack8(bpv, inv1);
        *(bf16x8*)(B2n + (size_t)it * D_ + l16 * 8) = pack8(b2, inv2);
    }
}

// ---------------- finish: out1 = A1@WA^T + side; out2 = A2@WB^T + (n>0 ? 1 : 0) ----------------
__global__ __launch_bounds__(256) void finish2(const __bf16* __restrict__ A1, const __bf16* __restrict__ WA,
                                               const __bf16* __restrict__ side,
                                               const __bf16* __restrict__ A2, const __bf16* __restrict__ WB,
                                               float* __restrict__ out1, float* __restrict__ out2,
                                               const int* __restrict__ offseg, int rows) {
    int lane = threadIdx.x & 63;
    int wave = threadIdx.x >> 6;
    int row0 = blockIdx.x * 64 + wave * 16;
    if (row0 >= rows) return;
    int l16 = lane & 15, kh = lane >> 4;
    int ar = row0 + l16;
    int arc = ar < rows ? ar : rows - 1;
    const __bf16* r1 = A1 + (size_t)arc * D_;
    const __bf16* r2 = A2 + (size_t)arc * D_;

    f32x4 acc1[8] = {}, acc2[8] = {};
#pragma unroll
    for (int k0 = 0; k0 < D_; k0 += 32) {
        int kk = k0 + kh * 8;
        bf16x8 f1 = *(const bf16x8*)(r1 + kk);
        bf16x8 f2 = *(const bf16x8*)(r2 + kk);
#pragma unroll
        for (int cb = 0; cb < 8; cb++) {
            bf16x8 wa = *(const bf16x8*)(WA + (size_t)(cb * 16 + l16) * D_ + kk);
            acc1[cb] = __builtin_amdgcn_mfma_f32_16x16x32_bf16(f1, wa, acc1[cb], 0, 0, 0);
            bf16x8 wb = *(const bf16x8*)(WB + (size_t)(cb * 16 + l16) * D_ + kk);
            acc2[cb] = __builtin_amdgcn_mfma_f32_16x16x32_bf16(f2, wb, acc2[cb], 0, 0, 0);
        }
    }
#pragma unroll
    for (int cb = 0; cb < 8; cb++) {
#pragma unroll
        for (int j = 0; j < 4; j++) {
            int r = row0 + kh * 4 + j;
            if (r < rows) {
                int c = cb * 16 + l16;
                float sv = (float)side[(size_t)r * D_ + c];
                out1[(size_t)r * D_ + c] = acc1[cb][j] + sv;
                float one = (offseg[r + 1] - offseg[r]) > 0 ? 1.f : 0.f;
                out2[(size_t)r * D_ + c] = acc2[cb][j] + one;
            }
        }
    }
}

extern "C" void kernel_launch(void* const* d_in, const int* in_sizes, int n_in,
                              void* d_out, int out_size, void* d_ws, size_t ws_size,
                              hipStream_t stream) {
    (void)n_in; (void)out_size; (void)ws_size;
    const float* u_emb = (const float*)d_in[0];
    const float* i_emb = (const float*)d_in[1];
    const int* edge_u = (const int*)d_in[2];
    const int* edge_i = (const int*)d_in[3];
    const int* rui = (const int*)d_in[4];
    const int* riu = (const int*)d_in[5];
    const int* last_u_items = (const int*)d_in[6];
    const int* last_i_users = (const int*)d_in[7];
    const float* W1  = (const float*)d_in[8];
    const float* W2  = (const float*)d_in[9];
    const float* W1b = (const float*)d_in[10];
    const float* W2b = (const float*)d_in[11];
    const float* W3  = (const float*)d_in[12];
    const float* W4  = (const float*)d_in[13];
    const float* pV  = (const float*)d_in[14];
    const float* pK  = (const float*)d_in[15];
    const float* last_user_table = (const float*)d_in[16];
    const float* last_item_table = (const float*)d_in[17];

    const int NU = in_sizes[0] / D_;
    const int NI = in_sizes[1] / D_;
    const int E  = in_sizes[2];
    const int UMAXr = in_sizes[14] / D_;
    const int IMAXr = in_sizes[15] / D_;
    const int NSEG = NU + NI;

    size_t cur = 0;
    auto alloc = [&](size_t bytes) -> void* {
        void* p = (char*)d_ws + cur;
        cur += (bytes + 255) & ~(size_t)255;
        return p;
    };

    __bf16* Wb4   = (__bf16*)alloc(4 * 16384 * 2);          // W1, W2, W1b, W2b bf16
    __bf16* M2t   = (__bf16*)alloc(16384 * 2);
    __bf16* M3t   = (__bf16*)alloc(16384 * 2);
    __bf16* M4t   = (__bf16*)alloc(16384 * 2);
    __bf16* pVW2  = (__bf16*)alloc((size_t)UMAXr * D_ * 2);
    __bf16* pKW1  = (__bf16*)alloc((size_t)IMAXr * D_ * 2);
    __bf16* pVb   = (__bf16*)alloc((size_t)UMAXr * D_ * 2);
    __bf16* pKb   = (__bf16*)alloc((size_t)IMAXr * D_ * 2);
    __bf16* ub_emb = (__bf16*)alloc((size_t)NU * D_ * 2);
    __bf16* ib_emb = (__bf16*)alloc((size_t)NI * D_ * 2);
    __bf16* um_t  = (__bf16*)alloc((size_t)NU * D_ * 2);
    __bf16* li_t  = (__bf16*)alloc((size_t)NU * D_ * 2);
    __bf16* lu_t  = (__bf16*)alloc((size_t)NU * D_ * 2);
    float* upv    = (float*)alloc((size_t)NU * UMAXr * 4);
    float* ipk    = (float*)alloc((size_t)NI * IMAXr * 4);
    __bf16* A1n   = (__bf16*)alloc((size_t)NU * D_ * 2);
    __bf16* PKn   = (__bf16*)alloc((size_t)NU * D_ * 2);
    __bf16* A2n   = (__bf16*)alloc((size_t)NU * D_ * 2);
    __bf16* B1n   = (__bf16*)alloc((size_t)NI * D_ * 2);
    __bf16* PVn   = (__bf16*)alloc((size_t)NI * D_ * 2);
    __bf16* B2n   = (__bf16*)alloc((size_t)NI * D_ * 2);
    float2* mb_val = (float2*)alloc((size_t)2 * E * 8);
    int4* recs    = (int4*)alloc((size_t)2 * E * 16);
    int* cnt_all  = (int*)alloc((size_t)NSEG * 4);
    int* off_all  = (int*)alloc((size_t)(NSEG + 1) * 4);
    int* pos_all  = (int*)alloc((size_t)NSEG * 4);
    int* parts    = (int*)alloc(1024 * 4);

    float* out = (float*)d_out;
    float* hLu = out;
    float* hSu = out + (size_t)NU * D_;
    float* hLi = out + (size_t)2 * NU * D_;
    float* hSi = out + (size_t)2 * NU * D_ + (size_t)NI * D_;

    // weight casts + combined matrices
    W4p w4; w4.p[0] = W1; w4.p[1] = W2; w4.p[2] = W1b; w4.p[3] = W2b;
    cvt_weights4<<<(4 * 16384 + 255) / 256, 256, 0, stream>>>(w4, Wb4);
    prep_mats<<<128 + (UMAXr > IMAXr ? UMAXr : IMAXr), 128, 0, stream>>>(W1, W2, W3, W4, pV, pK,
                                                                         M2t, M3t, M4t, pVW2, pKW1, UMAXr, IMAXr);
    cvt2<<<(UMAXr * D_ + 255) / 256, 256, 0, stream>>>(pV, pK, pVb, pKb, UMAXr * D_);
    size_t nue = (size_t)NU * D_, nie = (size_t)NI * D_;
    cvt_emb<<<(int)(((nue + nie) / 4 + 255) / 256), 256, 0, stream>>>(u_emb, i_emb, ub_emb, ib_emb, nue, nie);

    // CSR build
    hipMemsetAsync(cnt_all, 0, (size_t)NSEG * 4, stream);
    hist2<<<(E + 255) / 256, 256, 0, stream>>>(edge_u, edge_i, cnt_all, NU, E);
    int nb = (NSEG + SCAN_TILE - 1) / SCAN_TILE;
    scan_phaseA<<<nb, 256, 0, stream>>>(cnt_all, parts, NSEG);
    scan_phaseB<<<1, 1024, 0, stream>>>(parts, nb, off_all, NSEG);
    scan_phaseC<<<nb, 256, 0, stream>>>(cnt_all, parts, off_all, pos_all, NSEG);
    scatter2<<<(E + 255) / 256, 256, 0, stream>>>(edge_u, edge_i, rui, riu, pos_all, recs, NU, E);

    // transformed user vectors + positional dot tables
    int gu = (NU + 63) / 64, gi = (NI + 63) / 64;
    user_vecs<<<gu, 256, 0, stream>>>(u_emb, last_item_table, last_u_items, last_user_table, last_i_users,
                                      M2t, M3t, M4t, um_t, li_t, lu_t, NU);
    gemm_pvk<<<gu, 256, 0, stream>>>(ub_emb, pVW2, upv, NU, UMAXr);
    gemm_pvk<<<gi, 256, 0, stream>>>(ib_emb, pKW1, ipk, NI, IMAXr);

    // edge passes
    user_pass<<<(NU + 3) / 4, 256, 0, stream>>>(off_all, recs, ib_emb, um_t, li_t, lu_t,
                                                pKb, upv, mb_val, A1n, PKn, A2n, NU, UMAXr);
    item_pass<<<(NI + 3) / 4, 256, 0, stream>>>(off_all, recs, ub_emb, pVb, ipk, mb_val,
                                                B1n, PVn, B2n, NU, NI, IMAXr);

    // finish projections: hLu = A1n@W1b^T + PKn ; hSu = A2n@W1^T + 1[n>0]
    finish2<<<gu, 256, 0, stream>>>(A1n, Wb4 + 2 * 16384, PKn, A2n, Wb4 + 0 * 16384,
                                    hLu, hSu, off_all, NU);
    // hLi = B1n@W2b^T + PVn ; hSi = B2n@W2^T + 1[n>0]
    finish2<<<gi, 256, 0, stream>>>(B1n, Wb4 + 3 * 16384, PVn, B2n, Wb4 + 1 * 16384,
                                    hLi, hSi, off_all + NU, NI);
}

// Round 8
// 581.202 us; speedup vs baseline: 1.0268x; 1.0268x over previous
//
#include <hip/hip_runtime.h>
#include <hip/hip_bf16.h>
#include <math.h>

#define D_ 128
#define INV_SQRT_D 0.08838834764831845f
#define SCAN_CH 16
#define SCAN_TILE (256 * SCAN_CH)

typedef __bf16 bf16x8 __attribute__((ext_vector_type(8)));
typedef float f32x4 __attribute__((ext_vector_type(4)));

struct W4p { const float* p[4]; };

__device__ __forceinline__ void unpack8(bf16x8 v, float* f) {
    const uint32_t* u = (const uint32_t*)&v;
#pragma unroll
    for (int i = 0; i < 4; i++) {
        uint32_t w = u[i];
        f[2 * i]     = __uint_as_float(w << 16);
        f[2 * i + 1] = __uint_as_float(w & 0xffff0000u);
    }
}

__device__ __forceinline__ bf16x8 pack8(const float* f, float s) {
    bf16x8 r;
#pragma unroll
    for (int j = 0; j < 8; j++) r[j] = (__bf16)(f[j] * s);
    return r;
}

// ---------------- casts ----------------
__global__ __launch_bounds__(256) void cvt_weights4(W4p w, __bf16* __restrict__ out) {
    int idx = blockIdx.x * 256 + threadIdx.x;
    if (idx >= 4 * 16384) return;
    out[idx] = (__bf16)w.p[idx >> 14][idx & 16383];
}

__global__ __launch_bounds__(256) void cvt2(const float* __restrict__ a, const float* __restrict__ b,
                                            __bf16* __restrict__ oa, __bf16* __restrict__ ob, int n) {
    int idx = blockIdx.x * 256 + threadIdx.x;
    if (idx < n) { oa[idx] = (__bf16)a[idx]; ob[idx] = (__bf16)b[idx]; }
}

__global__ __launch_bounds__(256) void cvt_emb(const float* __restrict__ u, const float* __restrict__ i,
                                               __bf16* __restrict__ ub, __bf16* __restrict__ ib,
                                               size_t nue, size_t nie) {
    size_t idx4 = ((size_t)blockIdx.x * 256 + threadIdx.x) * 4;
    if (idx4 < nue) {
        float4 v = *(const float4*)(u + idx4);
        ub[idx4] = (__bf16)v.x; ub[idx4+1] = (__bf16)v.y; ub[idx4+2] = (__bf16)v.z; ub[idx4+3] = (__bf16)v.w;
    } else if (idx4 < nue + nie) {
        size_t j = idx4 - nue;
        float4 v = *(const float4*)(i + j);
        ib[j] = (__bf16)v.x; ib[j+1] = (__bf16)v.y; ib[j+2] = (__bf16)v.z; ib[j+3] = (__bf16)v.w;
    }
}

// ---------------- combined-matrix prep ----------------
__global__ __launch_bounds__(128) void prep_mats(const float* __restrict__ W1, const float* __restrict__ W2,
                                                 const float* __restrict__ W3, const float* __restrict__ W4,
                                                 const float* __restrict__ pV, const float* __restrict__ pK,
                                                 __bf16* __restrict__ M2t, __bf16* __restrict__ M3t,
                                                 __bf16* __restrict__ M4t,
                                                 __bf16* __restrict__ pVW2, __bf16* __restrict__ pKW1,
                                                 int umax, int imax) {
    __shared__ float sh[256];
    int b = blockIdx.x, t = threadIdx.x;
    if (b < 128) {
        sh[t] = W1[t * 128 + b];
        __syncthreads();
        float m2 = 0.f, m3 = 0.f, m4 = 0.f;
        for (int k = 0; k < 128; k++) {
            float w = sh[k];
            m2 = fmaf(w, W2[k * 128 + t], m2);
            m3 = fmaf(w, W3[k * 128 + t], m3);
            m4 = fmaf(w, W4[k * 128 + t], m4);
        }
        M2t[b * 128 + t] = (__bf16)(m2 * INV_SQRT_D);
        M3t[b * 128 + t] = (__bf16)(m3 * INV_SQRT_D);
        M4t[b * 128 + t] = (__bf16)(m4 * INV_SQRT_D);
    } else {
        int r = b - 128;
        if (r < umax) sh[t] = pV[r * 128 + t];
        if (r < imax) sh[128 + t] = pK[r * 128 + t];
        __syncthreads();
        float q = 0.f, qk = 0.f;
        for (int a = 0; a < 128; a++) {
            if (r < umax) q  = fmaf(sh[a], W2[a * 128 + t], q);
            if (r < imax) qk = fmaf(sh[128 + a], W1[a * 128 + t], qk);
        }
        if (r < umax) pVW2[r * 128 + t] = (__bf16)(q * INV_SQRT_D);
        if (r < imax) pKW1[r * 128 + t] = (__bf16)(qk * INV_SQRT_D);
    }
}

// ---------------- user transformed vectors ----------------
__global__ __launch_bounds__(256) void user_vecs(const float* __restrict__ u_emb,
                                                 const float* __restrict__ lit_tab, const int* __restrict__ g_li,
                                                 const float* __restrict__ lut_tab, const int* __restrict__ g_lu,
                                                 const __bf16* __restrict__ M2t, const __bf16* __restrict__ M3t,
                                                 const __bf16* __restrict__ M4t,
                                                 __bf16* __restrict__ um_t, __bf16* __restrict__ li_t,
                                                 __bf16* __restrict__ lu_t, int rows) {
    int lane = threadIdx.x & 63;
    int wave = threadIdx.x >> 6;
    int row0 = blockIdx.x * 64 + wave * 16;
    if (row0 >= rows) return;
    int l16 = lane & 15, kh = lane >> 4;
    int ar = row0 + l16;
    int arc = ar < rows ? ar : rows - 1;
    const float* rA = u_emb + (size_t)arc * D_;
    const float* rB = lit_tab + (size_t)g_li[arc] * D_;
    const float* rC = lut_tab + (size_t)g_lu[arc] * D_;

    f32x4 aA[8] = {}, aB[8] = {}, aC[8] = {};
#pragma unroll
    for (int k0 = 0; k0 < D_; k0 += 32) {
        int kk = k0 + kh * 8;
        float4 a0 = *(const float4*)(rA + kk), a1 = *(const float4*)(rA + kk + 4);
        float4 b0 = *(const float4*)(rB + kk), b1 = *(const float4*)(rB + kk + 4);
        float4 c0 = *(const float4*)(rC + kk), c1 = *(const float4*)(rC + kk + 4);
        bf16x8 fA, fB, fC;
        fA[0]=(__bf16)a0.x; fA[1]=(__bf16)a0.y; fA[2]=(__bf16)a0.z; fA[3]=(__bf16)a0.w;
        fA[4]=(__bf16)a1.x; fA[5]=(__bf16)a1.y; fA[6]=(__bf16)a1.z; fA[7]=(__bf16)a1.w;
        fB[0]=(__bf16)b0.x; fB[1]=(__bf16)b0.y; fB[2]=(__bf16)b0.z; fB[3]=(__bf16)b0.w;
        fB[4]=(__bf16)b1.x; fB[5]=(__bf16)b1.y; fB[6]=(__bf16)b1.z; fB[7]=(__bf16)b1.w;
        fC[0]=(__bf16)c0.x; fC[1]=(__bf16)c0.y; fC[2]=(__bf16)c0.z; fC[3]=(__bf16)c0.w;
        fC[4]=(__bf16)c1.x; fC[5]=(__bf16)c1.y; fC[6]=(__bf16)c1.z; fC[7]=(__bf16)c1.w;
#pragma unroll
        for (int cb = 0; cb < 8; cb++) {
            bf16x8 w2 = *(const bf16x8*)(M2t + (size_t)(cb * 16 + l16) * D_ + kk);
            aA[cb] = __builtin_amdgcn_mfma_f32_16x16x32_bf16(fA, w2, aA[cb], 0, 0, 0);
            bf16x8 w3 = *(const bf16x8*)(M3t + (size_t)(cb * 16 + l16) * D_ + kk);
            aB[cb] = __builtin_amdgcn_mfma_f32_16x16x32_bf16(fB, w3, aB[cb], 0, 0, 0);
            bf16x8 w4 = *(const bf16x8*)(M4t + (size_t)(cb * 16 + l16) * D_ + kk);
            aC[cb] = __builtin_amdgcn_mfma_f32_16x16x32_bf16(fC, w4, aC[cb], 0, 0, 0);
        }
    }
#pragma unroll
    for (int cb = 0; cb < 8; cb++) {
#pragma unroll
        for (int j = 0; j < 4; j++) {
            int r = row0 + kh * 4 + j;
            if (r < rows) {
                um_t[(size_t)r * D_ + cb * 16 + l16] = (__bf16)aA[cb][j];
                li_t[(size_t)r * D_ + cb * 16 + l16] = (__bf16)aB[cb][j];
                lu_t[(size_t)r * D_ + cb * 16 + l16] = (__bf16)aC[cb][j];
            }
        }
    }
}

// ---------------- small GEMM: Y(rows x ncols f32) = Xb @ P^T (scale prefolded in P) ----------------
__global__ __launch_bounds__(256) void gemm_pvk(const __bf16* __restrict__ Xb,
                                                const __bf16* __restrict__ Pb,
                                                float* __restrict__ Y, int rows, int ncols) {
    int lane = threadIdx.x & 63;
    int wave = threadIdx.x >> 6;
    int row0 = blockIdx.x * 64 + wave * 16;
    if (row0 >= rows) return;
    int l16 = lane & 15, kh = lane >> 4;
    int ar = row0 + l16;
    int arc = ar < rows ? ar : rows - 1;
    const __bf16* arow = Xb + (size_t)arc * D_;

    f32x4 acc[4] = {};
#pragma unroll
    for (int k0 = 0; k0 < D_; k0 += 32) {
        int kk = k0 + kh * 8;
        bf16x8 af = *(const bf16x8*)(arow + kk);
#pragma unroll
        for (int cb = 0; cb < 4; cb++) {
            int br = cb * 16 + l16;
            if (br >= ncols) br = ncols - 1;
            bf16x8 bf = *(const bf16x8*)(Pb + (size_t)br * D_ + kk);
            acc[cb] = __builtin_amdgcn_mfma_f32_16x16x32_bf16(af, bf, acc[cb], 0, 0, 0);
        }
    }
#pragma unroll
    for (int cb = 0; cb < 4; cb++) {
        int col = cb * 16 + l16;
        if (col >= ncols) continue;
#pragma unroll
        for (int j = 0; j < 4; j++) {
            int r = row0 + kh * 4 + j;
            if (r < rows) Y[(size_t)r * ncols + col] = acc[cb][j];
        }
    }
}

// ---------------- CSR build ----------------
__global__ __launch_bounds__(256) void hist2(const int* __restrict__ eu, const int* __restrict__ ei,
                                             int* __restrict__ cnt_all, int nu, int E) {
    int e = blockIdx.x * 256 + threadIdx.x;
    if (e < E) {
        atomicAdd(&cnt_all[eu[e]], 1);
        atomicAdd(&cnt_all[nu + ei[e]], 1);
    }
}

__global__ __launch_bounds__(256) void scan_phaseA(const int* __restrict__ cnt, int* __restrict__ part, int n) {
    __shared__ int wsum[4];
    int t = threadIdx.x, lane = t & 63, w = t >> 6;
    int i0 = blockIdx.x * SCAN_TILE + t * SCAN_CH;
    int tot = 0;
#pragma unroll
    for (int j = 0; j < SCAN_CH; j++) tot += (i0 + j < n) ? cnt[i0 + j] : 0;
#pragma unroll
    for (int d = 32; d; d >>= 1) tot += __shfl_xor(tot, d);
    if (lane == 0) wsum[w] = tot;
    __syncthreads();
    if (t == 0) part[blockIdx.x] = wsum[0] + wsum[1] + wsum[2] + wsum[3];
}

__global__ __launch_bounds__(1024) void scan_phaseB(int* __restrict__ part, int nb,
                                                    int* __restrict__ off, int n) {
    __shared__ int wsum[16];
    int t = threadIdx.x, lane = t & 63, w = t >> 6;
    int v = (t < nb) ? part[t] : 0;
    int x = v;
#pragma unroll
    for (int d = 1; d < 64; d <<= 1) {
        int y = __shfl_up(x, d);
        if (lane >= d) x += y;
    }
    if (lane == 63) wsum[w] = x;
    __syncthreads();
    int wbase = 0;
    for (int ww = 0; ww < w; ww++) wbase += wsum[ww];
    if (t < nb) part[t] = wbase + x - v;
    if (t == 1023) off[n] = wbase + x;
}

__global__ __launch_bounds__(256) void scan_phaseC(const int* __restrict__ cnt, const int* __restrict__ part,
                                                   int* __restrict__ off, int* __restrict__ pos, int n) {
    __shared__ int wsum[4];
    int t = threadIdx.x, lane = t & 63, w = t >> 6;
    int i0 = blockIdx.x * SCAN_TILE + t * SCAN_CH;
    int loc[SCAN_CH];
    int tot = 0;
#pragma unroll
    for (int j = 0; j < SCAN_CH; j++) {
        int v = (i0 + j < n) ? cnt[i0 + j] : 0;
        loc[j] = tot; tot += v;
    }
    int x = tot;
#pragma unroll
    for (int d = 1; d < 64; d <<= 1) {
        int y = __shfl_up(x, d);
        if (lane >= d) x += y;
    }
    if (lane == 63) wsum[w] = x;
    __syncthreads();
    int wbase = 0;
    for (int ww = 0; ww < w; ww++) wbase += wsum[ww];
    int excl = part[blockIdx.x] + wbase + x - tot;
#pragma unroll
    for (int j = 0; j < SCAN_CH; j++) {
        if (i0 + j < n) { off[i0 + j] = excl + loc[j]; pos[i0 + j] = excl + loc[j]; }
    }
}

__global__ __launch_bounds__(256) void scatter2(const int* __restrict__ eu, const int* __restrict__ ei,
                                                const int* __restrict__ rui, const int* __restrict__ riu,
                                                int* __restrict__ pos_all, int4* __restrict__ recs,
                                                int nu, int E) {
    int e = blockIdx.x * 256 + threadIdx.x;
    if (e < E) {
        int u = eu[e], it = ei[e], r1 = rui[e], r2 = riu[e];
        int pi = atomicAdd(&pos_all[nu + it], 1);
        int pu = atomicAdd(&pos_all[u], 1);
        recs[pu] = make_int4(it, r1, r2, pi);
        recs[pi] = make_int4(u, r1, r2, 0);
    }
}

// ---------------- user pass ----------------
__global__ __launch_bounds__(256) void user_pass(const int* __restrict__ off_all, const int4* __restrict__ recs,
                                                 const __bf16* __restrict__ ib_emb,
                                                 const __bf16* __restrict__ um_t,
                                                 const __bf16* __restrict__ li_t,
                                                 const __bf16* __restrict__ lu_t,
                                                 const __bf16* __restrict__ pKb,
                                                 const float* __restrict__ upv,
                                                 float2* __restrict__ mb_val,
                                                 __bf16* __restrict__ A1n, __bf16* __restrict__ PKn,
                                                 __bf16* __restrict__ A2n, int nu, int umax) {
    int u = blockIdx.x * 4 + (threadIdx.x >> 6);
    if (u >= nu) return;
    int lane = threadIdx.x & 63;
    int g = lane >> 4, l16 = lane & 15;
    int off = off_all[u], n = off_all[u + 1] - off;
    if (n == 0) {
        if (lane < 16) {
            bf16x8 z = {};
            *(bf16x8*)(A1n + (size_t)u * D_ + l16 * 8) = z;
            *(bf16x8*)(PKn + (size_t)u * D_ + l16 * 8) = z;
            *(bf16x8*)(A2n + (size_t)u * D_ + l16 * 8) = z;
        }
        return;
    }
    float um8[8], li8[8], lu8[8];
    unpack8(((const bf16x8*)(um_t + (size_t)u * D_))[l16], um8);
    unpack8(((const bf16x8*)(li_t + (size_t)u * D_))[l16], li8);
    unpack8(((const bf16x8*)(lu_t + (size_t)u * D_))[l16], lu8);
    const float* upv_row = upv + (size_t)u * umax;

    float s1 = 0.f, s2 = 0.f, a1[8] = {}, apk[8] = {}, a2[8] = {};
    for (int i = g; i < n; i += 8) {
        int4 ra = recs[off + i];
        bool hb = (i + 4) < n;
        int4 rb = recs[off + (hb ? i + 4 : i)];
        bf16x8 vieA = ((const bf16x8*)(ib_emb + (size_t)ra.x * D_))[l16];
        bf16x8 vpkA = ((const bf16x8*)(pKb + (size_t)ra.z * D_))[l16];
        bf16x8 vieB = ((const bf16x8*)(ib_emb + (size_t)rb.x * D_))[l16];
        bf16x8 vpkB = ((const bf16x8*)(pKb + (size_t)rb.z * D_))[l16];
        float fieA[8], fpkA[8], fieB[8], fpkB[8];
        unpack8(vieA, fieA); unpack8(vpkA, fpkA);
        unpack8(vieB, fieB); unpack8(vpkB, fpkB);
        float d1a = 0.f, d2a = 0.f, d3a = 0.f, d1b = 0.f, d2b = 0.f, d3b = 0.f;
#pragma unroll
        for (int j = 0; j < 8; j++) {
            d1a = fmaf(um8[j], fieA[j], d1a);
            d2a = fmaf(li8[j], fieA[j], d2a);
            d3a = fmaf(lu8[j], fieA[j], d3a);
            d1b = fmaf(um8[j], fieB[j], d1b);
            d2b = fmaf(li8[j], fieB[j], d2b);
            d3b = fmaf(lu8[j], fieB[j], d3b);
        }
#pragma unroll
        for (int d = 1; d < 16; d <<= 1) {
            d1a += __shfl_xor(d1a, d); d2a += __shfl_xor(d2a, d); d3a += __shfl_xor(d3a, d);
            d1b += __shfl_xor(d1b, d); d2b += __shfl_xor(d2b, d); d3b += __shfl_xor(d3b, d);
        }
        if (l16 == 0) {
            mb_val[ra.w] = make_float2(d1a, d3a);
            if (hb) mb_val[rb.w] = make_float2(d1b, d3b);
        }
        float w1a = __expf(d1a + upv_row[ra.y]);
        float w2a = __expf(d2a);
        float w1b = hb ? __expf(d1b + upv_row[rb.y]) : 0.f;
        float w2b = hb ? __expf(d2b) : 0.f;
        s1 += w1a + w1b; s2 += w2a + w2b;
#pragma unroll
        for (int j = 0; j < 8; j++) {
            a1[j]  = fmaf(w1a, fieA[j], fmaf(w1b, fieB[j], a1[j]));
            apk[j] = fmaf(w1a, fpkA[j], fmaf(w1b, fpkB[j], apk[j]));
            a2[j]  = fmaf(w2a, fieA[j], fmaf(w2b, fieB[j], a2[j]));
        }
    }
#pragma unroll
    for (int d = 16; d < 64; d <<= 1) {
        s1 += __shfl_xor(s1, d); s2 += __shfl_xor(s2, d);
#pragma unroll
        for (int j = 0; j < 8; j++) {
            a1[j]  += __shfl_xor(a1[j], d);
            apk[j] += __shfl_xor(apk[j], d);
            a2[j]  += __shfl_xor(a2[j], d);
        }
    }
    if (lane < 16) {
        float inv1 = 1.f / s1, inv2 = 1.f / s2;
        *(bf16x8*)(A1n + (size_t)u * D_ + l16 * 8) = pack8(a1, inv1);
        *(bf16x8*)(PKn + (size_t)u * D_ + l16 * 8) = pack8(apk, inv1);
        *(bf16x8*)(A2n + (size_t)u * D_ + l16 * 8) = pack8(a2, inv2);
    }
}

// ---------------- item pass ----------------
__global__ __launch_bounds__(256) void item_pass(const int* __restrict__ off_all, const int4* __restrict__ recs,
                                                 const __bf16* __restrict__ ub_emb,
                                                 const __bf16* __restrict__ pVb,
                                                 const float* __restrict__ ipk,
                                                 const float2* __restrict__ mb_val,
                                                 __bf16* __restrict__ B1n, __bf16* __restrict__ PVn,
                                                 __bf16* __restrict__ B2n, int nu, int ni, int imax) {
    int it = blockIdx.x * 4 + (threadIdx.x >> 6);
    if (it >= ni) return;
    int lane = threadIdx.x & 63;
    int g = lane >> 4, l16 = lane & 15;
    int off = off_all[nu + it], n = off_all[nu + it + 1] - off;
    if (n == 0) {
        if (lane < 16) {
            bf16x8 z = {};
            *(bf16x8*)(B1n + (size_t)it * D_ + l16 * 8) = z;
            *(bf16x8*)(PVn + (size_t)it * D_ + l16 * 8) = z;
            *(bf16x8*)(B2n + (size_t)it * D_ + l16 * 8) = z;
        }
        return;
    }
    const float* ipk_row = ipk + (size_t)it * imax;

    float s1 = 0.f, s2 = 0.f, b1[8] = {}, bpv[8] = {}, b2[8] = {};
    for (int i = g; i < n; i += 8) {
        int4 ra = recs[off + i];
        bool hb = (i + 4) < n;
        int4 rb = recs[off + (hb ? i + 4 : i)];
        float2 ma = mb_val[off + i];
        float2 mbv = hb ? mb_val[off + i + 4] : make_float2(0.f, 0.f);
        bf16x8 vueA = ((const bf16x8*)(ub_emb + (size_t)ra.x * D_))[l16];
        bf16x8 vpvA = ((const bf16x8*)(pVb + (size_t)ra.y * D_))[l16];
        bf16x8 vueB = ((const bf16x8*)(ub_emb + (size_t)rb.x * D_))[l16];
        bf16x8 vpvB = ((const bf16x8*)(pVb + (size_t)rb.y * D_))[l16];
        float fueA[8], fpvA[8], fueB[8], fpvB[8];
        unpack8(vueA, fueA); unpack8(vpvA, fpvA);
        unpack8(vueB, fueB); unpack8(vpvB, fpvB);
        float w1a = __expf(ma.x + ipk_row[ra.z]);
        float w2a = __expf(ma.y);
        float w1b = hb ? __expf(mbv.x + ipk_row[rb.z]) : 0.f;
        float w2b = hb ? __expf(mbv.y) : 0.f;
        s1 += w1a + w1b; s2 += w2a + w2b;
#pragma unroll
        for (int j = 0; j < 8; j++) {
            b1[j]  = fmaf(w1a, fueA[j], fmaf(w1b, fueB[j], b1[j]));
            bpv[j] = fmaf(w1a, fpvA[j], fmaf(w1b, fpvB[j], bpv[j]));
            b2[j]  = fmaf(w2a, fueA[j], fmaf(w2b, fueB[j], b2[j]));
        }
    }
#pragma unroll
    for (int d = 16; d < 64; d <<= 1) {
        s1 += __shfl_xor(s1, d); s2 += __shfl_xor(s2, d);
#pragma unroll
        for (int j = 0; j < 8; j++) {
            b1[j]  += __shfl_xor(b1[j], d);
            bpv[j] += __shfl_xor(bpv[j], d);
            b2[j]  += __shfl_xor(b2[j], d);
        }
    }
    if (lane < 16) {
        float inv1 = 1.f / s1, inv2 = 1.f / s2;
        *(bf16x8*)(B1n + (size_t)it * D_ + l16 * 8) = pack8(b1, inv1);
        *(bf16x8*)(PVn + (size_t)it * D_ + l16 * 8) = pack8(bpv, inv1);
        *(bf16x8*)(B2n + (size_t)it * D_ + l16 * 8) = pack8(b2, inv2);
    }
}

// ---------------- finish: LDS-staged epilogue with coalesced float4 stores ----------------
// out1 = A1@WA^T + side; out2 = A2@WB^T + (n>0 ? 1 : 0)
__global__ __launch_bounds__(256) void finish2(const __bf16* __restrict__ A1, const __bf16* __restrict__ WA,
                                               const __bf16* __restrict__ side,
                                               const __bf16* __restrict__ A2, const __bf16* __restrict__ WB,
                                               float* __restrict__ out1, float* __restrict__ out2,
                                               const int* __restrict__ offseg, int rows) {
    __shared__ float lds[4][16][132];
    int lane = threadIdx.x & 63;
    int wave = threadIdx.x >> 6;
    int row0 = blockIdx.x * 64 + wave * 16;
    bool act = row0 < rows;
    int l16 = lane & 15, kh = lane >> 4;
    int ar = row0 + l16;
    int arc = act ? (ar < rows ? ar : rows - 1) : 0;
    const __bf16* r1 = A1 + (size_t)arc * D_;
    const __bf16* r2 = A2 + (size_t)arc * D_;

    f32x4 acc1[8] = {}, acc2[8] = {};
    if (act) {
#pragma unroll
        for (int k0 = 0; k0 < D_; k0 += 32) {
            int kk = k0 + kh * 8;
            bf16x8 f1 = *(const bf16x8*)(r1 + kk);
            bf16x8 f2 = *(const bf16x8*)(r2 + kk);
#pragma unroll
            for (int cb = 0; cb < 8; cb++) {
                bf16x8 wa = *(const bf16x8*)(WA + (size_t)(cb * 16 + l16) * D_ + kk);
                acc1[cb] = __builtin_amdgcn_mfma_f32_16x16x32_bf16(f1, wa, acc1[cb], 0, 0, 0);
                bf16x8 wb = *(const bf16x8*)(WB + (size_t)(cb * 16 + l16) * D_ + kk);
                acc2[cb] = __builtin_amdgcn_mfma_f32_16x16x32_bf16(f2, wb, acc2[cb], 0, 0, 0);
            }
        }
#pragma unroll
        for (int cb = 0; cb < 8; cb++)
#pragma unroll
            for (int j = 0; j < 4; j++)
                lds[wave][kh * 4 + j][cb * 16 + l16] = acc1[cb][j];
    }
    __syncthreads();
    int hw = lane >> 5, c4 = (lane & 31) * 4;
    if (act) {
#pragma unroll
        for (int k = 0; k < 8; k++) {
            int wr = hw + k * 2;
            int rg = row0 + wr;
            if (rg < rows) {
                float4 v = *(const float4*)&lds[wave][wr][c4];
                ushort4 sv = *(const ushort4*)((const unsigned short*)side + (size_t)rg * D_ + c4);
                v.x += __uint_as_float((uint32_t)sv.x << 16);
                v.y += __uint_as_float((uint32_t)sv.y << 16);
                v.z += __uint_as_float((uint32_t)sv.z << 16);
                v.w += __uint_as_float((uint32_t)sv.w << 16);
                *(float4*)(out1 + (size_t)rg * D_ + c4) = v;
            }
        }
    }
    __syncthreads();
    if (act) {
#pragma unroll
        for (int cb = 0; cb < 8; cb++)
#pragma unroll
            for (int j = 0; j < 4; j++)
                lds[wave][kh * 4 + j][cb * 16 + l16] = acc2[cb][j];
    }
    __syncthreads();
    if (act) {
#pragma unroll
        for (int k = 0; k < 8; k++) {
            int wr = hw + k * 2;
            int rg = row0 + wr;
            if (rg < rows) {
                float one = (offseg[rg + 1] - offseg[rg]) > 0 ? 1.f : 0.f;
                float4 v = *(const float4*)&lds[wave][wr][c4];
                v.x += one; v.y += one; v.z += one; v.w += one;
                *(float4*)(out2 + (size_t)rg * D_ + c4) = v;
            }
        }
    }
}

extern "C" void kernel_launch(void* const* d_in, const int* in_sizes, int n_in,
                              void* d_out, int out_size, void* d_ws, size_t ws_size,
                              hipStream_t stream) {
    (void)n_in; (void)out_size; (void)ws_size;
    const float* u_emb = (const float*)d_in[0];
    const float* i_emb = (const float*)d_in[1];
    const int* edge_u = (const int*)d_in[2];
    const int* edge_i = (const int*)d_in[3];
    const int* rui = (const int*)d_in[4];
    const int* riu = (const int*)d_in[5];
    const int* last_u_items = (const int*)d_in[6];
    const int* last_i_users = (const int*)d_in[7];
    const float* W1  = (const float*)d_in[8];
    const float* W2  = (const float*)d_in[9];
    const float* W1b = (const float*)d_in[10];
    const float* W2b = (const float*)d_in[11];
    const float* W3  = (const float*)d_in[12];
    const float* W4  = (const float*)d_in[13];
    const float* pV  = (const float*)d_in[14];
    const float* pK  = (const float*)d_in[15];
    const float* last_user_table = (const float*)d_in[16];
    const float* last_item_table = (const float*)d_in[17];

    const int NU = in_sizes[0] / D_;
    const int NI = in_sizes[1] / D_;
    const int E  = in_sizes[2];
    const int UMAXr = in_sizes[14] / D_;
    const int IMAXr = in_sizes[15] / D_;
    const int NSEG = NU + NI;

    size_t cur = 0;
    auto alloc = [&](size_t bytes) -> void* {
        void* p = (char*)d_ws + cur;
        cur += (bytes + 255) & ~(size_t)255;
        return p;
    };

    __bf16* Wb4   = (__bf16*)alloc(4 * 16384 * 2);          // W1, W2, W1b, W2b bf16
    __bf16* M2t   = (__bf16*)alloc(16384 * 2);
    __bf16* M3t   = (__bf16*)alloc(16384 * 2);
    __bf16* M4t   = (__bf16*)alloc(16384 * 2);
    __bf16* pVW2  = (__bf16*)alloc((size_t)UMAXr * D_ * 2);
    __bf16* pKW1  = (__bf16*)alloc((size_t)IMAXr * D_ * 2);
    __bf16* pVb   = (__bf16*)alloc((size_t)UMAXr * D_ * 2);
    __bf16* pKb   = (__bf16*)alloc((size_t)IMAXr * D_ * 2);
    __bf16* ub_emb = (__bf16*)alloc((size_t)NU * D_ * 2);
    __bf16* ib_emb = (__bf16*)alloc((size_t)NI * D_ * 2);
    __bf16* um_t  = (__bf16*)alloc((size_t)NU * D_ * 2);
    __bf16* li_t  = (__bf16*)alloc((size_t)NU * D_ * 2);
    __bf16* lu_t  = (__bf16*)alloc((size_t)NU * D_ * 2);
    float* upv    = (float*)alloc((size_t)NU * UMAXr * 4);
    float* ipk    = (float*)alloc((size_t)NI * IMAXr * 4);
    __bf16* A1n   = (__bf16*)alloc((size_t)NU * D_ * 2);
    __bf16* PKn   = (__bf16*)alloc((size_t)NU * D_ * 2);
    __bf16* A2n   = (__bf16*)alloc((size_t)NU * D_ * 2);
    __bf16* B1n   = (__bf16*)alloc((size_t)NI * D_ * 2);
    __bf16* PVn   = (__bf16*)alloc((size_t)NI * D_ * 2);
    __bf16* B2n   = (__bf16*)alloc((size_t)NI * D_ * 2);
    float2* mb_val = (float2*)alloc((size_t)2 * E * 8);
    int4* recs    = (int4*)alloc((size_t)2 * E * 16);
    int* cnt_all  = (int*)alloc((size_t)NSEG * 4);
    int* off_all  = (int*)alloc((size_t)(NSEG + 1) * 4);
    int* pos_all  = (int*)alloc((size_t)NSEG * 4);
    int* parts    = (int*)alloc(1024 * 4);

    float* out = (float*)d_out;
    float* hLu = out;
    float* hSu = out + (size_t)NU * D_;
    float* hLi = out + (size_t)2 * NU * D_;
    float* hSi = out + (size_t)2 * NU * D_ + (size_t)NI * D_;

    // weight casts + combined matrices
    W4p w4; w4.p[0] = W1; w4.p[1] = W2; w4.p[2] = W1b; w4.p[3] = W2b;
    cvt_weights4<<<(4 * 16384 + 255) / 256, 256, 0, stream>>>(w4, Wb4);
    prep_mats<<<128 + (UMAXr > IMAXr ? UMAXr : IMAXr), 128, 0, stream>>>(W1, W2, W3, W4, pV, pK,
                                                                         M2t, M3t, M4t, pVW2, pKW1, UMAXr, IMAXr);
    cvt2<<<(UMAXr * D_ + 255) / 256, 256, 0, stream>>>(pV, pK, pVb, pKb, UMAXr * D_);
    size_t nue = (size_t)NU * D_, nie = (size_t)NI * D_;
    cvt_emb<<<(int)(((nue + nie) / 4 + 255) / 256), 256, 0, stream>>>(u_emb, i_emb, ub_emb, ib_emb, nue, nie);

    // CSR build
    hipMemsetAsync(cnt_all, 0, (size_t)NSEG * 4, stream);
    hist2<<<(E + 255) / 256, 256, 0, stream>>>(edge_u, edge_i, cnt_all, NU, E);
    int nb = (NSEG + SCAN_TILE - 1) / SCAN_TILE;
    scan_phaseA<<<nb, 256, 0, stream>>>(cnt_all, parts, NSEG);
    scan_phaseB<<<1, 1024, 0, stream>>>(parts, nb, off_all, NSEG);
    scan_phaseC<<<nb, 256, 0, stream>>>(cnt_all, parts, off_all, pos_all, NSEG);
    scatter2<<<(E + 255) / 256, 256, 0, stream>>>(edge_u, edge_i, rui, riu, pos_all, recs, NU, E);

    // transformed user vectors + positional dot tables
    int gu = (NU + 63) / 64, gi = (NI + 63) / 64;
    user_vecs<<<gu, 256, 0, stream>>>(u_emb, last_item_table, last_u_items, last_user_table, last_i_users,
                                      M2t, M3t, M4t, um_t, li_t, lu_t, NU);
    gemm_pvk<<<gu, 256, 0, stream>>>(ub_emb, pVW2, upv, NU, UMAXr);
    gemm_pvk<<<gi, 256, 0, stream>>>(ib_emb, pKW1, ipk, NI, IMAXr);

    // edge passes
    user_pass<<<(NU + 3) / 4, 256, 0, stream>>>(off_all, recs, ib_emb, um_t, li_t, lu_t,
                                                pKb, upv, mb_val, A1n, PKn, A2n, NU, UMAXr);
    item_pass<<<(NI + 3) / 4, 256, 0, stream>>>(off_all, recs, ub_emb, pVb, ipk, mb_val,
                                                B1n, PVn, B2n, NU, NI, IMAXr);

    // finish projections: hLu = A1n@W1b^T + PKn ; hSu = A2n@W1^T + 1[n>0]
    finish2<<<gu, 256, 0, stream>>>(A1n, Wb4 + 2 * 16384, PKn, A2n, Wb4 + 0 * 16384,
                                    hLu, hSu, off_all, NU);
    // hLi = B1n@W2b^T + PVn ; hSi = B2n@W2^T + 1[n>0]
    finish2<<<gi, 256, 0, stream>>>(B1n, Wb4 + 3 * 16384, PVn, B2n, Wb4 + 1 * 16384,
                                    hLi, hSi, off_all + NU, NI);
}

// Round 9
// 557.405 us; speedup vs baseline: 1.0706x; 1.0427x over previous
//
#include <hip/hip_runtime.h>
#include <hip/hip_bf16.h>
#include <math.h>

#define D_ 128
#define INV_SQRT_D 0.08838834764831845f
#define SCAN_CH 16
#define SCAN_TILE (256 * SCAN_CH)

typedef __bf16 bf16x8 __attribute__((ext_vector_type(8)));
typedef float f32x4 __attribute__((ext_vector_type(4)));

struct W4p { const float* p[4]; };

__device__ __forceinline__ void unpack8(bf16x8 v, float* f) {
    const uint32_t* u = (const uint32_t*)&v;
#pragma unroll
    for (int i = 0; i < 4; i++) {
        uint32_t w = u[i];
        f[2 * i]     = __uint_as_float(w << 16);
        f[2 * i + 1] = __uint_as_float(w & 0xffff0000u);
    }
}

__device__ __forceinline__ bf16x8 pack8(const float* f, float s) {
    bf16x8 r;
#pragma unroll
    for (int j = 0; j < 8; j++) r[j] = (__bf16)(f[j] * s);
    return r;
}

// ---------------- casts ----------------
__global__ __launch_bounds__(256) void cvt_weights4(W4p w, __bf16* __restrict__ out) {
    int idx = blockIdx.x * 256 + threadIdx.x;
    if (idx >= 4 * 16384) return;
    out[idx] = (__bf16)w.p[idx >> 14][idx & 16383];
}

__global__ __launch_bounds__(256) void cvt2(const float* __restrict__ a, const float* __restrict__ b,
                                            __bf16* __restrict__ oa, __bf16* __restrict__ ob, int n) {
    int idx = blockIdx.x * 256 + threadIdx.x;
    if (idx < n) { oa[idx] = (__bf16)a[idx]; ob[idx] = (__bf16)b[idx]; }
}

__global__ __launch_bounds__(256) void cvt_emb(const float* __restrict__ u, const float* __restrict__ i,
                                               __bf16* __restrict__ ub, __bf16* __restrict__ ib,
                                               size_t nue, size_t nie) {
    size_t idx4 = ((size_t)blockIdx.x * 256 + threadIdx.x) * 4;
    if (idx4 < nue) {
        float4 v = *(const float4*)(u + idx4);
        ub[idx4] = (__bf16)v.x; ub[idx4+1] = (__bf16)v.y; ub[idx4+2] = (__bf16)v.z; ub[idx4+3] = (__bf16)v.w;
    } else if (idx4 < nue + nie) {
        size_t j = idx4 - nue;
        float4 v = *(const float4*)(i + j);
        ib[j] = (__bf16)v.x; ib[j+1] = (__bf16)v.y; ib[j+2] = (__bf16)v.z; ib[j+3] = (__bf16)v.w;
    }
}

// ---------------- combined-matrix prep ----------------
__global__ __launch_bounds__(128) void prep_mats(const float* __restrict__ W1, const float* __restrict__ W2,
                                                 const float* __restrict__ W3, const float* __restrict__ W4,
                                                 const float* __restrict__ pV, const float* __restrict__ pK,
                                                 __bf16* __restrict__ M2t, __bf16* __restrict__ M3t,
                                                 __bf16* __restrict__ M4t,
                                                 __bf16* __restrict__ pVW2, __bf16* __restrict__ pKW1,
                                                 int umax, int imax) {
    __shared__ float sh[256];
    int b = blockIdx.x, t = threadIdx.x;
    if (b < 128) {
        sh[t] = W1[t * 128 + b];
        __syncthreads();
        float m2 = 0.f, m3 = 0.f, m4 = 0.f;
        for (int k = 0; k < 128; k++) {
            float w = sh[k];
            m2 = fmaf(w, W2[k * 128 + t], m2);
            m3 = fmaf(w, W3[k * 128 + t], m3);
            m4 = fmaf(w, W4[k * 128 + t], m4);
        }
        M2t[b * 128 + t] = (__bf16)(m2 * INV_SQRT_D);
        M3t[b * 128 + t] = (__bf16)(m3 * INV_SQRT_D);
        M4t[b * 128 + t] = (__bf16)(m4 * INV_SQRT_D);
    } else {
        int r = b - 128;
        if (r < umax) sh[t] = pV[r * 128 + t];
        if (r < imax) sh[128 + t] = pK[r * 128 + t];
        __syncthreads();
        float q = 0.f, qk = 0.f;
        for (int a = 0; a < 128; a++) {
            if (r < umax) q  = fmaf(sh[a], W2[a * 128 + t], q);
            if (r < imax) qk = fmaf(sh[128 + a], W1[a * 128 + t], qk);
        }
        if (r < umax) pVW2[r * 128 + t] = (__bf16)(q * INV_SQRT_D);
        if (r < imax) pKW1[r * 128 + t] = (__bf16)(qk * INV_SQRT_D);
    }
}

// ---------------- user transformed vectors ----------------
__global__ __launch_bounds__(256) void user_vecs(const float* __restrict__ u_emb,
                                                 const float* __restrict__ lit_tab, const int* __restrict__ g_li,
                                                 const float* __restrict__ lut_tab, const int* __restrict__ g_lu,
                                                 const __bf16* __restrict__ M2t, const __bf16* __restrict__ M3t,
                                                 const __bf16* __restrict__ M4t,
                                                 __bf16* __restrict__ um_t, __bf16* __restrict__ li_t,
                                                 __bf16* __restrict__ lu_t, int rows) {
    int lane = threadIdx.x & 63;
    int wave = threadIdx.x >> 6;
    int row0 = blockIdx.x * 64 + wave * 16;
    if (row0 >= rows) return;
    int l16 = lane & 15, kh = lane >> 4;
    int ar = row0 + l16;
    int arc = ar < rows ? ar : rows - 1;
    const float* rA = u_emb + (size_t)arc * D_;
    const float* rB = lit_tab + (size_t)g_li[arc] * D_;
    const float* rC = lut_tab + (size_t)g_lu[arc] * D_;

    f32x4 aA[8] = {}, aB[8] = {}, aC[8] = {};
#pragma unroll
    for (int k0 = 0; k0 < D_; k0 += 32) {
        int kk = k0 + kh * 8;
        float4 a0 = *(const float4*)(rA + kk), a1 = *(const float4*)(rA + kk + 4);
        float4 b0 = *(const float4*)(rB + kk), b1 = *(const float4*)(rB + kk + 4);
        float4 c0 = *(const float4*)(rC + kk), c1 = *(const float4*)(rC + kk + 4);
        bf16x8 fA, fB, fC;
        fA[0]=(__bf16)a0.x; fA[1]=(__bf16)a0.y; fA[2]=(__bf16)a0.z; fA[3]=(__bf16)a0.w;
        fA[4]=(__bf16)a1.x; fA[5]=(__bf16)a1.y; fA[6]=(__bf16)a1.z; fA[7]=(__bf16)a1.w;
        fB[0]=(__bf16)b0.x; fB[1]=(__bf16)b0.y; fB[2]=(__bf16)b0.z; fB[3]=(__bf16)b0.w;
        fB[4]=(__bf16)b1.x; fB[5]=(__bf16)b1.y; fB[6]=(__bf16)b1.z; fB[7]=(__bf16)b1.w;
        fC[0]=(__bf16)c0.x; fC[1]=(__bf16)c0.y; fC[2]=(__bf16)c0.z; fC[3]=(__bf16)c0.w;
        fC[4]=(__bf16)c1.x; fC[5]=(__bf16)c1.y; fC[6]=(__bf16)c1.z; fC[7]=(__bf16)c1.w;
#pragma unroll
        for (int cb = 0; cb < 8; cb++) {
            bf16x8 w2 = *(const bf16x8*)(M2t + (size_t)(cb * 16 + l16) * D_ + kk);
            aA[cb] = __builtin_amdgcn_mfma_f32_16x16x32_bf16(fA, w2, aA[cb], 0, 0, 0);
            bf16x8 w3 = *(const bf16x8*)(M3t + (size_t)(cb * 16 + l16) * D_ + kk);
            aB[cb] = __builtin_amdgcn_mfma_f32_16x16x32_bf16(fB, w3, aB[cb], 0, 0, 0);
            bf16x8 w4 = *(const bf16x8*)(M4t + (size_t)(cb * 16 + l16) * D_ + kk);
            aC[cb] = __builtin_amdgcn_mfma_f32_16x16x32_bf16(fC, w4, aC[cb], 0, 0, 0);
        }
    }
#pragma unroll
    for (int cb = 0; cb < 8; cb++) {
#pragma unroll
        for (int j = 0; j < 4; j++) {
            int r = row0 + kh * 4 + j;
            if (r < rows) {
                um_t[(size_t)r * D_ + cb * 16 + l16] = (__bf16)aA[cb][j];
                li_t[(size_t)r * D_ + cb * 16 + l16] = (__bf16)aB[cb][j];
                lu_t[(size_t)r * D_ + cb * 16 + l16] = (__bf16)aC[cb][j];
            }
        }
    }
}

// ---------------- small GEMM: Y(rows x ncols f32) = Xb @ P^T (scale prefolded in P) ----------------
__global__ __launch_bounds__(256) void gemm_pvk(const __bf16* __restrict__ Xb,
                                                const __bf16* __restrict__ Pb,
                                                float* __restrict__ Y, int rows, int ncols) {
    int lane = threadIdx.x & 63;
    int wave = threadIdx.x >> 6;
    int row0 = blockIdx.x * 64 + wave * 16;
    if (row0 >= rows) return;
    int l16 = lane & 15, kh = lane >> 4;
    int ar = row0 + l16;
    int arc = ar < rows ? ar : rows - 1;
    const __bf16* arow = Xb + (size_t)arc * D_;

    f32x4 acc[4] = {};
#pragma unroll
    for (int k0 = 0; k0 < D_; k0 += 32) {
        int kk = k0 + kh * 8;
        bf16x8 af = *(const bf16x8*)(arow + kk);
#pragma unroll
        for (int cb = 0; cb < 4; cb++) {
            int br = cb * 16 + l16;
            if (br >= ncols) br = ncols - 1;
            bf16x8 bf = *(const bf16x8*)(Pb + (size_t)br * D_ + kk);
            acc[cb] = __builtin_amdgcn_mfma_f32_16x16x32_bf16(af, bf, acc[cb], 0, 0, 0);
        }
    }
#pragma unroll
    for (int cb = 0; cb < 4; cb++) {
        int col = cb * 16 + l16;
        if (col >= ncols) continue;
#pragma unroll
        for (int j = 0; j < 4; j++) {
            int r = row0 + kh * 4 + j;
            if (r < rows) Y[(size_t)r * ncols + col] = acc[cb][j];
        }
    }
}

// ---------------- CSR build ----------------
__global__ __launch_bounds__(256) void hist2(const int* __restrict__ eu, const int* __restrict__ ei,
                                             int* __restrict__ cnt_all, int nu, int E) {
    int e = blockIdx.x * 256 + threadIdx.x;
    if (e < E) {
        atomicAdd(&cnt_all[eu[e]], 1);
        atomicAdd(&cnt_all[nu + ei[e]], 1);
    }
}

__global__ __launch_bounds__(256) void scan_phaseA(const int* __restrict__ cnt, int* __restrict__ part, int n) {
    __shared__ int wsum[4];
    int t = threadIdx.x, lane = t & 63, w = t >> 6;
    int i0 = blockIdx.x * SCAN_TILE + t * SCAN_CH;
    int tot = 0;
#pragma unroll
    for (int j = 0; j < SCAN_CH; j++) tot += (i0 + j < n) ? cnt[i0 + j] : 0;
#pragma unroll
    for (int d = 32; d; d >>= 1) tot += __shfl_xor(tot, d);
    if (lane == 0) wsum[w] = tot;
    __syncthreads();
    if (t == 0) part[blockIdx.x] = wsum[0] + wsum[1] + wsum[2] + wsum[3];
}

__global__ __launch_bounds__(1024) void scan_phaseB(int* __restrict__ part, int nb,
                                                    int* __restrict__ off, int n) {
    __shared__ int wsum[16];
    int t = threadIdx.x, lane = t & 63, w = t >> 6;
    int v = (t < nb) ? part[t] : 0;
    int x = v;
#pragma unroll
    for (int d = 1; d < 64; d <<= 1) {
        int y = __shfl_up(x, d);
        if (lane >= d) x += y;
    }
    if (lane == 63) wsum[w] = x;
    __syncthreads();
    int wbase = 0;
    for (int ww = 0; ww < w; ww++) wbase += wsum[ww];
    if (t < nb) part[t] = wbase + x - v;
    if (t == 1023) off[n] = wbase + x;
}

__global__ __launch_bounds__(256) void scan_phaseC(const int* __restrict__ cnt, const int* __restrict__ part,
                                                   int* __restrict__ off, int* __restrict__ pos, int n) {
    __shared__ int wsum[4];
    int t = threadIdx.x, lane = t & 63, w = t >> 6;
    int i0 = blockIdx.x * SCAN_TILE + t * SCAN_CH;
    int loc[SCAN_CH];
    int tot = 0;
#pragma unroll
    for (int j = 0; j < SCAN_CH; j++) {
        int v = (i0 + j < n) ? cnt[i0 + j] : 0;
        loc[j] = tot; tot += v;
    }
    int x = tot;
#pragma unroll
    for (int d = 1; d < 64; d <<= 1) {
        int y = __shfl_up(x, d);
        if (lane >= d) x += y;
    }
    if (lane == 63) wsum[w] = x;
    __syncthreads();
    int wbase = 0;
    for (int ww = 0; ww < w; ww++) wbase += wsum[ww];
    int excl = part[blockIdx.x] + wbase + x - tot;
#pragma unroll
    for (int j = 0; j < SCAN_CH; j++) {
        if (i0 + j < n) { off[i0 + j] = excl + loc[j]; pos[i0 + j] = excl + loc[j]; }
    }
}

__global__ __launch_bounds__(256) void scatter2(const int* __restrict__ eu, const int* __restrict__ ei,
                                                const int* __restrict__ rui, const int* __restrict__ riu,
                                                int* __restrict__ pos_all, int4* __restrict__ recs,
                                                int nu, int E) {
    int e = blockIdx.x * 256 + threadIdx.x;
    if (e < E) {
        int u = eu[e], it = ei[e], r1 = rui[e], r2 = riu[e];
        int pi = atomicAdd(&pos_all[nu + it], 1);
        int pu = atomicAdd(&pos_all[u], 1);
        recs[pu] = make_int4(it, r1, r2, pi);
        recs[pi] = make_int4(u, r1, r2, 0);
    }
}

// ---------------- user pass ----------------
__global__ __launch_bounds__(256) void user_pass(const int* __restrict__ off_all, const int4* __restrict__ recs,
                                                 const __bf16* __restrict__ ib_emb,
                                                 const __bf16* __restrict__ um_t,
                                                 const __bf16* __restrict__ li_t,
                                                 const __bf16* __restrict__ lu_t,
                                                 const __bf16* __restrict__ pKb,
                                                 const float* __restrict__ upv,
                                                 float2* __restrict__ mb_val,
                                                 __bf16* __restrict__ A1n, __bf16* __restrict__ PKn,
                                                 __bf16* __restrict__ A2n, int nu, int umax) {
    int u = blockIdx.x * 4 + (threadIdx.x >> 6);
    if (u >= nu) return;
    int lane = threadIdx.x & 63;
    int g = lane >> 4, l16 = lane & 15;
    int off = off_all[u], n = off_all[u + 1] - off;
    if (n == 0) {
        if (lane < 16) {
            bf16x8 z = {};
            *(bf16x8*)(A1n + (size_t)u * D_ + l16 * 8) = z;
            *(bf16x8*)(PKn + (size_t)u * D_ + l16 * 8) = z;
            *(bf16x8*)(A2n + (size_t)u * D_ + l16 * 8) = z;
        }
        return;
    }
    float um8[8], li8[8], lu8[8];
    unpack8(((const bf16x8*)(um_t + (size_t)u * D_))[l16], um8);
    unpack8(((const bf16x8*)(li_t + (size_t)u * D_))[l16], li8);
    unpack8(((const bf16x8*)(lu_t + (size_t)u * D_))[l16], lu8);
    const float* upv_row = upv + (size_t)u * umax;

    float s1 = 0.f, s2 = 0.f, a1[8] = {}, apk[8] = {}, a2[8] = {};
    for (int i = g; i < n; i += 8) {
        int4 ra = recs[off + i];
        bool hb = (i + 4) < n;
        int4 rb = recs[off + (hb ? i + 4 : i)];
        bf16x8 vieA = ((const bf16x8*)(ib_emb + (size_t)ra.x * D_))[l16];
        bf16x8 vpkA = ((const bf16x8*)(pKb + (size_t)ra.z * D_))[l16];
        bf16x8 vieB = ((const bf16x8*)(ib_emb + (size_t)rb.x * D_))[l16];
        bf16x8 vpkB = ((const bf16x8*)(pKb + (size_t)rb.z * D_))[l16];
        float fieA[8], fpkA[8], fieB[8], fpkB[8];
        unpack8(vieA, fieA); unpack8(vpkA, fpkA);
        unpack8(vieB, fieB); unpack8(vpkB, fpkB);
        float d1a = 0.f, d2a = 0.f, d3a = 0.f, d1b = 0.f, d2b = 0.f, d3b = 0.f;
#pragma unroll
        for (int j = 0; j < 8; j++) {
            d1a = fmaf(um8[j], fieA[j], d1a);
            d2a = fmaf(li8[j], fieA[j], d2a);
            d3a = fmaf(lu8[j], fieA[j], d3a);
            d1b = fmaf(um8[j], fieB[j], d1b);
            d2b = fmaf(li8[j], fieB[j], d2b);
            d3b = fmaf(lu8[j], fieB[j], d3b);
        }
#pragma unroll
        for (int d = 1; d < 16; d <<= 1) {
            d1a += __shfl_xor(d1a, d); d2a += __shfl_xor(d2a, d); d3a += __shfl_xor(d3a, d);
            d1b += __shfl_xor(d1b, d); d2b += __shfl_xor(d2b, d); d3b += __shfl_xor(d3b, d);
        }
        if (l16 == 0) {
            mb_val[ra.w] = make_float2(d1a, d3a);
            if (hb) mb_val[rb.w] = make_float2(d1b, d3b);
        }
        float w1a = __expf(d1a + upv_row[ra.y]);
        float w2a = __expf(d2a);
        float w1b = hb ? __expf(d1b + upv_row[rb.y]) : 0.f;
        float w2b = hb ? __expf(d2b) : 0.f;
        s1 += w1a + w1b; s2 += w2a + w2b;
#pragma unroll
        for (int j = 0; j < 8; j++) {
            a1[j]  = fmaf(w1a, fieA[j], fmaf(w1b, fieB[j], a1[j]));
            apk[j] = fmaf(w1a, fpkA[j], fmaf(w1b, fpkB[j], apk[j]));
            a2[j]  = fmaf(w2a, fieA[j], fmaf(w2b, fieB[j], a2[j]));
        }
    }
#pragma unroll
    for (int d = 16; d < 64; d <<= 1) {
        s1 += __shfl_xor(s1, d); s2 += __shfl_xor(s2, d);
#pragma unroll
        for (int j = 0; j < 8; j++) {
            a1[j]  += __shfl_xor(a1[j], d);
            apk[j] += __shfl_xor(apk[j], d);
            a2[j]  += __shfl_xor(a2[j], d);
        }
    }
    if (lane < 16) {
        float inv1 = 1.f / s1, inv2 = 1.f / s2;
        *(bf16x8*)(A1n + (size_t)u * D_ + l16 * 8) = pack8(a1, inv1);
        *(bf16x8*)(PKn + (size_t)u * D_ + l16 * 8) = pack8(apk, inv1);
        *(bf16x8*)(A2n + (size_t)u * D_ + l16 * 8) = pack8(a2, inv2);
    }
}

// ---------------- item pass ----------------
__global__ __launch_bounds__(256) void item_pass(const int* __restrict__ off_all, const int4* __restrict__ recs,
                                                 const __bf16* __restrict__ ub_emb,
                                                 const __bf16* __restrict__ pVb,
                                                 const float* __restrict__ ipk,
                                                 const float2* __restrict__ mb_val,
                                                 __bf16* __restrict__ B1n, __bf16* __restrict__ PVn,
                                                 __bf16* __restrict__ B2n, int nu, int ni, int imax) {
    int it = blockIdx.x * 4 + (threadIdx.x >> 6);
    if (it >= ni) return;
    int lane = threadIdx.x & 63;
    int g = lane >> 4, l16 = lane & 15;
    int off = off_all[nu + it], n = off_all[nu + it + 1] - off;
    if (n == 0) {
        if (lane < 16) {
            bf16x8 z = {};
            *(bf16x8*)(B1n + (size_t)it * D_ + l16 * 8) = z;
            *(bf16x8*)(PVn + (size_t)it * D_ + l16 * 8) = z;
            *(bf16x8*)(B2n + (size_t)it * D_ + l16 * 8) = z;
        }
        return;
    }
    const float* ipk_row = ipk + (size_t)it * imax;

    float s1 = 0.f, s2 = 0.f, b1[8] = {}, bpv[8] = {}, b2[8] = {};
    for (int i = g; i < n; i += 8) {
        int4 ra = recs[off + i];
        bool hb = (i + 4) < n;
        int4 rb = recs[off + (hb ? i + 4 : i)];
        float2 ma = mb_val[off + i];
        float2 mbv = hb ? mb_val[off + i + 4] : make_float2(0.f, 0.f);
        bf16x8 vueA = ((const bf16x8*)(ub_emb + (size_t)ra.x * D_))[l16];
        bf16x8 vpvA = ((const bf16x8*)(pVb + (size_t)ra.y * D_))[l16];
        bf16x8 vueB = ((const bf16x8*)(ub_emb + (size_t)rb.x * D_))[l16];
        bf16x8 vpvB = ((const bf16x8*)(pVb + (size_t)rb.y * D_))[l16];
        float fueA[8], fpvA[8], fueB[8], fpvB[8];
        unpack8(vueA, fueA); unpack8(vpvA, fpvA);
        unpack8(vueB, fueB); unpack8(vpvB, fpvB);
        float w1a = __expf(ma.x + ipk_row[ra.z]);
        float w2a = __expf(ma.y);
        float w1b = hb ? __expf(mbv.x + ipk_row[rb.z]) : 0.f;
        float w2b = hb ? __expf(mbv.y) : 0.f;
        s1 += w1a + w1b; s2 += w2a + w2b;
#pragma unroll
        for (int j = 0; j < 8; j++) {
            b1[j]  = fmaf(w1a, fueA[j], fmaf(w1b, fueB[j], b1[j]));
            bpv[j] = fmaf(w1a, fpvA[j], fmaf(w1b, fpvB[j], bpv[j]));
            b2[j]  = fmaf(w2a, fueA[j], fmaf(w2b, fueB[j], b2[j]));
        }
    }
#pragma unroll
    for (int d = 16; d < 64; d <<= 1) {
        s1 += __shfl_xor(s1, d); s2 += __shfl_xor(s2, d);
#pragma unroll
        for (int j = 0; j < 8; j++) {
            b1[j]  += __shfl_xor(b1[j], d);
            bpv[j] += __shfl_xor(bpv[j], d);
            b2[j]  += __shfl_xor(b2[j], d);
        }
    }
    if (lane < 16) {
        float inv1 = 1.f / s1, inv2 = 1.f / s2;
        *(bf16x8*)(B1n + (size_t)it * D_ + l16 * 8) = pack8(b1, inv1);
        *(bf16x8*)(PVn + (size_t)it * D_ + l16 * 8) = pack8(bpv, inv1);
        *(bf16x8*)(B2n + (size_t)it * D_ + l16 * 8) = pack8(b2, inv2);
    }
}

// ---------------- finish GEMM: out = A@W^T + (side ? side : 1[n>0]) ----------------
// W staged in LDS (padded rows), wave-private output staging, 256 rows/block.
__global__ __launch_bounds__(256) void finish1(const __bf16* __restrict__ A, const __bf16* __restrict__ Wsrc,
                                               const __bf16* __restrict__ side, const int* __restrict__ offseg,
                                               float* __restrict__ out, int rows) {
    __shared__ __bf16 sW[128][136];
    __shared__ float stg[4][16][132];
    int t = threadIdx.x;
    // cooperative weight load: 128x128 bf16, 16B per slot, 2048 slots
#pragma unroll
    for (int it = 0; it < 8; it++) {
        int slot = it * 256 + t;
        int r = slot >> 4, c16 = (slot & 15) * 8;
        bf16x8 v = *(const bf16x8*)(Wsrc + (size_t)r * D_ + c16);
        *(bf16x8*)(&sW[r][c16]) = v;
    }
    __syncthreads();
    int lane = t & 63, wave = t >> 6;
    int l16 = lane & 15, kh = lane >> 4;
    int hw = lane >> 5, c4 = (lane & 31) * 4;

    for (int tt = 0; tt < 4; tt++) {
        int row0 = blockIdx.x * 256 + (tt * 4 + wave) * 16;
        if (row0 >= rows) break;
        int ar = row0 + l16;
        int arc = ar < rows ? ar : rows - 1;
        const __bf16* rA = A + (size_t)arc * D_;
        bf16x8 a0 = *(const bf16x8*)(rA + kh * 8);
        bf16x8 a1 = *(const bf16x8*)(rA + 32 + kh * 8);
        bf16x8 a2 = *(const bf16x8*)(rA + 64 + kh * 8);
        bf16x8 a3 = *(const bf16x8*)(rA + 96 + kh * 8);
        f32x4 acc[8] = {};
#pragma unroll
        for (int cb = 0; cb < 8; cb++) {
            int wr = cb * 16 + l16;
            acc[cb] = __builtin_amdgcn_mfma_f32_16x16x32_bf16(a0, *(const bf16x8*)(&sW[wr][kh * 8]), acc[cb], 0, 0, 0);
            acc[cb] = __builtin_amdgcn_mfma_f32_16x16x32_bf16(a1, *(const bf16x8*)(&sW[wr][32 + kh * 8]), acc[cb], 0, 0, 0);
            acc[cb] = __builtin_amdgcn_mfma_f32_16x16x32_bf16(a2, *(const bf16x8*)(&sW[wr][64 + kh * 8]), acc[cb], 0, 0, 0);
            acc[cb] = __builtin_amdgcn_mfma_f32_16x16x32_bf16(a3, *(const bf16x8*)(&sW[wr][96 + kh * 8]), acc[cb], 0, 0, 0);
        }
        // wave-private transpose staging (no block barrier needed)
#pragma unroll
        for (int cb = 0; cb < 8; cb++)
#pragma unroll
            for (int j = 0; j < 4; j++)
                stg[wave][kh * 4 + j][cb * 16 + l16] = acc[cb][j];
#pragma unroll
        for (int k = 0; k < 8; k++) {
            int wr = hw + k * 2;
            int rg = row0 + wr;
            if (rg < rows) {
                float4 v = *(const float4*)&stg[wave][wr][c4];
                if (side) {
                    ushort4 sv = *(const ushort4*)((const unsigned short*)side + (size_t)rg * D_ + c4);
                    v.x += __uint_as_float((uint32_t)sv.x << 16);
                    v.y += __uint_as_float((uint32_t)sv.y << 16);
                    v.z += __uint_as_float((uint32_t)sv.z << 16);
                    v.w += __uint_as_float((uint32_t)sv.w << 16);
                } else {
                    float one = (offseg[rg + 1] - offseg[rg]) > 0 ? 1.f : 0.f;
                    v.x += one; v.y += one; v.z += one; v.w += one;
                }
                *(float4*)(out + (size_t)rg * D_ + c4) = v;
            }
        }
    }
}

extern "C" void kernel_launch(void* const* d_in, const int* in_sizes, int n_in,
                              void* d_out, int out_size, void* d_ws, size_t ws_size,
                              hipStream_t stream) {
    (void)n_in; (void)out_size; (void)ws_size;
    const float* u_emb = (const float*)d_in[0];
    const float* i_emb = (const float*)d_in[1];
    const int* edge_u = (const int*)d_in[2];
    const int* edge_i = (const int*)d_in[3];
    const int* rui = (const int*)d_in[4];
    const int* riu = (const int*)d_in[5];
    const int* last_u_items = (const int*)d_in[6];
    const int* last_i_users = (const int*)d_in[7];
    const float* W1  = (const float*)d_in[8];
    const float* W2  = (const float*)d_in[9];
    const float* W1b = (const float*)d_in[10];
    const float* W2b = (const float*)d_in[11];
    const float* W3  = (const float*)d_in[12];
    const float* W4  = (const float*)d_in[13];
    const float* pV  = (const float*)d_in[14];
    const float* pK  = (const float*)d_in[15];
    const float* last_user_table = (const float*)d_in[16];
    const float* last_item_table = (const float*)d_in[17];

    const int NU = in_sizes[0] / D_;
    const int NI = in_sizes[1] / D_;
    const int E  = in_sizes[2];
    const int UMAXr = in_sizes[14] / D_;
    const int IMAXr = in_sizes[15] / D_;
    const int NSEG = NU + NI;

    size_t cur = 0;
    auto alloc = [&](size_t bytes) -> void* {
        void* p = (char*)d_ws + cur;
        cur += (bytes + 255) & ~(size_t)255;
        return p;
    };

    __bf16* Wb4   = (__bf16*)alloc(4 * 16384 * 2);          // W1, W2, W1b, W2b bf16
    __bf16* M2t   = (__bf16*)alloc(16384 * 2);
    __bf16* M3t   = (__bf16*)alloc(16384 * 2);
    __bf16* M4t   = (__bf16*)alloc(16384 * 2);
    __bf16* pVW2  = (__bf16*)alloc((size_t)UMAXr * D_ * 2);
    __bf16* pKW1  = (__bf16*)alloc((size_t)IMAXr * D_ * 2);
    __bf16* pVb   = (__bf16*)alloc((size_t)UMAXr * D_ * 2);
    __bf16* pKb   = (__bf16*)alloc((size_t)IMAXr * D_ * 2);
    __bf16* ub_emb = (__bf16*)alloc((size_t)NU * D_ * 2);
    __bf16* ib_emb = (__bf16*)alloc((size_t)NI * D_ * 2);
    __bf16* um_t  = (__bf16*)alloc((size_t)NU * D_ * 2);
    __bf16* li_t  = (__bf16*)alloc((size_t)NU * D_ * 2);
    __bf16* lu_t  = (__bf16*)alloc((size_t)NU * D_ * 2);
    float* upv    = (float*)alloc((size_t)NU * UMAXr * 4);
    float* ipk    = (float*)alloc((size_t)NI * IMAXr * 4);
    __bf16* A1n   = (__bf16*)alloc((size_t)NU * D_ * 2);
    __bf16* PKn   = (__bf16*)alloc((size_t)NU * D_ * 2);
    __bf16* A2n   = (__bf16*)alloc((size_t)NU * D_ * 2);
    __bf16* B1n   = (__bf16*)alloc((size_t)NI * D_ * 2);
    __bf16* PVn   = (__bf16*)alloc((size_t)NI * D_ * 2);
    __bf16* B2n   = (__bf16*)alloc((size_t)NI * D_ * 2);
    float2* mb_val = (float2*)alloc((size_t)2 * E * 8);
    int4* recs    = (int4*)alloc((size_t)2 * E * 16);
    int* cnt_all  = (int*)alloc((size_t)NSEG * 4);
    int* off_all  = (int*)alloc((size_t)(NSEG + 1) * 4);
    int* pos_all  = (int*)alloc((size_t)NSEG * 4);
    int* parts    = (int*)alloc(1024 * 4);

    float* out = (float*)d_out;
    float* hLu = out;
    float* hSu = out + (size_t)NU * D_;
    float* hLi = out + (size_t)2 * NU * D_;
    float* hSi = out + (size_t)2 * NU * D_ + (size_t)NI * D_;

    // weight casts + combined matrices
    W4p w4; w4.p[0] = W1; w4.p[1] = W2; w4.p[2] = W1b; w4.p[3] = W2b;
    cvt_weights4<<<(4 * 16384 + 255) / 256, 256, 0, stream>>>(w4, Wb4);
    prep_mats<<<128 + (UMAXr > IMAXr ? UMAXr : IMAXr), 128, 0, stream>>>(W1, W2, W3, W4, pV, pK,
                                                                         M2t, M3t, M4t, pVW2, pKW1, UMAXr, IMAXr);
    cvt2<<<(UMAXr * D_ + 255) / 256, 256, 0, stream>>>(pV, pK, pVb, pKb, UMAXr * D_);
    size_t nue = (size_t)NU * D_, nie = (size_t)NI * D_;
    cvt_emb<<<(int)(((nue + nie) / 4 + 255) / 256), 256, 0, stream>>>(u_emb, i_emb, ub_emb, ib_emb, nue, nie);

    // CSR build
    hipMemsetAsync(cnt_all, 0, (size_t)NSEG * 4, stream);
    hist2<<<(E + 255) / 256, 256, 0, stream>>>(edge_u, edge_i, cnt_all, NU, E);
    int nb = (NSEG + SCAN_TILE - 1) / SCAN_TILE;
    scan_phaseA<<<nb, 256, 0, stream>>>(cnt_all, parts, NSEG);
    scan_phaseB<<<1, 1024, 0, stream>>>(parts, nb, off_all, NSEG);
    scan_phaseC<<<nb, 256, 0, stream>>>(cnt_all, parts, off_all, pos_all, NSEG);
    scatter2<<<(E + 255) / 256, 256, 0, stream>>>(edge_u, edge_i, rui, riu, pos_all, recs, NU, E);

    // transformed user vectors + positional dot tables
    int gu = (NU + 63) / 64, gi = (NI + 63) / 64;
    user_vecs<<<gu, 256, 0, stream>>>(u_emb, last_item_table, last_u_items, last_user_table, last_i_users,
                                      M2t, M3t, M4t, um_t, li_t, lu_t, NU);
    gemm_pvk<<<gu, 256, 0, stream>>>(ub_emb, pVW2, upv, NU, UMAXr);
    gemm_pvk<<<gi, 256, 0, stream>>>(ib_emb, pKW1, ipk, NI, IMAXr);

    // edge passes
    user_pass<<<(NU + 3) / 4, 256, 0, stream>>>(off_all, recs, ib_emb, um_t, li_t, lu_t,
                                                pKb, upv, mb_val, A1n, PKn, A2n, NU, UMAXr);
    item_pass<<<(NI + 3) / 4, 256, 0, stream>>>(off_all, recs, ub_emb, pVb, ipk, mb_val,
                                                B1n, PVn, B2n, NU, NI, IMAXr);

    // finish projections (weights LDS-staged, one output per launch):
    int fu = (NU + 255) / 256, fi = (NI + 255) / 256;
    finish1<<<fu, 256, 0, stream>>>(A1n, Wb4 + 2 * 16384, PKn, nullptr, hLu, NU);          // hLu = A1@W1b^T + PKn
    finish1<<<fu, 256, 0, stream>>>(A2n, Wb4 + 0 * 16384, nullptr, off_all, hSu, NU);      // hSu = A2@W1^T + 1
    finish1<<<fi, 256, 0, stream>>>(B1n, Wb4 + 3 * 16384, PVn, nullptr, hLi, NI);          // hLi = B1@W2b^T + PVn
    finish1<<<fi, 256, 0, stream>>>(B2n, Wb4 + 1 * 16384, nullptr, off_all + NU, hSi, NI); // hSi = B2@W2^T + 1
}

// Round 10
// 541.213 us; speedup vs baseline: 1.1027x; 1.0299x over previous
//
#include <hip/hip_runtime.h>
#include <hip/hip_bf16.h>
#include <math.h>

#define D_ 128
#define INV_SQRT_D 0.08838834764831845f
#define SCAN_CH 16
#define SCAN_TILE (256 * SCAN_CH)

typedef __bf16 bf16x8 __attribute__((ext_vector_type(8)));
typedef float f32x4 __attribute__((ext_vector_type(4)));

struct W4p { const float* p[4]; };

__device__ __forceinline__ void unpack8(bf16x8 v, float* f) {
    const uint32_t* u = (const uint32_t*)&v;
#pragma unroll
    for (int i = 0; i < 4; i++) {
        uint32_t w = u[i];
        f[2 * i]     = __uint_as_float(w << 16);
        f[2 * i + 1] = __uint_as_float(w & 0xffff0000u);
    }
}

__device__ __forceinline__ bf16x8 pack8(const float* f, float s) {
    bf16x8 r;
#pragma unroll
    for (int j = 0; j < 8; j++) r[j] = (__bf16)(f[j] * s);
    return r;
}

// ---------------- casts: weights + pV/pK in one kernel ----------------
__global__ __launch_bounds__(256) void cvt_small(W4p w, const float* __restrict__ pV, const float* __restrict__ pK,
                                                 __bf16* __restrict__ outW, __bf16* __restrict__ pVb,
                                                 __bf16* __restrict__ pKb, int npv, int npk) {
    int idx = blockIdx.x * 256 + threadIdx.x;
    if (idx < 4 * 16384) {
        outW[idx] = (__bf16)w.p[idx >> 14][idx & 16383];
    } else if (idx - 4 * 16384 < npv) {
        int j = idx - 4 * 16384;
        pVb[j] = (__bf16)pV[j];
    } else if (idx - 4 * 16384 - npv < npk) {
        int j = idx - 4 * 16384 - npv;
        pKb[j] = (__bf16)pK[j];
    }
}

__global__ __launch_bounds__(256) void cvt_emb(const float* __restrict__ u, const float* __restrict__ i,
                                               __bf16* __restrict__ ub, __bf16* __restrict__ ib,
                                               size_t nue, size_t nie) {
    size_t idx4 = ((size_t)blockIdx.x * 256 + threadIdx.x) * 4;
    if (idx4 < nue) {
        float4 v = *(const float4*)(u + idx4);
        ub[idx4] = (__bf16)v.x; ub[idx4+1] = (__bf16)v.y; ub[idx4+2] = (__bf16)v.z; ub[idx4+3] = (__bf16)v.w;
    } else if (idx4 < nue + nie) {
        size_t j = idx4 - nue;
        float4 v = *(const float4*)(i + j);
        ib[j] = (__bf16)v.x; ib[j+1] = (__bf16)v.y; ib[j+2] = (__bf16)v.z; ib[j+3] = (__bf16)v.w;
    }
}

// ---------------- combined-matrix prep ----------------
__global__ __launch_bounds__(128) void prep_mats(const float* __restrict__ W1, const float* __restrict__ W2,
                                                 const float* __restrict__ W3, const float* __restrict__ W4,
                                                 const float* __restrict__ pV, const float* __restrict__ pK,
                                                 __bf16* __restrict__ M2t, __bf16* __restrict__ M3t,
                                                 __bf16* __restrict__ M4t,
                                                 __bf16* __restrict__ pVW2, __bf16* __restrict__ pKW1,
                                                 int umax, int imax) {
    __shared__ float sh[256];
    int b = blockIdx.x, t = threadIdx.x;
    if (b < 128) {
        sh[t] = W1[t * 128 + b];
        __syncthreads();
        float m2 = 0.f, m3 = 0.f, m4 = 0.f;
        for (int k = 0; k < 128; k++) {
            float w = sh[k];
            m2 = fmaf(w, W2[k * 128 + t], m2);
            m3 = fmaf(w, W3[k * 128 + t], m3);
            m4 = fmaf(w, W4[k * 128 + t], m4);
        }
        M2t[b * 128 + t] = (__bf16)(m2 * INV_SQRT_D);
        M3t[b * 128 + t] = (__bf16)(m3 * INV_SQRT_D);
        M4t[b * 128 + t] = (__bf16)(m4 * INV_SQRT_D);
    } else {
        int r = b - 128;
        if (r < umax) sh[t] = pV[r * 128 + t];
        if (r < imax) sh[128 + t] = pK[r * 128 + t];
        __syncthreads();
        float q = 0.f, qk = 0.f;
        for (int a = 0; a < 128; a++) {
            if (r < umax) q  = fmaf(sh[a], W2[a * 128 + t], q);
            if (r < imax) qk = fmaf(sh[128 + a], W1[a * 128 + t], qk);
        }
        if (r < umax) pVW2[r * 128 + t] = (__bf16)(q * INV_SQRT_D);
        if (r < imax) pKW1[r * 128 + t] = (__bf16)(qk * INV_SQRT_D);
    }
}

// ---------------- user transformed vectors ----------------
__global__ __launch_bounds__(256) void user_vecs(const float* __restrict__ u_emb,
                                                 const float* __restrict__ lit_tab, const int* __restrict__ g_li,
                                                 const float* __restrict__ lut_tab, const int* __restrict__ g_lu,
                                                 const __bf16* __restrict__ M2t, const __bf16* __restrict__ M3t,
                                                 const __bf16* __restrict__ M4t,
                                                 __bf16* __restrict__ um_t, __bf16* __restrict__ li_t,
                                                 __bf16* __restrict__ lu_t, int rows) {
    int lane = threadIdx.x & 63;
    int wave = threadIdx.x >> 6;
    int row0 = blockIdx.x * 64 + wave * 16;
    if (row0 >= rows) return;
    int l16 = lane & 15, kh = lane >> 4;
    int ar = row0 + l16;
    int arc = ar < rows ? ar : rows - 1;
    const float* rA = u_emb + (size_t)arc * D_;
    const float* rB = lit_tab + (size_t)g_li[arc] * D_;
    const float* rC = lut_tab + (size_t)g_lu[arc] * D_;

    f32x4 aA[8] = {}, aB[8] = {}, aC[8] = {};
#pragma unroll
    for (int k0 = 0; k0 < D_; k0 += 32) {
        int kk = k0 + kh * 8;
        float4 a0 = *(const float4*)(rA + kk), a1 = *(const float4*)(rA + kk + 4);
        float4 b0 = *(const float4*)(rB + kk), b1 = *(const float4*)(rB + kk + 4);
        float4 c0 = *(const float4*)(rC + kk), c1 = *(const float4*)(rC + kk + 4);
        bf16x8 fA, fB, fC;
        fA[0]=(__bf16)a0.x; fA[1]=(__bf16)a0.y; fA[2]=(__bf16)a0.z; fA[3]=(__bf16)a0.w;
        fA[4]=(__bf16)a1.x; fA[5]=(__bf16)a1.y; fA[6]=(__bf16)a1.z; fA[7]=(__bf16)a1.w;
        fB[0]=(__bf16)b0.x; fB[1]=(__bf16)b0.y; fB[2]=(__bf16)b0.z; fB[3]=(__bf16)b0.w;
        fB[4]=(__bf16)b1.x; fB[5]=(__bf16)b1.y; fB[6]=(__bf16)b1.z; fB[7]=(__bf16)b1.w;
        fC[0]=(__bf16)c0.x; fC[1]=(__bf16)c0.y; fC[2]=(__bf16)c0.z; fC[3]=(__bf16)c0.w;
        fC[4]=(__bf16)c1.x; fC[5]=(__bf16)c1.y; fC[6]=(__bf16)c1.z; fC[7]=(__bf16)c1.w;
#pragma unroll
        for (int cb = 0; cb < 8; cb++) {
            bf16x8 w2 = *(const bf16x8*)(M2t + (size_t)(cb * 16 + l16) * D_ + kk);
            aA[cb] = __builtin_amdgcn_mfma_f32_16x16x32_bf16(fA, w2, aA[cb], 0, 0, 0);
            bf16x8 w3 = *(const bf16x8*)(M3t + (size_t)(cb * 16 + l16) * D_ + kk);
            aB[cb] = __builtin_amdgcn_mfma_f32_16x16x32_bf16(fB, w3, aB[cb], 0, 0, 0);
            bf16x8 w4 = *(const bf16x8*)(M4t + (size_t)(cb * 16 + l16) * D_ + kk);
            aC[cb] = __builtin_amdgcn_mfma_f32_16x16x32_bf16(fC, w4, aC[cb], 0, 0, 0);
        }
    }
#pragma unroll
    for (int cb = 0; cb < 8; cb++) {
#pragma unroll
        for (int j = 0; j < 4; j++) {
            int r = row0 + kh * 4 + j;
            if (r < rows) {
                um_t[(size_t)r * D_ + cb * 16 + l16] = (__bf16)aA[cb][j];
                li_t[(size_t)r * D_ + cb * 16 + l16] = (__bf16)aB[cb][j];
                lu_t[(size_t)r * D_ + cb * 16 + l16] = (__bf16)aC[cb][j];
            }
        }
    }
}

// ---------------- small GEMM: Y(rows x ncols f32) = Xb @ P^T (scale prefolded in P) ----------------
__global__ __launch_bounds__(256) void gemm_pvk(const __bf16* __restrict__ Xb,
                                                const __bf16* __restrict__ Pb,
                                                float* __restrict__ Y, int rows, int ncols) {
    int lane = threadIdx.x & 63;
    int wave = threadIdx.x >> 6;
    int row0 = blockIdx.x * 64 + wave * 16;
    if (row0 >= rows) return;
    int l16 = lane & 15, kh = lane >> 4;
    int ar = row0 + l16;
    int arc = ar < rows ? ar : rows - 1;
    const __bf16* arow = Xb + (size_t)arc * D_;

    f32x4 acc[4] = {};
#pragma unroll
    for (int k0 = 0; k0 < D_; k0 += 32) {
        int kk = k0 + kh * 8;
        bf16x8 af = *(const bf16x8*)(arow + kk);
#pragma unroll
        for (int cb = 0; cb < 4; cb++) {
            int br = cb * 16 + l16;
            if (br >= ncols) br = ncols - 1;
            bf16x8 bf = *(const bf16x8*)(Pb + (size_t)br * D_ + kk);
            acc[cb] = __builtin_amdgcn_mfma_f32_16x16x32_bf16(af, bf, acc[cb], 0, 0, 0);
        }
    }
#pragma unroll
    for (int cb = 0; cb < 4; cb++) {
        int col = cb * 16 + l16;
        if (col >= ncols) continue;
#pragma unroll
        for (int j = 0; j < 4; j++) {
            int r = row0 + kh * 4 + j;
            if (r < rows) Y[(size_t)r * ncols + col] = acc[cb][j];
        }
    }
}

// ---------------- CSR build ----------------
__global__ __launch_bounds__(256) void hist2(const int* __restrict__ eu, const int* __restrict__ ei,
                                             int* __restrict__ cnt_all, int nu, int E) {
    int e = blockIdx.x * 256 + threadIdx.x;
    if (e < E) {
        atomicAdd(&cnt_all[eu[e]], 1);
        atomicAdd(&cnt_all[nu + ei[e]], 1);
    }
}

__global__ __launch_bounds__(256) void scan_phaseA(const int* __restrict__ cnt, int* __restrict__ part, int n) {
    __shared__ int wsum[4];
    int t = threadIdx.x, lane = t & 63, w = t >> 6;
    int i0 = blockIdx.x * SCAN_TILE + t * SCAN_CH;
    int tot = 0;
#pragma unroll
    for (int j = 0; j < SCAN_CH; j++) tot += (i0 + j < n) ? cnt[i0 + j] : 0;
#pragma unroll
    for (int d = 32; d; d >>= 1) tot += __shfl_xor(tot, d);
    if (lane == 0) wsum[w] = tot;
    __syncthreads();
    if (t == 0) part[blockIdx.x] = wsum[0] + wsum[1] + wsum[2] + wsum[3];
}

__global__ __launch_bounds__(1024) void scan_phaseB(int* __restrict__ part, int nb,
                                                    int* __restrict__ off, int n) {
    __shared__ int wsum[16];
    int t = threadIdx.x, lane = t & 63, w = t >> 6;
    int v = (t < nb) ? part[t] : 0;
    int x = v;
#pragma unroll
    for (int d = 1; d < 64; d <<= 1) {
        int y = __shfl_up(x, d);
        if (lane >= d) x += y;
    }
    if (lane == 63) wsum[w] = x;
    __syncthreads();
    int wbase = 0;
    for (int ww = 0; ww < w; ww++) wbase += wsum[ww];
    if (t < nb) part[t] = wbase + x - v;
    if (t == 1023) off[n] = wbase + x;
}

__global__ __launch_bounds__(256) void scan_phaseC(const int* __restrict__ cnt, const int* __restrict__ part,
                                                   int* __restrict__ off, int* __restrict__ pos, int n) {
    __shared__ int wsum[4];
    int t = threadIdx.x, lane = t & 63, w = t >> 6;
    int i0 = blockIdx.x * SCAN_TILE + t * SCAN_CH;
    int loc[SCAN_CH];
    int tot = 0;
#pragma unroll
    for (int j = 0; j < SCAN_CH; j++) {
        int v = (i0 + j < n) ? cnt[i0 + j] : 0;
        loc[j] = tot; tot += v;
    }
    int x = tot;
#pragma unroll
    for (int d = 1; d < 64; d <<= 1) {
        int y = __shfl_up(x, d);
        if (lane >= d) x += y;
    }
    if (lane == 63) wsum[w] = x;
    __syncthreads();
    int wbase = 0;
    for (int ww = 0; ww < w; ww++) wbase += wsum[ww];
    int excl = part[blockIdx.x] + wbase + x - tot;
#pragma unroll
    for (int j = 0; j < SCAN_CH; j++) {
        if (i0 + j < n) { off[i0 + j] = excl + loc[j]; pos[i0 + j] = excl + loc[j]; }
    }
}

// scatter packed: user list gets int2{it|rui<<18|riu<<24, item_slot}; item list gets int{u|rui<<18|riu<<24}
__global__ __launch_bounds__(256) void scatter2(const int* __restrict__ eu, const int* __restrict__ ei,
                                                const int* __restrict__ rui, const int* __restrict__ riu,
                                                int* __restrict__ pos_all, int2* __restrict__ u_list,
                                                int* __restrict__ i_list, int nu, int E) {
    int e = blockIdx.x * 256 + threadIdx.x;
    if (e < E) {
        int u = eu[e], it = ei[e], r1 = rui[e], r2 = riu[e];
        int rbits = (r1 << 18) | (r2 << 24);
        int pi = atomicAdd(&pos_all[nu + it], 1) - E;
        int pu = atomicAdd(&pos_all[u], 1);
        u_list[pu] = make_int2(it | rbits, pi);
        i_list[pi] = u | rbits;
    }
}

// ---------------- user pass ----------------
__global__ __launch_bounds__(256) void user_pass(const int* __restrict__ off_all, const int2* __restrict__ u_list,
                                                 const __bf16* __restrict__ ib_emb,
                                                 const __bf16* __restrict__ um_t,
                                                 const __bf16* __restrict__ li_t,
                                                 const __bf16* __restrict__ lu_t,
                                                 const __bf16* __restrict__ pKb,
                                                 const float* __restrict__ upv,
                                                 float2* __restrict__ mb_val,
                                                 __bf16* __restrict__ A1n, __bf16* __restrict__ PKn,
                                                 __bf16* __restrict__ A2n, int nu, int umax) {
    int u = blockIdx.x * 4 + (threadIdx.x >> 6);
    if (u >= nu) return;
    int lane = threadIdx.x & 63;
    int g = lane >> 4, l16 = lane & 15;
    int off = off_all[u], n = off_all[u + 1] - off;
    if (n == 0) {
        if (lane < 16) {
            bf16x8 z = {};
            *(bf16x8*)(A1n + (size_t)u * D_ + l16 * 8) = z;
            *(bf16x8*)(PKn + (size_t)u * D_ + l16 * 8) = z;
            *(bf16x8*)(A2n + (size_t)u * D_ + l16 * 8) = z;
        }
        return;
    }
    float um8[8], li8[8], lu8[8];
    unpack8(((const bf16x8*)(um_t + (size_t)u * D_))[l16], um8);
    unpack8(((const bf16x8*)(li_t + (size_t)u * D_))[l16], li8);
    unpack8(((const bf16x8*)(lu_t + (size_t)u * D_))[l16], lu8);
    const float* upv_row = upv + (size_t)u * umax;

    float s1 = 0.f, s2 = 0.f, a1[8] = {}, apk[8] = {}, a2[8] = {};
    for (int i = g; i < n; i += 8) {
        int2 ra = u_list[off + i];
        bool hb = (i + 4) < n;
        int2 rb = u_list[off + (hb ? i + 4 : i)];
        int itA = ra.x & 0x3FFFF, r1A = (ra.x >> 18) & 0x3F, r2A = (ra.x >> 24) & 0x3F;
        int itB = rb.x & 0x3FFFF, r1B = (rb.x >> 18) & 0x3F, r2B = (rb.x >> 24) & 0x3F;
        bf16x8 vieA = ((const bf16x8*)(ib_emb + (size_t)itA * D_))[l16];
        bf16x8 vpkA = ((const bf16x8*)(pKb + (size_t)r2A * D_))[l16];
        bf16x8 vieB = ((const bf16x8*)(ib_emb + (size_t)itB * D_))[l16];
        bf16x8 vpkB = ((const bf16x8*)(pKb + (size_t)r2B * D_))[l16];
        float fieA[8], fpkA[8], fieB[8], fpkB[8];
        unpack8(vieA, fieA); unpack8(vpkA, fpkA);
        unpack8(vieB, fieB); unpack8(vpkB, fpkB);
        float d1a = 0.f, d2a = 0.f, d3a = 0.f, d1b = 0.f, d2b = 0.f, d3b = 0.f;
#pragma unroll
        for (int j = 0; j < 8; j++) {
            d1a = fmaf(um8[j], fieA[j], d1a);
            d2a = fmaf(li8[j], fieA[j], d2a);
            d3a = fmaf(lu8[j], fieA[j], d3a);
            d1b = fmaf(um8[j], fieB[j], d1b);
            d2b = fmaf(li8[j], fieB[j], d2b);
            d3b = fmaf(lu8[j], fieB[j], d3b);
        }
#pragma unroll
        for (int d = 1; d < 16; d <<= 1) {
            d1a += __shfl_xor(d1a, d); d2a += __shfl_xor(d2a, d); d3a += __shfl_xor(d3a, d);
            d1b += __shfl_xor(d1b, d); d2b += __shfl_xor(d2b, d); d3b += __shfl_xor(d3b, d);
        }
        if (l16 == 0) {
            mb_val[ra.y] = make_float2(d1a, d3a);
            if (hb) mb_val[rb.y] = make_float2(d1b, d3b);
        }
        float w1a = __expf(d1a + upv_row[r1A]);
        float w2a = __expf(d2a);
        float w1b = hb ? __expf(d1b + upv_row[r1B]) : 0.f;
        float w2b = hb ? __expf(d2b) : 0.f;
        s1 += w1a + w1b; s2 += w2a + w2b;
#pragma unroll
        for (int j = 0; j < 8; j++) {
            a1[j]  = fmaf(w1a, fieA[j], fmaf(w1b, fieB[j], a1[j]));
            apk[j] = fmaf(w1a, fpkA[j], fmaf(w1b, fpkB[j], apk[j]));
            a2[j]  = fmaf(w2a, fieA[j], fmaf(w2b, fieB[j], a2[j]));
        }
    }
#pragma unroll
    for (int d = 16; d < 64; d <<= 1) {
        s1 += __shfl_xor(s1, d); s2 += __shfl_xor(s2, d);
#pragma unroll
        for (int j = 0; j < 8; j++) {
            a1[j]  += __shfl_xor(a1[j], d);
            apk[j] += __shfl_xor(apk[j], d);
            a2[j]  += __shfl_xor(a2[j], d);
        }
    }
    if (lane < 16) {
        float inv1 = 1.f / s1, inv2 = 1.f / s2;
        *(bf16x8*)(A1n + (size_t)u * D_ + l16 * 8) = pack8(a1, inv1);
        *(bf16x8*)(PKn + (size_t)u * D_ + l16 * 8) = pack8(apk, inv1);
        *(bf16x8*)(A2n + (size_t)u * D_ + l16 * 8) = pack8(a2, inv2);
    }
}

// ---------------- item pass ----------------
__global__ __launch_bounds__(256) void item_pass(const int* __restrict__ off_all, const int* __restrict__ i_list,
                                                 const __bf16* __restrict__ ub_emb,
                                                 const __bf16* __restrict__ pVb,
                                                 const float* __restrict__ ipk,
                                                 const float2* __restrict__ mb_val,
                                                 __bf16* __restrict__ B1n, __bf16* __restrict__ PVn,
                                                 __bf16* __restrict__ B2n, int nu, int ni, int imax, int E) {
    int it = blockIdx.x * 4 + (threadIdx.x >> 6);
    if (it >= ni) return;
    int lane = threadIdx.x & 63;
    int g = lane >> 4, l16 = lane & 15;
    int ioff = off_all[nu + it] - E, n = off_all[nu + it + 1] - E - ioff;
    if (n == 0) {
        if (lane < 16) {
            bf16x8 z = {};
            *(bf16x8*)(B1n + (size_t)it * D_ + l16 * 8) = z;
            *(bf16x8*)(PVn + (size_t)it * D_ + l16 * 8) = z;
            *(bf16x8*)(B2n + (size_t)it * D_ + l16 * 8) = z;
        }
        return;
    }
    const float* ipk_row = ipk + (size_t)it * imax;

    float s1 = 0.f, s2 = 0.f, b1[8] = {}, bpv[8] = {}, b2[8] = {};
    for (int i = g; i < n; i += 8) {
        int pa = i_list[ioff + i];
        bool hb = (i + 4) < n;
        int pb = i_list[ioff + (hb ? i + 4 : i)];
        int uA = pa & 0x3FFFF, r1A = (pa >> 18) & 0x3F, r2A = (pa >> 24) & 0x3F;
        int uB = pb & 0x3FFFF, r1B = (pb >> 18) & 0x3F, r2B = (pb >> 24) & 0x3F;
        float2 ma = mb_val[ioff + i];
        float2 mbv = hb ? mb_val[ioff + i + 4] : make_float2(0.f, 0.f);
        bf16x8 vueA = ((const bf16x8*)(ub_emb + (size_t)uA * D_))[l16];
        bf16x8 vpvA = ((const bf16x8*)(pVb + (size_t)r1A * D_))[l16];
        bf16x8 vueB = ((const bf16x8*)(ub_emb + (size_t)uB * D_))[l16];
        bf16x8 vpvB = ((const bf16x8*)(pVb + (size_t)r1B * D_))[l16];
        float fueA[8], fpvA[8], fueB[8], fpvB[8];
        unpack8(vueA, fueA); unpack8(vpvA, fpvA);
        unpack8(vueB, fueB); unpack8(vpvB, fpvB);
        float w1a = __expf(ma.x + ipk_row[r2A]);
        float w2a = __expf(ma.y);
        float w1b = hb ? __expf(mbv.x + ipk_row[r2B]) : 0.f;
        float w2b = hb ? __expf(mbv.y) : 0.f;
        s1 += w1a + w1b; s2 += w2a + w2b;
#pragma unroll
        for (int j = 0; j < 8; j++) {
            b1[j]  = fmaf(w1a, fueA[j], fmaf(w1b, fueB[j], b1[j]));
            bpv[j] = fmaf(w1a, fpvA[j], fmaf(w1b, fpvB[j], bpv[j]));
            b2[j]  = fmaf(w2a, fueA[j], fmaf(w2b, fueB[j], b2[j]));
        }
    }
#pragma unroll
    for (int d = 16; d < 64; d <<= 1) {
        s1 += __shfl_xor(s1, d); s2 += __shfl_xor(s2, d);
#pragma unroll
        for (int j = 0; j < 8; j++) {
            b1[j]  += __shfl_xor(b1[j], d);
            bpv[j] += __shfl_xor(bpv[j], d);
            b2[j]  += __shfl_xor(b2[j], d);
        }
    }
    if (lane < 16) {
        float inv1 = 1.f / s1, inv2 = 1.f / s2;
        *(bf16x8*)(B1n + (size_t)it * D_ + l16 * 8) = pack8(b1, inv1);
        *(bf16x8*)(PVn + (size_t)it * D_ + l16 * 8) = pack8(bpv, inv1);
        *(bf16x8*)(B2n + (size_t)it * D_ + l16 * 8) = pack8(b2, inv2);
    }
}

// ---------------- finish GEMM: out = A@W^T + (side ? side : 1[n>0]) ----------------
__global__ __launch_bounds__(256) void finish1(const __bf16* __restrict__ A, const __bf16* __restrict__ Wsrc,
                                               const __bf16* __restrict__ side, const int* __restrict__ offseg,
                                               float* __restrict__ out, int rows) {
    __shared__ __bf16 sW[128][136];
    __shared__ float stg[4][16][132];
    int t = threadIdx.x;
#pragma unroll
    for (int it = 0; it < 8; it++) {
        int slot = it * 256 + t;
        int r = slot >> 4, c16 = (slot & 15) * 8;
        bf16x8 v = *(const bf16x8*)(Wsrc + (size_t)r * D_ + c16);
        *(bf16x8*)(&sW[r][c16]) = v;
    }
    __syncthreads();
    int lane = t & 63, wave = t >> 6;
    int l16 = lane & 15, kh = lane >> 4;
    int hw = lane >> 5, c4 = (lane & 31) * 4;

    for (int tt = 0; tt < 4; tt++) {
        int row0 = blockIdx.x * 256 + (tt * 4 + wave) * 16;
        if (row0 >= rows) break;
        int ar = row0 + l16;
        int arc = ar < rows ? ar : rows - 1;
        const __bf16* rA = A + (size_t)arc * D_;
        bf16x8 a0 = *(const bf16x8*)(rA + kh * 8);
        bf16x8 a1 = *(const bf16x8*)(rA + 32 + kh * 8);
        bf16x8 a2 = *(const bf16x8*)(rA + 64 + kh * 8);
        bf16x8 a3 = *(const bf16x8*)(rA + 96 + kh * 8);
        f32x4 acc[8] = {};
#pragma unroll
        for (int cb = 0; cb < 8; cb++) {
            int wr = cb * 16 + l16;
            acc[cb] = __builtin_amdgcn_mfma_f32_16x16x32_bf16(a0, *(const bf16x8*)(&sW[wr][kh * 8]), acc[cb], 0, 0, 0);
            acc[cb] = __builtin_amdgcn_mfma_f32_16x16x32_bf16(a1, *(const bf16x8*)(&sW[wr][32 + kh * 8]), acc[cb], 0, 0, 0);
            acc[cb] = __builtin_amdgcn_mfma_f32_16x16x32_bf16(a2, *(const bf16x8*)(&sW[wr][64 + kh * 8]), acc[cb], 0, 0, 0);
            acc[cb] = __builtin_amdgcn_mfma_f32_16x16x32_bf16(a3, *(const bf16x8*)(&sW[wr][96 + kh * 8]), acc[cb], 0, 0, 0);
        }
#pragma unroll
        for (int cb = 0; cb < 8; cb++)
#pragma unroll
            for (int j = 0; j < 4; j++)
                stg[wave][kh * 4 + j][cb * 16 + l16] = acc[cb][j];
#pragma unroll
        for (int k = 0; k < 8; k++) {
            int wr = hw + k * 2;
            int rg = row0 + wr;
            if (rg < rows) {
                float4 v = *(const float4*)&stg[wave][wr][c4];
                if (side) {
                    ushort4 sv = *(const ushort4*)((const unsigned short*)side + (size_t)rg * D_ + c4);
                    v.x += __uint_as_float((uint32_t)sv.x << 16);
                    v.y += __uint_as_float((uint32_t)sv.y << 16);
                    v.z += __uint_as_float((uint32_t)sv.z << 16);
                    v.w += __uint_as_float((uint32_t)sv.w << 16);
                } else {
                    float one = (offseg[rg + 1] - offseg[rg]) > 0 ? 1.f : 0.f;
                    v.x += one; v.y += one; v.z += one; v.w += one;
                }
                *(float4*)(out + (size_t)rg * D_ + c4) = v;
            }
        }
    }
}

extern "C" void kernel_launch(void* const* d_in, const int* in_sizes, int n_in,
                              void* d_out, int out_size, void* d_ws, size_t ws_size,
                              hipStream_t stream) {
    (void)n_in; (void)out_size; (void)ws_size;
    const float* u_emb = (const float*)d_in[0];
    const float* i_emb = (const float*)d_in[1];
    const int* edge_u = (const int*)d_in[2];
    const int* edge_i = (const int*)d_in[3];
    const int* rui = (const int*)d_in[4];
    const int* riu = (const int*)d_in[5];
    const int* last_u_items = (const int*)d_in[6];
    const int* last_i_users = (const int*)d_in[7];
    const float* W1  = (const float*)d_in[8];
    const float* W2  = (const float*)d_in[9];
    const float* W1b = (const float*)d_in[10];
    const float* W2b = (const float*)d_in[11];
    const float* W3  = (const float*)d_in[12];
    const float* W4  = (const float*)d_in[13];
    const float* pV  = (const float*)d_in[14];
    const float* pK  = (const float*)d_in[15];
    const float* last_user_table = (const float*)d_in[16];
    const float* last_item_table = (const float*)d_in[17];

    const int NU = in_sizes[0] / D_;
    const int NI = in_sizes[1] / D_;
    const int E  = in_sizes[2];
    const int UMAXr = in_sizes[14] / D_;
    const int IMAXr = in_sizes[15] / D_;
    const int NSEG = NU + NI;

    size_t cur = 0;
    auto alloc = [&](size_t bytes) -> void* {
        void* p = (char*)d_ws + cur;
        cur += (bytes + 255) & ~(size_t)255;
        return p;
    };

    __bf16* Wb4   = (__bf16*)alloc(4 * 16384 * 2);
    __bf16* M2t   = (__bf16*)alloc(16384 * 2);
    __bf16* M3t   = (__bf16*)alloc(16384 * 2);
    __bf16* M4t   = (__bf16*)alloc(16384 * 2);
    __bf16* pVW2  = (__bf16*)alloc((size_t)UMAXr * D_ * 2);
    __bf16* pKW1  = (__bf16*)alloc((size_t)IMAXr * D_ * 2);
    __bf16* pVb   = (__bf16*)alloc((size_t)UMAXr * D_ * 2);
    __bf16* pKb   = (__bf16*)alloc((size_t)IMAXr * D_ * 2);
    __bf16* ub_emb = (__bf16*)alloc((size_t)NU * D_ * 2);
    __bf16* ib_emb = (__bf16*)alloc((size_t)NI * D_ * 2);
    __bf16* um_t  = (__bf16*)alloc((size_t)NU * D_ * 2);
    __bf16* li_t  = (__bf16*)alloc((size_t)NU * D_ * 2);
    __bf16* lu_t  = (__bf16*)alloc((size_t)NU * D_ * 2);
    float* upv    = (float*)alloc((size_t)NU * UMAXr * 4);
    float* ipk    = (float*)alloc((size_t)NI * IMAXr * 4);
    __bf16* A1n   = (__bf16*)alloc((size_t)NU * D_ * 2);
    __bf16* PKn   = (__bf16*)alloc((size_t)NU * D_ * 2);
    __bf16* A2n   = (__bf16*)alloc((size_t)NU * D_ * 2);
    __bf16* B1n   = (__bf16*)alloc((size_t)NI * D_ * 2);
    __bf16* PVn   = (__bf16*)alloc((size_t)NI * D_ * 2);
    __bf16* B2n   = (__bf16*)alloc((size_t)NI * D_ * 2);
    float2* mb_val = (float2*)alloc((size_t)E * 8);
    int2* u_list  = (int2*)alloc((size_t)E * 8);
    int* i_list   = (int*)alloc((size_t)E * 4);
    int* cnt_all  = (int*)alloc((size_t)NSEG * 4);
    int* off_all  = (int*)alloc((size_t)(NSEG + 1) * 4);
    int* pos_all  = (int*)alloc((size_t)NSEG * 4);
    int* parts    = (int*)alloc(1024 * 4);

    float* out = (float*)d_out;
    float* hLu = out;
    float* hSu = out + (size_t)NU * D_;
    float* hLi = out + (size_t)2 * NU * D_;
    float* hSi = out + (size_t)2 * NU * D_ + (size_t)NI * D_;

    // weight casts + combined matrices
    W4p w4; w4.p[0] = W1; w4.p[1] = W2; w4.p[2] = W1b; w4.p[3] = W2b;
    int npv = UMAXr * D_, npk = IMAXr * D_;
    cvt_small<<<(4 * 16384 + npv + npk + 255) / 256, 256, 0, stream>>>(w4, pV, pK, Wb4, pVb, pKb, npv, npk);
    prep_mats<<<128 + (UMAXr > IMAXr ? UMAXr : IMAXr), 128, 0, stream>>>(W1, W2, W3, W4, pV, pK,
                                                                         M2t, M3t, M4t, pVW2, pKW1, UMAXr, IMAXr);
    size_t nue = (size_t)NU * D_, nie = (size_t)NI * D_;
    cvt_emb<<<(int)(((nue + nie) / 4 + 255) / 256), 256, 0, stream>>>(u_emb, i_emb, ub_emb, ib_emb, nue, nie);

    // CSR build
    hipMemsetAsync(cnt_all, 0, (size_t)NSEG * 4, stream);
    hist2<<<(E + 255) / 256, 256, 0, stream>>>(edge_u, edge_i, cnt_all, NU, E);
    int nb = (NSEG + SCAN_TILE - 1) / SCAN_TILE;
    scan_phaseA<<<nb, 256, 0, stream>>>(cnt_all, parts, NSEG);
    scan_phaseB<<<1, 1024, 0, stream>>>(parts, nb, off_all, NSEG);
    scan_phaseC<<<nb, 256, 0, stream>>>(cnt_all, parts, off_all, pos_all, NSEG);
    scatter2<<<(E + 255) / 256, 256, 0, stream>>>(edge_u, edge_i, rui, riu, pos_all, u_list, i_list, NU, E);

    // transformed user vectors + positional dot tables
    int gu = (NU + 63) / 64, gi = (NI + 63) / 64;
    user_vecs<<<gu, 256, 0, stream>>>(u_emb, last_item_table, last_u_items, last_user_table, last_i_users,
                                      M2t, M3t, M4t, um_t, li_t, lu_t, NU);
    gemm_pvk<<<gu, 256, 0, stream>>>(ub_emb, pVW2, upv, NU, UMAXr);
    gemm_pvk<<<gi, 256, 0, stream>>>(ib_emb, pKW1, ipk, NI, IMAXr);

    // edge passes
    user_pass<<<(NU + 3) / 4, 256, 0, stream>>>(off_all, u_list, ib_emb, um_t, li_t, lu_t,
                                                pKb, upv, mb_val, A1n, PKn, A2n, NU, UMAXr);
    item_pass<<<(NI + 3) / 4, 256, 0, stream>>>(off_all, i_list, ub_emb, pVb, ipk, mb_val,
                                                B1n, PVn, B2n, NU, NI, IMAXr, E);

    // finish projections
    int fu = (NU + 255) / 256, fi = (NI + 255) / 256;
    finish1<<<fu, 256, 0, stream>>>(A1n, Wb4 + 2 * 16384, PKn, nullptr, hLu, NU);
    finish1<<<fu, 256, 0, stream>>>(A2n, Wb4 + 0 * 16384, nullptr, off_all, hSu, NU);
    finish1<<<fi, 256, 0, stream>>>(B1n, Wb4 + 3 * 16384, PVn, nullptr, hLi, NI);
    finish1<<<fi, 256, 0, stream>>>(B2n, Wb4 + 1 * 16384, nullptr, off_all + NU, hSi, NI);
}

// Round 12
// 508.549 us; speedup vs baseline: 1.1735x; 1.0642x over previous
//
#include <hip/hip_runtime.h>
#include <hip/hip_bf16.h>
#include <math.h>

#define D_ 128
#define INV_SQRT_D 0.08838834764831845f
#define SCAN_CH 16
#define SCAN_TILE (256 * SCAN_CH)

typedef __bf16 bf16x8 __attribute__((ext_vector_type(8)));
typedef float f32x4 __attribute__((ext_vector_type(4)));

struct W4p { const float* p[4]; };

__device__ __forceinline__ void unpack8(bf16x8 v, float* f) {
    const uint32_t* u = (const uint32_t*)&v;
#pragma unroll
    for (int i = 0; i < 4; i++) {
        uint32_t w = u[i];
        f[2 * i]     = __uint_as_float(w << 16);
        f[2 * i + 1] = __uint_as_float(w & 0xffff0000u);
    }
}

__device__ __forceinline__ bf16x8 pack8(const float* f, float s) {
    bf16x8 r;
#pragma unroll
    for (int j = 0; j < 8; j++) r[j] = (__bf16)(f[j] * s);
    return r;
}

__device__ __forceinline__ float bf2f(__bf16 v) {
    return __uint_as_float((uint32_t)(*(unsigned short*)&v) << 16);
}

// ---------------- casts: weights + pV/pK in one kernel ----------------
__global__ __launch_bounds__(256) void cvt_small(W4p w, const float* __restrict__ pV, const float* __restrict__ pK,
                                                 __bf16* __restrict__ outW, __bf16* __restrict__ pVb,
                                                 __bf16* __restrict__ pKb, int npv, int npk) {
    int idx = blockIdx.x * 256 + threadIdx.x;
    if (idx < 4 * 16384) {
        outW[idx] = (__bf16)w.p[idx >> 14][idx & 16383];
    } else if (idx - 4 * 16384 < npv) {
        int j = idx - 4 * 16384;
        pVb[j] = (__bf16)pV[j];
    } else if (idx - 4 * 16384 - npv < npk) {
        int j = idx - 4 * 16384 - npv;
        pKb[j] = (__bf16)pK[j];
    }
}

__global__ __launch_bounds__(256) void cvt_emb(const float* __restrict__ u, const float* __restrict__ i,
                                               __bf16* __restrict__ ub, __bf16* __restrict__ ib,
                                               size_t nue, size_t nie) {
    size_t idx4 = ((size_t)blockIdx.x * 256 + threadIdx.x) * 4;
    if (idx4 < nue) {
        float4 v = *(const float4*)(u + idx4);
        ub[idx4] = (__bf16)v.x; ub[idx4+1] = (__bf16)v.y; ub[idx4+2] = (__bf16)v.z; ub[idx4+3] = (__bf16)v.w;
    } else if (idx4 < nue + nie) {
        size_t j = idx4 - nue;
        float4 v = *(const float4*)(i + j);
        ib[j] = (__bf16)v.x; ib[j+1] = (__bf16)v.y; ib[j+2] = (__bf16)v.z; ib[j+3] = (__bf16)v.w;
    }
}

// ---------------- combined-matrix prep ----------------
__global__ __launch_bounds__(128) void prep_mats(const float* __restrict__ W1, const float* __restrict__ W2,
                                                 const float* __restrict__ W3, const float* __restrict__ W4,
                                                 const float* __restrict__ pV, const float* __restrict__ pK,
                                                 __bf16* __restrict__ M2t, __bf16* __restrict__ M3t,
                                                 __bf16* __restrict__ M4t,
                                                 __bf16* __restrict__ pVW2, __bf16* __restrict__ pKW1,
                                                 int umax, int imax) {
    __shared__ float sh[256];
    int b = blockIdx.x, t = threadIdx.x;
    if (b < 128) {
        sh[t] = W1[t * 128 + b];
        __syncthreads();
        float m2 = 0.f, m3 = 0.f, m4 = 0.f;
        for (int k = 0; k < 128; k++) {
            float w = sh[k];
            m2 = fmaf(w, W2[k * 128 + t], m2);
            m3 = fmaf(w, W3[k * 128 + t], m3);
            m4 = fmaf(w, W4[k * 128 + t], m4);
        }
        M2t[b * 128 + t] = (__bf16)(m2 * INV_SQRT_D);
        M3t[b * 128 + t] = (__bf16)(m3 * INV_SQRT_D);
        M4t[b * 128 + t] = (__bf16)(m4 * INV_SQRT_D);
    } else {
        int r = b - 128;
        if (r < umax) sh[t] = pV[r * 128 + t];
        if (r < imax) sh[128 + t] = pK[r * 128 + t];
        __syncthreads();
        float q = 0.f, qk = 0.f;
        for (int a = 0; a < 128; a++) {
            if (r < umax) q  = fmaf(sh[a], W2[a * 128 + t], q);
            if (r < imax) qk = fmaf(sh[128 + a], W1[a * 128 + t], qk);
        }
        if (r < umax) pVW2[r * 128 + t] = (__bf16)(q * INV_SQRT_D);
        if (r < imax) pKW1[r * 128 + t] = (__bf16)(qk * INV_SQRT_D);
    }
}

// ---------------- user transformed vectors ----------------
__global__ __launch_bounds__(256) void user_vecs(const float* __restrict__ u_emb,
                                                 const float* __restrict__ lit_tab, const int* __restrict__ g_li,
                                                 const float* __restrict__ lut_tab, const int* __restrict__ g_lu,
                                                 const __bf16* __restrict__ M2t, const __bf16* __restrict__ M3t,
                                                 const __bf16* __restrict__ M4t,
                                                 __bf16* __restrict__ um_t, __bf16* __restrict__ li_t,
                                                 __bf16* __restrict__ lu_t, int rows) {
    int lane = threadIdx.x & 63;
    int wave = threadIdx.x >> 6;
    int row0 = blockIdx.x * 64 + wave * 16;
    if (row0 >= rows) return;
    int l16 = lane & 15, kh = lane >> 4;
    int ar = row0 + l16;
    int arc = ar < rows ? ar : rows - 1;
    const float* rA = u_emb + (size_t)arc * D_;
    const float* rB = lit_tab + (size_t)g_li[arc] * D_;
    const float* rC = lut_tab + (size_t)g_lu[arc] * D_;

    f32x4 aA[8] = {}, aB[8] = {}, aC[8] = {};
#pragma unroll
    for (int k0 = 0; k0 < D_; k0 += 32) {
        int kk = k0 + kh * 8;
        float4 a0 = *(const float4*)(rA + kk), a1 = *(const float4*)(rA + kk + 4);
        float4 b0 = *(const float4*)(rB + kk), b1 = *(const float4*)(rB + kk + 4);
        float4 c0 = *(const float4*)(rC + kk), c1 = *(const float4*)(rC + kk + 4);
        bf16x8 fA, fB, fC;
        fA[0]=(__bf16)a0.x; fA[1]=(__bf16)a0.y; fA[2]=(__bf16)a0.z; fA[3]=(__bf16)a0.w;
        fA[4]=(__bf16)a1.x; fA[5]=(__bf16)a1.y; fA[6]=(__bf16)a1.z; fA[7]=(__bf16)a1.w;
        fB[0]=(__bf16)b0.x; fB[1]=(__bf16)b0.y; fB[2]=(__bf16)b0.z; fB[3]=(__bf16)b0.w;
        fB[4]=(__bf16)b1.x; fB[5]=(__bf16)b1.y; fB[6]=(__bf16)b1.z; fB[7]=(__bf16)b1.w;
        fC[0]=(__bf16)c0.x; fC[1]=(__bf16)c0.y; fC[2]=(__bf16)c0.z; fC[3]=(__bf16)c0.w;
        fC[4]=(__bf16)c1.x; fC[5]=(__bf16)c1.y; fC[6]=(__bf16)c1.z; fC[7]=(__bf16)c1.w;
#pragma unroll
        for (int cb = 0; cb < 8; cb++) {
            bf16x8 w2 = *(const bf16x8*)(M2t + (size_t)(cb * 16 + l16) * D_ + kk);
            aA[cb] = __builtin_amdgcn_mfma_f32_16x16x32_bf16(fA, w2, aA[cb], 0, 0, 0);
            bf16x8 w3 = *(const bf16x8*)(M3t + (size_t)(cb * 16 + l16) * D_ + kk);
            aB[cb] = __builtin_amdgcn_mfma_f32_16x16x32_bf16(fB, w3, aB[cb], 0, 0, 0);
            bf16x8 w4 = *(const bf16x8*)(M4t + (size_t)(cb * 16 + l16) * D_ + kk);
            aC[cb] = __builtin_amdgcn_mfma_f32_16x16x32_bf16(fC, w4, aC[cb], 0, 0, 0);
        }
    }
#pragma unroll
    for (int cb = 0; cb < 8; cb++) {
#pragma unroll
        for (int j = 0; j < 4; j++) {
            int r = row0 + kh * 4 + j;
            if (r < rows) {
                um_t[(size_t)r * D_ + cb * 16 + l16] = (__bf16)aA[cb][j];
                li_t[(size_t)r * D_ + cb * 16 + l16] = (__bf16)aB[cb][j];
                lu_t[(size_t)r * D_ + cb * 16 + l16] = (__bf16)aC[cb][j];
            }
        }
    }
}

// ---------------- merged positional-dot GEMMs: Y(rows x ncols bf16) = Xb @ P^T ----------------
struct PvkA { const __bf16* X; const __bf16* P; __bf16* Y; int rows; int ncols; };
struct Pvk2 { PvkA a[2]; };
__global__ __launch_bounds__(256) void gemm_pvk2(Pvk2 p) {
    PvkA q = p.a[blockIdx.y];
    int lane = threadIdx.x & 63;
    int wave = threadIdx.x >> 6;
    int row0 = blockIdx.x * 64 + wave * 16;
    if (row0 >= q.rows) return;
    int l16 = lane & 15, kh = lane >> 4;
    int ar = row0 + l16;
    int arc = ar < q.rows ? ar : q.rows - 1;
    const __bf16* arow = q.X + (size_t)arc * D_;

    f32x4 acc[4] = {};
#pragma unroll
    for (int k0 = 0; k0 < D_; k0 += 32) {
        int kk = k0 + kh * 8;
        bf16x8 af = *(const bf16x8*)(arow + kk);
#pragma unroll
        for (int cb = 0; cb < 4; cb++) {
            int br = cb * 16 + l16;
            if (br >= q.ncols) br = q.ncols - 1;
            bf16x8 bf = *(const bf16x8*)(q.P + (size_t)br * D_ + kk);
            acc[cb] = __builtin_amdgcn_mfma_f32_16x16x32_bf16(af, bf, acc[cb], 0, 0, 0);
        }
    }
#pragma unroll
    for (int cb = 0; cb < 4; cb++) {
        int col = cb * 16 + l16;
        if (col >= q.ncols) continue;
#pragma unroll
        for (int j = 0; j < 4; j++) {
            int r = row0 + kh * 4 + j;
            if (r < q.rows) q.Y[(size_t)r * q.ncols + col] = (__bf16)acc[cb][j];
        }
    }
}

// ---------------- CSR build ----------------
__global__ __launch_bounds__(256) void hist2(const int* __restrict__ eu, const int* __restrict__ ei,
                                             int* __restrict__ cnt_all, int nu, int E) {
    int e = blockIdx.x * 256 + threadIdx.x;
    if (e < E) {
        atomicAdd(&cnt_all[eu[e]], 1);
        atomicAdd(&cnt_all[nu + ei[e]], 1);
    }
}

__global__ __launch_bounds__(256) void scan_phaseA(const int* __restrict__ cnt, int* __restrict__ part, int n) {
    __shared__ int wsum[4];
    int t = threadIdx.x, lane = t & 63, w = t >> 6;
    int i0 = blockIdx.x * SCAN_TILE + t * SCAN_CH;
    int tot = 0;
#pragma unroll
    for (int j = 0; j < SCAN_CH; j++) tot += (i0 + j < n) ? cnt[i0 + j] : 0;
#pragma unroll
    for (int d = 32; d; d >>= 1) tot += __shfl_xor(tot, d);
    if (lane == 0) wsum[w] = tot;
    __syncthreads();
    if (t == 0) part[blockIdx.x] = wsum[0] + wsum[1] + wsum[2] + wsum[3];
}

__global__ __launch_bounds__(1024) void scan_phaseB(int* __restrict__ part, int nb,
                                                    int* __restrict__ off, int n) {
    __shared__ int wsum[16];
    int t = threadIdx.x, lane = t & 63, w = t >> 6;
    int v = (t < nb) ? part[t] : 0;
    int x = v;
#pragma unroll
    for (int d = 1; d < 64; d <<= 1) {
        int y = __shfl_up(x, d);
        if (lane >= d) x += y;
    }
    if (lane == 63) wsum[w] = x;
    __syncthreads();
    int wbase = 0;
    for (int ww = 0; ww < w; ww++) wbase += wsum[ww];
    if (t < nb) part[t] = wbase + x - v;
    if (t == 1023) off[n] = wbase + x;
}

__global__ __launch_bounds__(256) void scan_phaseC(const int* __restrict__ cnt, const int* __restrict__ part,
                                                   int* __restrict__ off, int* __restrict__ pos, int n) {
    __shared__ int wsum[4];
    int t = threadIdx.x, lane = t & 63, w = t >> 6;
    int i0 = blockIdx.x * SCAN_TILE + t * SCAN_CH;
    int loc[SCAN_CH];
    int tot = 0;
#pragma unroll
    for (int j = 0; j < SCAN_CH; j++) {
        int v = (i0 + j < n) ? cnt[i0 + j] : 0;
        loc[j] = tot; tot += v;
    }
    int x = tot;
#pragma unroll
    for (int d = 1; d < 64; d <<= 1) {
        int y = __shfl_up(x, d);
        if (lane >= d) x += y;
    }
    if (lane == 63) wsum[w] = x;
    __syncthreads();
    int wbase = 0;
    for (int ww = 0; ww < w; ww++) wbase += wsum[ww];
    int excl = part[blockIdx.x] + wbase + x - tot;
#pragma unroll
    for (int j = 0; j < SCAN_CH; j++) {
        if (i0 + j < n) { off[i0 + j] = excl + loc[j]; pos[i0 + j] = excl + loc[j]; }
    }
}

// scatter packed: user list gets int2{it|rui<<18|riu<<24, item_slot}; item list gets int{u|rui<<18|riu<<24}
__global__ __launch_bounds__(256) void scatter2(const int* __restrict__ eu, const int* __restrict__ ei,
                                                const int* __restrict__ rui, const int* __restrict__ riu,
                                                int* __restrict__ pos_all, int2* __restrict__ u_list,
                                                int* __restrict__ i_list, int nu, int E) {
    int e = blockIdx.x * 256 + threadIdx.x;
    if (e < E) {
        int u = eu[e], it = ei[e], r1 = rui[e], r2 = riu[e];
        int rbits = (r1 << 18) | (r2 << 24);
        int pi = atomicAdd(&pos_all[nu + it], 1) - E;
        int pu = atomicAdd(&pos_all[u], 1);
        u_list[pu] = make_int2(it | rbits, pi);
        i_list[pi] = u | rbits;
    }
}

// ---------------- user pass ----------------
__global__ __launch_bounds__(256) void user_pass(const int* __restrict__ off_all, const int2* __restrict__ u_list,
                                                 const __bf16* __restrict__ ib_emb,
                                                 const __bf16* __restrict__ um_t,
                                                 const __bf16* __restrict__ li_t,
                                                 const __bf16* __restrict__ lu_t,
                                                 const __bf16* __restrict__ pKb,
                                                 const __bf16* __restrict__ upv,
                                                 float2* __restrict__ mb_val,
                                                 __bf16* __restrict__ A1n, __bf16* __restrict__ PKn,
                                                 __bf16* __restrict__ A2n, int nu, int umax) {
    int u = blockIdx.x * 4 + (threadIdx.x >> 6);
    if (u >= nu) return;
    int lane = threadIdx.x & 63;
    int g = lane >> 4, l16 = lane & 15;
    int off = off_all[u], n = off_all[u + 1] - off;
    if (n == 0) {
        if (lane < 16) {
            bf16x8 z = {};
            *(bf16x8*)(A1n + (size_t)u * D_ + l16 * 8) = z;
            *(bf16x8*)(PKn + (size_t)u * D_ + l16 * 8) = z;
            *(bf16x8*)(A2n + (size_t)u * D_ + l16 * 8) = z;
        }
        return;
    }
    float um8[8], li8[8], lu8[8];
    unpack8(((const bf16x8*)(um_t + (size_t)u * D_))[l16], um8);
    unpack8(((const bf16x8*)(li_t + (size_t)u * D_))[l16], li8);
    unpack8(((const bf16x8*)(lu_t + (size_t)u * D_))[l16], lu8);
    const __bf16* upv_row = upv + (size_t)u * umax;

    float s1 = 0.f, s2 = 0.f, a1[8] = {}, apk[8] = {}, a2[8] = {};
    for (int i = g; i < n; i += 8) {
        int2 ra = u_list[off + i];
        bool hb = (i + 4) < n;
        int2 rb = u_list[off + (hb ? i + 4 : i)];
        int itA = ra.x & 0x3FFFF, r1A = (ra.x >> 18) & 0x3F, r2A = (ra.x >> 24) & 0x3F;
        int itB = rb.x & 0x3FFFF, r1B = (rb.x >> 18) & 0x3F, r2B = (rb.x >> 24) & 0x3F;
        bf16x8 vieA = ((const bf16x8*)(ib_emb + (size_t)itA * D_))[l16];
        bf16x8 vpkA = ((const bf16x8*)(pKb + (size_t)r2A * D_))[l16];
        bf16x8 vieB = ((const bf16x8*)(ib_emb + (size_t)itB * D_))[l16];
        bf16x8 vpkB = ((const bf16x8*)(pKb + (size_t)r2B * D_))[l16];
        float fieA[8], fpkA[8], fieB[8], fpkB[8];
        unpack8(vieA, fieA); unpack8(vpkA, fpkA);
        unpack8(vieB, fieB); unpack8(vpkB, fpkB);
        float d1a = 0.f, d2a = 0.f, d3a = 0.f, d1b = 0.f, d2b = 0.f, d3b = 0.f;
#pragma unroll
        for (int j = 0; j < 8; j++) {
            d1a = fmaf(um8[j], fieA[j], d1a);
            d2a = fmaf(li8[j], fieA[j], d2a);
            d3a = fmaf(lu8[j], fieA[j], d3a);
            d1b = fmaf(um8[j], fieB[j], d1b);
            d2b = fmaf(li8[j], fieB[j], d2b);
            d3b = fmaf(lu8[j], fieB[j], d3b);
        }
#pragma unroll
        for (int d = 1; d < 16; d <<= 1) {
            d1a += __shfl_xor(d1a, d); d2a += __shfl_xor(d2a, d); d3a += __shfl_xor(d3a, d);
            d1b += __shfl_xor(d1b, d); d2b += __shfl_xor(d2b, d); d3b += __shfl_xor(d3b, d);
        }
        if (l16 == 0) {
            mb_val[ra.y] = make_float2(d1a, d3a);
            if (hb) mb_val[rb.y] = make_float2(d1b, d3b);
        }
        float w1a = __expf(d1a + bf2f(upv_row[r1A]));
        float w2a = __expf(d2a);
        float w1b = hb ? __expf(d1b + bf2f(upv_row[r1B])) : 0.f;
        float w2b = hb ? __expf(d2b) : 0.f;
        s1 += w1a + w1b; s2 += w2a + w2b;
#pragma unroll
        for (int j = 0; j < 8; j++) {
            a1[j]  = fmaf(w1a, fieA[j], fmaf(w1b, fieB[j], a1[j]));
            apk[j] = fmaf(w1a, fpkA[j], fmaf(w1b, fpkB[j], apk[j]));
            a2[j]  = fmaf(w2a, fieA[j], fmaf(w2b, fieB[j], a2[j]));
        }
    }
#pragma unroll
    for (int d = 16; d < 64; d <<= 1) {
        s1 += __shfl_xor(s1, d); s2 += __shfl_xor(s2, d);
#pragma unroll
        for (int j = 0; j < 8; j++) {
            a1[j]  += __shfl_xor(a1[j], d);
            apk[j] += __shfl_xor(apk[j], d);
            a2[j]  += __shfl_xor(a2[j], d);
        }
    }
    if (lane < 16) {
        float inv1 = 1.f / s1, inv2 = 1.f / s2;
        *(bf16x8*)(A1n + (size_t)u * D_ + l16 * 8) = pack8(a1, inv1);
        *(bf16x8*)(PKn + (size_t)u * D_ + l16 * 8) = pack8(apk, inv1);
        *(bf16x8*)(A2n + (size_t)u * D_ + l16 * 8) = pack8(a2, inv2);
    }
}

// ---------------- item pass ----------------
__global__ __launch_bounds__(256) void item_pass(const int* __restrict__ off_all, const int* __restrict__ i_list,
                                                 const __bf16* __restrict__ ub_emb,
                                                 const __bf16* __restrict__ pVb,
                                                 const __bf16* __restrict__ ipk,
                                                 const float2* __restrict__ mb_val,
                                                 __bf16* __restrict__ B1n, __bf16* __restrict__ PVn,
                                                 __bf16* __restrict__ B2n, int nu, int ni, int imax, int E) {
    int it = blockIdx.x * 4 + (threadIdx.x >> 6);
    if (it >= ni) return;
    int lane = threadIdx.x & 63;
    int g = lane >> 4, l16 = lane & 15;
    int ioff = off_all[nu + it] - E, n = off_all[nu + it + 1] - E - ioff;
    if (n == 0) {
        if (lane < 16) {
            bf16x8 z = {};
            *(bf16x8*)(B1n + (size_t)it * D_ + l16 * 8) = z;
            *(bf16x8*)(PVn + (size_t)it * D_ + l16 * 8) = z;
            *(bf16x8*)(B2n + (size_t)it * D_ + l16 * 8) = z;
        }
        return;
    }
    const __bf16* ipk_row = ipk + (size_t)it * imax;

    float s1 = 0.f, s2 = 0.f, b1[8] = {}, bpv[8] = {}, b2[8] = {};
    for (int i = g; i < n; i += 8) {
        int pa = i_list[ioff + i];
        bool hb = (i + 4) < n;
        int pb = i_list[ioff + (hb ? i + 4 : i)];
        int uA = pa & 0x3FFFF, r1A = (pa >> 18) & 0x3F, r2A = (pa >> 24) & 0x3F;
        int uB = pb & 0x3FFFF, r1B = (pb >> 18) & 0x3F, r2B = (pb >> 24) & 0x3F;
        float2 ma = mb_val[ioff + i];
        float2 mbv = hb ? mb_val[ioff + i + 4] : make_float2(0.f, 0.f);
        bf16x8 vueA = ((const bf16x8*)(ub_emb + (size_t)uA * D_))[l16];
        bf16x8 vpvA = ((const bf16x8*)(pVb + (size_t)r1A * D_))[l16];
        bf16x8 vueB = ((const bf16x8*)(ub_emb + (size_t)uB * D_))[l16];
        bf16x8 vpvB = ((const bf16x8*)(pVb + (size_t)r1B * D_))[l16];
        float fueA[8], fpvA[8], fueB[8], fpvB[8];
        unpack8(vueA, fueA); unpack8(vpvA, fpvA);
        unpack8(vueB, fueB); unpack8(vpvB, fpvB);
        float w1a = __expf(ma.x + bf2f(ipk_row[r2A]));
        float w2a = __expf(ma.y);
        float w1b = hb ? __expf(mbv.x + bf2f(ipk_row[r2B])) : 0.f;
        float w2b = hb ? __expf(mbv.y) : 0.f;
        s1 += w1a + w1b; s2 += w2a + w2b;
#pragma unroll
        for (int j = 0; j < 8; j++) {
            b1[j]  = fmaf(w1a, fueA[j], fmaf(w1b, fueB[j], b1[j]));
            bpv[j] = fmaf(w1a, fpvA[j], fmaf(w1b, fpvB[j], bpv[j]));
            b2[j]  = fmaf(w2a, fueA[j], fmaf(w2b, fueB[j], b2[j]));
        }
    }
#pragma unroll
    for (int d = 16; d < 64; d <<= 1) {
        s1 += __shfl_xor(s1, d); s2 += __shfl_xor(s2, d);
#pragma unroll
        for (int j = 0; j < 8; j++) {
            b1[j]  += __shfl_xor(b1[j], d);
            bpv[j] += __shfl_xor(bpv[j], d);
            b2[j]  += __shfl_xor(b2[j], d);
        }
    }
    if (lane < 16) {
        float inv1 = 1.f / s1, inv2 = 1.f / s2;
        *(bf16x8*)(B1n + (size_t)it * D_ + l16 * 8) = pack8(b1, inv1);
        *(bf16x8*)(PVn + (size_t)it * D_ + l16 * 8) = pack8(bpv, inv1);
        *(bf16x8*)(B2n + (size_t)it * D_ + l16 * 8) = pack8(b2, inv2);
    }
}

// ---------------- finish GEMM (4 configs via blockIdx.y) ----------------
struct FinArgs { const __bf16* A; const __bf16* W; const __bf16* side; const int* offseg; float* out; int rows; };
struct Fin4 { FinArgs f[4]; };
__global__ __launch_bounds__(256) void finish4(Fin4 fa) {
    FinArgs q = fa.f[blockIdx.y];
    if (blockIdx.x * 256 >= (unsigned)q.rows) return;
    __shared__ __bf16 sW[128][136];
    __shared__ float stg[4][16][132];
    int t = threadIdx.x;
#pragma unroll
    for (int it = 0; it < 8; it++) {
        int slot = it * 256 + t;
        int r = slot >> 4, c16 = (slot & 15) * 8;
        bf16x8 v = *(const bf16x8*)(q.W + (size_t)r * D_ + c16);
        *(bf16x8*)(&sW[r][c16]) = v;
    }
    __syncthreads();
    int lane = t & 63, wave = t >> 6;
    int l16 = lane & 15, kh = lane >> 4;
    int hw = lane >> 5, c4 = (lane & 31) * 4;

    for (int tt = 0; tt < 4; tt++) {
        int row0 = blockIdx.x * 256 + (tt * 4 + wave) * 16;
        if (row0 >= q.rows) break;
        int ar = row0 + l16;
        int arc = ar < q.rows ? ar : q.rows - 1;
        const __bf16* rA = q.A + (size_t)arc * D_;
        bf16x8 a0 = *(const bf16x8*)(rA + kh * 8);
        bf16x8 a1 = *(const bf16x8*)(rA + 32 + kh * 8);
        bf16x8 a2 = *(const bf16x8*)(rA + 64 + kh * 8);
        bf16x8 a3 = *(const bf16x8*)(rA + 96 + kh * 8);
        f32x4 acc[8] = {};
#pragma unroll
        for (int cb = 0; cb < 8; cb++) {
            int wr = cb * 16 + l16;
            acc[cb] = __builtin_amdgcn_mfma_f32_16x16x32_bf16(a0, *(const bf16x8*)(&sW[wr][kh * 8]), acc[cb], 0, 0, 0);
            acc[cb] = __builtin_amdgcn_mfma_f32_16x16x32_bf16(a1, *(const bf16x8*)(&sW[wr][32 + kh * 8]), acc[cb], 0, 0, 0);
            acc[cb] = __builtin_amdgcn_mfma_f32_16x16x32_bf16(a2, *(const bf16x8*)(&sW[wr][64 + kh * 8]), acc[cb], 0, 0, 0);
            acc[cb] = __builtin_amdgcn_mfma_f32_16x16x32_bf16(a3, *(const bf16x8*)(&sW[wr][96 + kh * 8]), acc[cb], 0, 0, 0);
        }
#pragma unroll
        for (int cb = 0; cb < 8; cb++)
#pragma unroll
            for (int j = 0; j < 4; j++)
                stg[wave][kh * 4 + j][cb * 16 + l16] = acc[cb][j];
#pragma unroll
        for (int k = 0; k < 8; k++) {
            int wr = hw + k * 2;
            int rg = row0 + wr;
            if (rg < q.rows) {
                float4 v = *(const float4*)&stg[wave][wr][c4];
                if (q.side) {
                    ushort4 sv = *(const ushort4*)((const unsigned short*)q.side + (size_t)rg * D_ + c4);
                    v.x += __uint_as_float((uint32_t)sv.x << 16);
                    v.y += __uint_as_float((uint32_t)sv.y << 16);
                    v.z += __uint_as_float((uint32_t)sv.z << 16);
                    v.w += __uint_as_float((uint32_t)sv.w << 16);
                } else {
                    float one = (q.offseg[rg + 1] - q.offseg[rg]) > 0 ? 1.f : 0.f;
                    v.x += one; v.y += one; v.z += one; v.w += one;
                }
                *(float4*)(q.out + (size_t)rg * D_ + c4) = v;
            }
        }
    }
}

extern "C" void kernel_launch(void* const* d_in, const int* in_sizes, int n_in,
                              void* d_out, int out_size, void* d_ws, size_t ws_size,
                              hipStream_t stream) {
    (void)n_in; (void)out_size; (void)ws_size;
    const float* u_emb = (const float*)d_in[0];
    const float* i_emb = (const float*)d_in[1];
    const int* edge_u = (const int*)d_in[2];
    const int* edge_i = (const int*)d_in[3];
    const int* rui = (const int*)d_in[4];
    const int* riu = (const int*)d_in[5];
    const int* last_u_items = (const int*)d_in[6];
    const int* last_i_users = (const int*)d_in[7];
    const float* W1  = (const float*)d_in[8];
    const float* W2  = (const float*)d_in[9];
    const float* W1b = (const float*)d_in[10];
    const float* W2b = (const float*)d_in[11];
    const float* W3  = (const float*)d_in[12];
    const float* W4  = (const float*)d_in[13];
    const float* pV  = (const float*)d_in[14];
    const float* pK  = (const float*)d_in[15];
    const float* last_user_table = (const float*)d_in[16];
    const float* last_item_table = (const float*)d_in[17];

    const int NU = in_sizes[0] / D_;
    const int NI = in_sizes[1] / D_;
    const int E  = in_sizes[2];
    const int UMAXr = in_sizes[14] / D_;
    const int IMAXr = in_sizes[15] / D_;
    const int NSEG = NU + NI;

    size_t cur = 0;
    auto alloc = [&](size_t bytes) -> void* {
        void* p = (char*)d_ws + cur;
        cur += (bytes + 255) & ~(size_t)255;
        return p;
    };

    __bf16* Wb4   = (__bf16*)alloc(4 * 16384 * 2);
    __bf16* M2t   = (__bf16*)alloc(16384 * 2);
    __bf16* M3t   = (__bf16*)alloc(16384 * 2);
    __bf16* M4t   = (__bf16*)alloc(16384 * 2);
    __bf16* pVW2  = (__bf16*)alloc((size_t)UMAXr * D_ * 2);
    __bf16* pKW1  = (__bf16*)alloc((size_t)IMAXr * D_ * 2);
    __bf16* pVb   = (__bf16*)alloc((size_t)UMAXr * D_ * 2);
    __bf16* pKb   = (__bf16*)alloc((size_t)IMAXr * D_ * 2);
    __bf16* ub_emb = (__bf16*)alloc((size_t)NU * D_ * 2);
    __bf16* ib_emb = (__bf16*)alloc((size_t)NI * D_ * 2);
    __bf16* um_t  = (__bf16*)alloc((size_t)NU * D_ * 2);
    __bf16* li_t  = (__bf16*)alloc((size_t)NU * D_ * 2);
    __bf16* lu_t  = (__bf16*)alloc((size_t)NU * D_ * 2);
    __bf16* upv   = (__bf16*)alloc((size_t)NU * UMAXr * 2);
    __bf16* ipk   = (__bf16*)alloc((size_t)NI * IMAXr * 2);
    __bf16* A1n   = (__bf16*)alloc((size_t)NU * D_ * 2);
    __bf16* PKn   = (__bf16*)alloc((size_t)NU * D_ * 2);
    __bf16* A2n   = (__bf16*)alloc((size_t)NU * D_ * 2);
    __bf16* B1n   = (__bf16*)alloc((size_t)NI * D_ * 2);
    __bf16* PVn   = (__bf16*)alloc((size_t)NI * D_ * 2);
    __bf16* B2n   = (__bf16*)alloc((size_t)NI * D_ * 2);
    float2* mb_val = (float2*)alloc((size_t)E * 8);
    int2* u_list  = (int2*)alloc((size_t)E * 8);
    int* i_list   = (int*)alloc((size_t)E * 4);
    int* cnt_all  = (int*)alloc((size_t)NSEG * 4);
    int* off_all  = (int*)alloc((size_t)(NSEG + 1) * 4);
    int* pos_all  = (int*)alloc((size_t)NSEG * 4);
    int* parts    = (int*)alloc(1024 * 4);

    float* out = (float*)d_out;
    float* hLu = out;
    float* hSu = out + (size_t)NU * D_;
    float* hLi = out + (size_t)2 * NU * D_;
    float* hSi = out + (size_t)2 * NU * D_ + (size_t)NI * D_;

    // weight casts + combined matrices
    W4p w4; w4.p[0] = W1; w4.p[1] = W2; w4.p[2] = W1b; w4.p[3] = W2b;
    int npv = UMAXr * D_, npk = IMAXr * D_;
    cvt_small<<<(4 * 16384 + npv + npk + 255) / 256, 256, 0, stream>>>(w4, pV, pK, Wb4, pVb, pKb, npv, npk);
    prep_mats<<<128 + (UMAXr > IMAXr ? UMAXr : IMAXr), 128, 0, stream>>>(W1, W2, W3, W4, pV, pK,
                                                                         M2t, M3t, M4t, pVW2, pKW1, UMAXr, IMAXr);
    size_t nue = (size_t)NU * D_, nie = (size_t)NI * D_;
    cvt_emb<<<(int)(((nue + nie) / 4 + 255) / 256), 256, 0, stream>>>(u_emb, i_emb, ub_emb, ib_emb, nue, nie);

    // CSR build
    hipMemsetAsync(cnt_all, 0, (size_t)NSEG * 4, stream);
    hist2<<<(E + 255) / 256, 256, 0, stream>>>(edge_u, edge_i, cnt_all, NU, E);
    int nb = (NSEG + SCAN_TILE - 1) / SCAN_TILE;
    scan_phaseA<<<nb, 256, 0, stream>>>(cnt_all, parts, NSEG);
    scan_phaseB<<<1, 1024, 0, stream>>>(parts, nb, off_all, NSEG);
    scan_phaseC<<<nb, 256, 0, stream>>>(cnt_all, parts, off_all, pos_all, NSEG);
    scatter2<<<(E + 255) / 256, 256, 0, stream>>>(edge_u, edge_i, rui, riu, pos_all, u_list, i_list, NU, E);

    // transformed user vectors + positional dot tables
    int gu = (NU + 63) / 64, gi = (NI + 63) / 64;
    user_vecs<<<gu, 256, 0, stream>>>(u_emb, last_item_table, last_u_items, last_user_table, last_i_users,
                                      M2t, M3t, M4t, um_t, li_t, lu_t, NU);
    Pvk2 pv2;
    pv2.a[0] = {ub_emb, pVW2, upv, NU, UMAXr};
    pv2.a[1] = {ib_emb, pKW1, ipk, NI, IMAXr};
    gemm_pvk2<<<dim3((gu > gi ? gu : gi), 2), 256, 0, stream>>>(pv2);

    // edge passes
    user_pass<<<(NU + 3) / 4, 256, 0, stream>>>(off_all, u_list, ib_emb, um_t, li_t, lu_t,
                                                pKb, upv, mb_val, A1n, PKn, A2n, NU, UMAXr);
    item_pass<<<(NI + 3) / 4, 256, 0, stream>>>(off_all, i_list, ub_emb, pVb, ipk, mb_val,
                                                B1n, PVn, B2n, NU, NI, IMAXr, E);

    // finish projections (one launch, 4 configs)
    int fu = (NU + 255) / 256, fi = (NI + 255) / 256;
    Fin4 fa;
    fa.f[0] = {A1n, Wb4 + 2 * 16384, PKn, nullptr, hLu, NU};
    fa.f[1] = {A2n, Wb4 + 0 * 16384, nullptr, off_all, hSu, NU};
    fa.f[2] = {B1n, Wb4 + 3 * 16384, PVn, nullptr, hLi, NI};
    fa.f[3] = {B2n, Wb4 + 1 * 16384, nullptr, off_all + NU, hSi, NI};
    finish4<<<dim3((fu > fi ? fu : fi), 4), 256, 0, stream>>>(fa);
}

// Round 13
// 488.440 us; speedup vs baseline: 1.2218x; 1.0412x over previous
//
#include <hip/hip_runtime.h>
#include <hip/hip_bf16.h>
#include <math.h>

#define D_ 128
#define INV_SQRT_D 0.08838834764831845f
#define SCAN_CH 16
#define SCAN_TILE (256 * SCAN_CH)

typedef __bf16 bf16x8 __attribute__((ext_vector_type(8)));
typedef float f32x4 __attribute__((ext_vector_type(4)));

struct W4p { const float* p[4]; };

__device__ __forceinline__ void unpack8(bf16x8 v, float* f) {
    const uint32_t* u = (const uint32_t*)&v;
#pragma unroll
    for (int i = 0; i < 4; i++) {
        uint32_t w = u[i];
        f[2 * i]     = __uint_as_float(w << 16);
        f[2 * i + 1] = __uint_as_float(w & 0xffff0000u);
    }
}

__device__ __forceinline__ bf16x8 pack8(const float* f, float s) {
    bf16x8 r;
#pragma unroll
    for (int j = 0; j < 8; j++) r[j] = (__bf16)(f[j] * s);
    return r;
}

__device__ __forceinline__ float bf2f(__bf16 v) {
    return __uint_as_float((uint32_t)(*(unsigned short*)&v) << 16);
}

// ---------------- casts: weights + pV/pK in one kernel ----------------
__global__ __launch_bounds__(256) void cvt_small(W4p w, const float* __restrict__ pV, const float* __restrict__ pK,
                                                 __bf16* __restrict__ outW, __bf16* __restrict__ pVb,
                                                 __bf16* __restrict__ pKb, int npv, int npk) {
    int idx = blockIdx.x * 256 + threadIdx.x;
    if (idx < 4 * 16384) {
        outW[idx] = (__bf16)w.p[idx >> 14][idx & 16383];
    } else if (idx - 4 * 16384 < npv) {
        int j = idx - 4 * 16384;
        pVb[j] = (__bf16)pV[j];
    } else if (idx - 4 * 16384 - npv < npk) {
        int j = idx - 4 * 16384 - npv;
        pKb[j] = (__bf16)pK[j];
    }
}

__global__ __launch_bounds__(256) void cvt_emb(const float* __restrict__ u, const float* __restrict__ i,
                                               __bf16* __restrict__ ub, __bf16* __restrict__ ib,
                                               size_t nue, size_t nie) {
    size_t idx4 = ((size_t)blockIdx.x * 256 + threadIdx.x) * 4;
    if (idx4 < nue) {
        float4 v = *(const float4*)(u + idx4);
        ub[idx4] = (__bf16)v.x; ub[idx4+1] = (__bf16)v.y; ub[idx4+2] = (__bf16)v.z; ub[idx4+3] = (__bf16)v.w;
    } else if (idx4 < nue + nie) {
        size_t j = idx4 - nue;
        float4 v = *(const float4*)(i + j);
        ib[j] = (__bf16)v.x; ib[j+1] = (__bf16)v.y; ib[j+2] = (__bf16)v.z; ib[j+3] = (__bf16)v.w;
    }
}

// ---------------- combined-matrix prep ----------------
__global__ __launch_bounds__(128) void prep_mats(const float* __restrict__ W1, const float* __restrict__ W2,
                                                 const float* __restrict__ W3, const float* __restrict__ W4,
                                                 const float* __restrict__ pV, const float* __restrict__ pK,
                                                 __bf16* __restrict__ M2t, __bf16* __restrict__ M3t,
                                                 __bf16* __restrict__ M4t,
                                                 __bf16* __restrict__ pVW2, __bf16* __restrict__ pKW1,
                                                 int umax, int imax) {
    __shared__ float sh[256];
    int b = blockIdx.x, t = threadIdx.x;
    if (b < 128) {
        sh[t] = W1[t * 128 + b];
        __syncthreads();
        float m2 = 0.f, m3 = 0.f, m4 = 0.f;
        for (int k = 0; k < 128; k++) {
            float w = sh[k];
            m2 = fmaf(w, W2[k * 128 + t], m2);
            m3 = fmaf(w, W3[k * 128 + t], m3);
            m4 = fmaf(w, W4[k * 128 + t], m4);
        }
        M2t[b * 128 + t] = (__bf16)(m2 * INV_SQRT_D);
        M3t[b * 128 + t] = (__bf16)(m3 * INV_SQRT_D);
        M4t[b * 128 + t] = (__bf16)(m4 * INV_SQRT_D);
    } else {
        int r = b - 128;
        if (r < umax) sh[t] = pV[r * 128 + t];
        if (r < imax) sh[128 + t] = pK[r * 128 + t];
        __syncthreads();
        float q = 0.f, qk = 0.f;
        for (int a = 0; a < 128; a++) {
            if (r < umax) q  = fmaf(sh[a], W2[a * 128 + t], q);
            if (r < imax) qk = fmaf(sh[128 + a], W1[a * 128 + t], qk);
        }
        if (r < umax) pVW2[r * 128 + t] = (__bf16)(q * INV_SQRT_D);
        if (r < imax) pKW1[r * 128 + t] = (__bf16)(qk * INV_SQRT_D);
    }
}

// ---------------- user transformed vectors ----------------
__global__ __launch_bounds__(256) void user_vecs(const float* __restrict__ u_emb,
                                                 const float* __restrict__ lit_tab, const int* __restrict__ g_li,
                                                 const float* __restrict__ lut_tab, const int* __restrict__ g_lu,
                                                 const __bf16* __restrict__ M2t, const __bf16* __restrict__ M3t,
                                                 const __bf16* __restrict__ M4t,
                                                 __bf16* __restrict__ um_t, __bf16* __restrict__ li_t,
                                                 __bf16* __restrict__ lu_t, int rows) {
    int lane = threadIdx.x & 63;
    int wave = threadIdx.x >> 6;
    int row0 = blockIdx.x * 64 + wave * 16;
    if (row0 >= rows) return;
    int l16 = lane & 15, kh = lane >> 4;
    int ar = row0 + l16;
    int arc = ar < rows ? ar : rows - 1;
    const float* rA = u_emb + (size_t)arc * D_;
    const float* rB = lit_tab + (size_t)g_li[arc] * D_;
    const float* rC = lut_tab + (size_t)g_lu[arc] * D_;

    f32x4 aA[8] = {}, aB[8] = {}, aC[8] = {};
#pragma unroll
    for (int k0 = 0; k0 < D_; k0 += 32) {
        int kk = k0 + kh * 8;
        float4 a0 = *(const float4*)(rA + kk), a1 = *(const float4*)(rA + kk + 4);
        float4 b0 = *(const float4*)(rB + kk), b1 = *(const float4*)(rB + kk + 4);
        float4 c0 = *(const float4*)(rC + kk), c1 = *(const float4*)(rC + kk + 4);
        bf16x8 fA, fB, fC;
        fA[0]=(__bf16)a0.x; fA[1]=(__bf16)a0.y; fA[2]=(__bf16)a0.z; fA[3]=(__bf16)a0.w;
        fA[4]=(__bf16)a1.x; fA[5]=(__bf16)a1.y; fA[6]=(__bf16)a1.z; fA[7]=(__bf16)a1.w;
        fB[0]=(__bf16)b0.x; fB[1]=(__bf16)b0.y; fB[2]=(__bf16)b0.z; fB[3]=(__bf16)b0.w;
        fB[4]=(__bf16)b1.x; fB[5]=(__bf16)b1.y; fB[6]=(__bf16)b1.z; fB[7]=(__bf16)b1.w;
        fC[0]=(__bf16)c0.x; fC[1]=(__bf16)c0.y; fC[2]=(__bf16)c0.z; fC[3]=(__bf16)c0.w;
        fC[4]=(__bf16)c1.x; fC[5]=(__bf16)c1.y; fC[6]=(__bf16)c1.z; fC[7]=(__bf16)c1.w;
#pragma unroll
        for (int cb = 0; cb < 8; cb++) {
            bf16x8 w2 = *(const bf16x8*)(M2t + (size_t)(cb * 16 + l16) * D_ + kk);
            aA[cb] = __builtin_amdgcn_mfma_f32_16x16x32_bf16(fA, w2, aA[cb], 0, 0, 0);
            bf16x8 w3 = *(const bf16x8*)(M3t + (size_t)(cb * 16 + l16) * D_ + kk);
            aB[cb] = __builtin_amdgcn_mfma_f32_16x16x32_bf16(fB, w3, aB[cb], 0, 0, 0);
            bf16x8 w4 = *(const bf16x8*)(M4t + (size_t)(cb * 16 + l16) * D_ + kk);
            aC[cb] = __builtin_amdgcn_mfma_f32_16x16x32_bf16(fC, w4, aC[cb], 0, 0, 0);
        }
    }
#pragma unroll
    for (int cb = 0; cb < 8; cb++) {
#pragma unroll
        for (int j = 0; j < 4; j++) {
            int r = row0 + kh * 4 + j;
            if (r < rows) {
                um_t[(size_t)r * D_ + cb * 16 + l16] = (__bf16)aA[cb][j];
                li_t[(size_t)r * D_ + cb * 16 + l16] = (__bf16)aB[cb][j];
                lu_t[(size_t)r * D_ + cb * 16 + l16] = (__bf16)aC[cb][j];
            }
        }
    }
}

// ---------------- merged positional-dot GEMMs: Y(rows x ncols bf16) = Xb @ P^T ----------------
struct PvkA { const __bf16* X; const __bf16* P; __bf16* Y; int rows; int ncols; };
struct Pvk2 { PvkA a[2]; };
__global__ __launch_bounds__(256) void gemm_pvk2(Pvk2 p) {
    PvkA q = p.a[blockIdx.y];
    int lane = threadIdx.x & 63;
    int wave = threadIdx.x >> 6;
    int row0 = blockIdx.x * 64 + wave * 16;
    if (row0 >= q.rows) return;
    int l16 = lane & 15, kh = lane >> 4;
    int ar = row0 + l16;
    int arc = ar < q.rows ? ar : q.rows - 1;
    const __bf16* arow = q.X + (size_t)arc * D_;

    f32x4 acc[4] = {};
#pragma unroll
    for (int k0 = 0; k0 < D_; k0 += 32) {
        int kk = k0 + kh * 8;
        bf16x8 af = *(const bf16x8*)(arow + kk);
#pragma unroll
        for (int cb = 0; cb < 4; cb++) {
            int br = cb * 16 + l16;
            if (br >= q.ncols) br = q.ncols - 1;
            bf16x8 bf = *(const bf16x8*)(q.P + (size_t)br * D_ + kk);
            acc[cb] = __builtin_amdgcn_mfma_f32_16x16x32_bf16(af, bf, acc[cb], 0, 0, 0);
        }
    }
#pragma unroll
    for (int cb = 0; cb < 4; cb++) {
        int col = cb * 16 + l16;
        if (col >= q.ncols) continue;
#pragma unroll
        for (int j = 0; j < 4; j++) {
            int r = row0 + kh * 4 + j;
            if (r < q.rows) q.Y[(size_t)r * q.ncols + col] = (__bf16)acc[cb][j];
        }
    }
}

// ---------------- CSR build ----------------
__global__ __launch_bounds__(256) void hist2(const int* __restrict__ eu, const int* __restrict__ ei,
                                             int* __restrict__ cnt_all, int nu, int E) {
    int e = blockIdx.x * 256 + threadIdx.x;
    if (e < E) {
        atomicAdd(&cnt_all[eu[e]], 1);
        atomicAdd(&cnt_all[nu + ei[e]], 1);
    }
}

__global__ __launch_bounds__(256) void scan_phaseA(const int* __restrict__ cnt, int* __restrict__ part, int n) {
    __shared__ int wsum[4];
    int t = threadIdx.x, lane = t & 63, w = t >> 6;
    int i0 = blockIdx.x * SCAN_TILE + t * SCAN_CH;
    int tot = 0;
#pragma unroll
    for (int j = 0; j < SCAN_CH; j++) tot += (i0 + j < n) ? cnt[i0 + j] : 0;
#pragma unroll
    for (int d = 32; d; d >>= 1) tot += __shfl_xor(tot, d);
    if (lane == 0) wsum[w] = tot;
    __syncthreads();
    if (t == 0) part[blockIdx.x] = wsum[0] + wsum[1] + wsum[2] + wsum[3];
}

__global__ __launch_bounds__(1024) void scan_phaseB(int* __restrict__ part, int nb,
                                                    int* __restrict__ off, int n) {
    __shared__ int wsum[16];
    int t = threadIdx.x, lane = t & 63, w = t >> 6;
    int v = (t < nb) ? part[t] : 0;
    int x = v;
#pragma unroll
    for (int d = 1; d < 64; d <<= 1) {
        int y = __shfl_up(x, d);
        if (lane >= d) x += y;
    }
    if (lane == 63) wsum[w] = x;
    __syncthreads();
    int wbase = 0;
    for (int ww = 0; ww < w; ww++) wbase += wsum[ww];
    if (t < nb) part[t] = wbase + x - v;
    if (t == 1023) off[n] = wbase + x;
}

__global__ __launch_bounds__(256) void scan_phaseC(const int* __restrict__ cnt, const int* __restrict__ part,
                                                   int* __restrict__ off, int* __restrict__ pos, int n) {
    __shared__ int wsum[4];
    int t = threadIdx.x, lane = t & 63, w = t >> 6;
    int i0 = blockIdx.x * SCAN_TILE + t * SCAN_CH;
    int loc[SCAN_CH];
    int tot = 0;
#pragma unroll
    for (int j = 0; j < SCAN_CH; j++) {
        int v = (i0 + j < n) ? cnt[i0 + j] : 0;
        loc[j] = tot; tot += v;
    }
    int x = tot;
#pragma unroll
    for (int d = 1; d < 64; d <<= 1) {
        int y = __shfl_up(x, d);
        if (lane >= d) x += y;
    }
    if (lane == 63) wsum[w] = x;
    __syncthreads();
    int wbase = 0;
    for (int ww = 0; ww < w; ww++) wbase += wsum[ww];
    int excl = part[blockIdx.x] + wbase + x - tot;
#pragma unroll
    for (int j = 0; j < SCAN_CH; j++) {
        if (i0 + j < n) { off[i0 + j] = excl + loc[j]; pos[i0 + j] = excl + loc[j]; }
    }
}

// scatter packed: user list gets int2{it|rui<<18|riu<<24, item_slot}; item list gets int{u|rui<<18|riu<<24}
__global__ __launch_bounds__(256) void scatter2(const int* __restrict__ eu, const int* __restrict__ ei,
                                                const int* __restrict__ rui, const int* __restrict__ riu,
                                                int* __restrict__ pos_all, int2* __restrict__ u_list,
                                                int* __restrict__ i_list, int nu, int E) {
    int e = blockIdx.x * 256 + threadIdx.x;
    if (e < E) {
        int u = eu[e], it = ei[e], r1 = rui[e], r2 = riu[e];
        int rbits = (r1 << 18) | (r2 << 24);
        int pi = atomicAdd(&pos_all[nu + it], 1) - E;
        int pu = atomicAdd(&pos_all[u], 1);
        u_list[pu] = make_int2(it | rbits, pi);
        i_list[pi] = u | rbits;
    }
}

// ---------------- user pass ----------------
__global__ __launch_bounds__(256) void user_pass(const int* __restrict__ off_all, const int2* __restrict__ u_list,
                                                 const __bf16* __restrict__ ib_emb,
                                                 const __bf16* __restrict__ um_t,
                                                 const __bf16* __restrict__ li_t,
                                                 const __bf16* __restrict__ lu_t,
                                                 const __bf16* __restrict__ pKb,
                                                 const __bf16* __restrict__ upv,
                                                 float2* __restrict__ mb_val,
                                                 __bf16* __restrict__ A1n, __bf16* __restrict__ PKn,
                                                 __bf16* __restrict__ A2n, int nu, int umax) {
    int u = blockIdx.x * 4 + (threadIdx.x >> 6);
    if (u >= nu) return;
    int lane = threadIdx.x & 63;
    int g = lane >> 4, l16 = lane & 15;
    int off = off_all[u], n = off_all[u + 1] - off;
    if (n == 0) {
        if (lane < 16) {
            bf16x8 z = {};
            *(bf16x8*)(A1n + (size_t)u * D_ + l16 * 8) = z;
            *(bf16x8*)(PKn + (size_t)u * D_ + l16 * 8) = z;
            *(bf16x8*)(A2n + (size_t)u * D_ + l16 * 8) = z;
        }
        return;
    }
    float um8[8], li8[8], lu8[8];
    unpack8(((const bf16x8*)(um_t + (size_t)u * D_))[l16], um8);
    unpack8(((const bf16x8*)(li_t + (size_t)u * D_))[l16], li8);
    unpack8(((const bf16x8*)(lu_t + (size_t)u * D_))[l16], lu8);
    const __bf16* upv_row = upv + (size_t)u * umax;

    float s1 = 0.f, s2 = 0.f, a1[8] = {}, apk[8] = {}, a2[8] = {};
    for (int i = g; i < n; i += 8) {
        int2 ra = u_list[off + i];
        bool hb = (i + 4) < n;
        int2 rb = u_list[off + (hb ? i + 4 : i)];
        int itA = ra.x & 0x3FFFF, r1A = (ra.x >> 18) & 0x3F, r2A = (ra.x >> 24) & 0x3F;
        int itB = rb.x & 0x3FFFF, r1B = (rb.x >> 18) & 0x3F, r2B = (rb.x >> 24) & 0x3F;
        bf16x8 vieA = ((const bf16x8*)(ib_emb + (size_t)itA * D_))[l16];
        bf16x8 vpkA = ((const bf16x8*)(pKb + (size_t)r2A * D_))[l16];
        bf16x8 vieB = ((const bf16x8*)(ib_emb + (size_t)itB * D_))[l16];
        bf16x8 vpkB = ((const bf16x8*)(pKb + (size_t)r2B * D_))[l16];
        float fieA[8], fpkA[8], fieB[8], fpkB[8];
        unpack8(vieA, fieA); unpack8(vpkA, fpkA);
        unpack8(vieB, fieB); unpack8(vpkB, fpkB);
        float d1a = 0.f, d2a = 0.f, d3a = 0.f, d1b = 0.f, d2b = 0.f, d3b = 0.f;
#pragma unroll
        for (int j = 0; j < 8; j++) {
            d1a = fmaf(um8[j], fieA[j], d1a);
            d2a = fmaf(li8[j], fieA[j], d2a);
            d3a = fmaf(lu8[j], fieA[j], d3a);
            d1b = fmaf(um8[j], fieB[j], d1b);
            d2b = fmaf(li8[j], fieB[j], d2b);
            d3b = fmaf(lu8[j], fieB[j], d3b);
        }
#pragma unroll
        for (int d = 1; d < 16; d <<= 1) {
            d1a += __shfl_xor(d1a, d); d2a += __shfl_xor(d2a, d); d3a += __shfl_xor(d3a, d);
            d1b += __shfl_xor(d1b, d); d2b += __shfl_xor(d2b, d); d3b += __shfl_xor(d3b, d);
        }
        if (l16 == 0) {
            mb_val[ra.y] = make_float2(d1a, d3a);
            if (hb) mb_val[rb.y] = make_float2(d1b, d3b);
        }
        float w1a = __expf(d1a + bf2f(upv_row[r1A]));
        float w2a = __expf(d2a);
        float w1b = hb ? __expf(d1b + bf2f(upv_row[r1B])) : 0.f;
        float w2b = hb ? __expf(d2b) : 0.f;
        s1 += w1a + w1b; s2 += w2a + w2b;
#pragma unroll
        for (int j = 0; j < 8; j++) {
            a1[j]  = fmaf(w1a, fieA[j], fmaf(w1b, fieB[j], a1[j]));
            apk[j] = fmaf(w1a, fpkA[j], fmaf(w1b, fpkB[j], apk[j]));
            a2[j]  = fmaf(w2a, fieA[j], fmaf(w2b, fieB[j], a2[j]));
        }
    }
#pragma unroll
    for (int d = 16; d < 64; d <<= 1) {
        s1 += __shfl_xor(s1, d); s2 += __shfl_xor(s2, d);
#pragma unroll
        for (int j = 0; j < 8; j++) {
            a1[j]  += __shfl_xor(a1[j], d);
            apk[j] += __shfl_xor(apk[j], d);
            a2[j]  += __shfl_xor(a2[j], d);
        }
    }
    if (lane < 16) {
        float inv1 = 1.f / s1, inv2 = 1.f / s2;
        *(bf16x8*)(A1n + (size_t)u * D_ + l16 * 8) = pack8(a1, inv1);
        *(bf16x8*)(PKn + (size_t)u * D_ + l16 * 8) = pack8(apk, inv1);
        *(bf16x8*)(A2n + (size_t)u * D_ + l16 * 8) = pack8(a2, inv2);
    }
}

// ---------------- item pass ----------------
__global__ __launch_bounds__(256) void item_pass(const int* __restrict__ off_all, const int* __restrict__ i_list,
                                                 const __bf16* __restrict__ ub_emb,
                                                 const __bf16* __restrict__ pVb,
                                                 const __bf16* __restrict__ ipk,
                                                 const float2* __restrict__ mb_val,
                                                 __bf16* __restrict__ B1n, __bf16* __restrict__ PVn,
                                                 __bf16* __restrict__ B2n, int nu, int ni, int imax, int E) {
    int it = blockIdx.x * 4 + (threadIdx.x >> 6);
    if (it >= ni) return;
    int lane = threadIdx.x & 63;
    int g = lane >> 4, l16 = lane & 15;
    int ioff = off_all[nu + it] - E, n = off_all[nu + it + 1] - E - ioff;
    if (n == 0) {
        if (lane < 16) {
            bf16x8 z = {};
            *(bf16x8*)(B1n + (size_t)it * D_ + l16 * 8) = z;
            *(bf16x8*)(PVn + (size_t)it * D_ + l16 * 8) = z;
            *(bf16x8*)(B2n + (size_t)it * D_ + l16 * 8) = z;
        }
        return;
    }
    const __bf16* ipk_row = ipk + (size_t)it * imax;

    float s1 = 0.f, s2 = 0.f, b1[8] = {}, bpv[8] = {}, b2[8] = {};
    for (int i = g; i < n; i += 8) {
        int pa = i_list[ioff + i];
        bool hb = (i + 4) < n;
        int pb = i_list[ioff + (hb ? i + 4 : i)];
        int uA = pa & 0x3FFFF, r1A = (pa >> 18) & 0x3F, r2A = (pa >> 24) & 0x3F;
        int uB = pb & 0x3FFFF, r1B = (pb >> 18) & 0x3F, r2B = (pb >> 24) & 0x3F;
        float2 ma = mb_val[ioff + i];
        float2 mbv = hb ? mb_val[ioff + i + 4] : make_float2(0.f, 0.f);
        bf16x8 vueA = ((const bf16x8*)(ub_emb + (size_t)uA * D_))[l16];
        bf16x8 vpvA = ((const bf16x8*)(pVb + (size_t)r1A * D_))[l16];
        bf16x8 vueB = ((const bf16x8*)(ub_emb + (size_t)uB * D_))[l16];
        bf16x8 vpvB = ((const bf16x8*)(pVb + (size_t)r1B * D_))[l16];
        float fueA[8], fpvA[8], fueB[8], fpvB[8];
        unpack8(vueA, fueA); unpack8(vpvA, fpvA);
        unpack8(vueB, fueB); unpack8(vpvB, fpvB);
        float w1a = __expf(ma.x + bf2f(ipk_row[r2A]));
        float w2a = __expf(ma.y);
        float w1b = hb ? __expf(mbv.x + bf2f(ipk_row[r2B])) : 0.f;
        float w2b = hb ? __expf(mbv.y) : 0.f;
        s1 += w1a + w1b; s2 += w2a + w2b;
#pragma unroll
        for (int j = 0; j < 8; j++) {
            b1[j]  = fmaf(w1a, fueA[j], fmaf(w1b, fueB[j], b1[j]));
            bpv[j] = fmaf(w1a, fpvA[j], fmaf(w1b, fpvB[j], bpv[j]));
            b2[j]  = fmaf(w2a, fueA[j], fmaf(w2b, fueB[j], b2[j]));
        }
    }
#pragma unroll
    for (int d = 16; d < 64; d <<= 1) {
        s1 += __shfl_xor(s1, d); s2 += __shfl_xor(s2, d);
#pragma unroll
        for (int j = 0; j < 8; j++) {
            b1[j]  += __shfl_xor(b1[j], d);
            bpv[j] += __shfl_xor(bpv[j], d);
            b2[j]  += __shfl_xor(b2[j], d);
        }
    }
    if (lane < 16) {
        float inv1 = 1.f / s1, inv2 = 1.f / s2;
        *(bf16x8*)(B1n + (size_t)it * D_ + l16 * 8) = pack8(b1, inv1);
        *(bf16x8*)(PVn + (size_t)it * D_ + l16 * 8) = pack8(bpv, inv1);
        *(bf16x8*)(B2n + (size_t)it * D_ + l16 * 8) = pack8(b2, inv2);
    }
}

// ---------------- finish GEMM (4 configs via blockIdx.y), swapped-operand direct-store epilogue ----------------
// acc[cc] = mfma(a=W frag, b=A frag) -> lane(l16,kh) holds out[rowblk+l16][cc*16 + kh*4 + j]
struct FinArgs { const __bf16* A; const __bf16* W; const __bf16* side; const int* offseg; float* out; int rows; };
struct Fin4 { FinArgs f[4]; };
__global__ __launch_bounds__(256) void finish4(Fin4 fa) {
    FinArgs q = fa.f[blockIdx.y];
    if (blockIdx.x * 256 >= (unsigned)q.rows) return;
    __shared__ __bf16 sW[128][136];
    int t = threadIdx.x;
#pragma unroll
    for (int it = 0; it < 8; it++) {
        int slot = it * 256 + t;
        int r = slot >> 4, c16 = (slot & 15) * 8;
        bf16x8 v = *(const bf16x8*)(q.W + (size_t)r * D_ + c16);
        *(bf16x8*)(&sW[r][c16]) = v;
    }
    __syncthreads();
    int lane = t & 63, wave = t >> 6;
    int l16 = lane & 15, kh = lane >> 4;

    for (int tt = 0; tt < 4; tt++) {
        int rowblk = blockIdx.x * 256 + (tt * 4 + wave) * 16;
        if (rowblk >= q.rows) break;
        int ar = rowblk + l16;
        bool rok = ar < q.rows;
        int arc = rok ? ar : q.rows - 1;
        const __bf16* rA = q.A + (size_t)arc * D_;
        bf16x8 b0 = *(const bf16x8*)(rA + kh * 8);
        bf16x8 b1 = *(const bf16x8*)(rA + 32 + kh * 8);
        bf16x8 b2 = *(const bf16x8*)(rA + 64 + kh * 8);
        bf16x8 b3 = *(const bf16x8*)(rA + 96 + kh * 8);
        float addv = 0.f;
        if (!q.side && rok) addv = (q.offseg[ar + 1] - q.offseg[ar]) > 0 ? 1.f : 0.f;
#pragma unroll
        for (int cc = 0; cc < 8; cc++) {
            int wr = cc * 16 + l16;
            f32x4 acc = {};
            acc = __builtin_amdgcn_mfma_f32_16x16x32_bf16(*(const bf16x8*)(&sW[wr][kh * 8]), b0, acc, 0, 0, 0);
            acc = __builtin_amdgcn_mfma_f32_16x16x32_bf16(*(const bf16x8*)(&sW[wr][32 + kh * 8]), b1, acc, 0, 0, 0);
            acc = __builtin_amdgcn_mfma_f32_16x16x32_bf16(*(const bf16x8*)(&sW[wr][64 + kh * 8]), b2, acc, 0, 0, 0);
            acc = __builtin_amdgcn_mfma_f32_16x16x32_bf16(*(const bf16x8*)(&sW[wr][96 + kh * 8]), b3, acc, 0, 0, 0);
            if (rok) {
                int col = cc * 16 + kh * 4;
                float4 v = make_float4(acc[0], acc[1], acc[2], acc[3]);
                if (q.side) {
                    ushort4 sv = *(const ushort4*)((const unsigned short*)q.side + (size_t)ar * D_ + col);
                    v.x += __uint_as_float((uint32_t)sv.x << 16);
                    v.y += __uint_as_float((uint32_t)sv.y << 16);
                    v.z += __uint_as_float((uint32_t)sv.z << 16);
                    v.w += __uint_as_float((uint32_t)sv.w << 16);
                } else {
                    v.x += addv; v.y += addv; v.z += addv; v.w += addv;
                }
                *(float4*)(q.out + (size_t)ar * D_ + col) = v;
            }
        }
    }
}

extern "C" void kernel_launch(void* const* d_in, const int* in_sizes, int n_in,
                              void* d_out, int out_size, void* d_ws, size_t ws_size,
                              hipStream_t stream) {
    (void)n_in; (void)out_size; (void)ws_size;
    const float* u_emb = (const float*)d_in[0];
    const float* i_emb = (const float*)d_in[1];
    const int* edge_u = (const int*)d_in[2];
    const int* edge_i = (const int*)d_in[3];
    const int* rui = (const int*)d_in[4];
    const int* riu = (const int*)d_in[5];
    const int* last_u_items = (const int*)d_in[6];
    const int* last_i_users = (const int*)d_in[7];
    const float* W1  = (const float*)d_in[8];
    const float* W2  = (const float*)d_in[9];
    const float* W1b = (const float*)d_in[10];
    const float* W2b = (const float*)d_in[11];
    const float* W3  = (const float*)d_in[12];
    const float* W4  = (const float*)d_in[13];
    const float* pV  = (const float*)d_in[14];
    const float* pK  = (const float*)d_in[15];
    const float* last_user_table = (const float*)d_in[16];
    const float* last_item_table = (const float*)d_in[17];

    const int NU = in_sizes[0] / D_;
    const int NI = in_sizes[1] / D_;
    const int E  = in_sizes[2];
    const int UMAXr = in_sizes[14] / D_;
    const int IMAXr = in_sizes[15] / D_;
    const int NSEG = NU + NI;

    size_t cur = 0;
    auto alloc = [&](size_t bytes) -> void* {
        void* p = (char*)d_ws + cur;
        cur += (bytes + 255) & ~(size_t)255;
        return p;
    };

    __bf16* Wb4   = (__bf16*)alloc(4 * 16384 * 2);
    __bf16* M2t   = (__bf16*)alloc(16384 * 2);
    __bf16* M3t   = (__bf16*)alloc(16384 * 2);
    __bf16* M4t   = (__bf16*)alloc(16384 * 2);
    __bf16* pVW2  = (__bf16*)alloc((size_t)UMAXr * D_ * 2);
    __bf16* pKW1  = (__bf16*)alloc((size_t)IMAXr * D_ * 2);
    __bf16* pVb   = (__bf16*)alloc((size_t)UMAXr * D_ * 2);
    __bf16* pKb   = (__bf16*)alloc((size_t)IMAXr * D_ * 2);
    __bf16* ub_emb = (__bf16*)alloc((size_t)NU * D_ * 2);
    __bf16* ib_emb = (__bf16*)alloc((size_t)NI * D_ * 2);
    __bf16* um_t  = (__bf16*)alloc((size_t)NU * D_ * 2);
    __bf16* li_t  = (__bf16*)alloc((size_t)NU * D_ * 2);
    __bf16* lu_t  = (__bf16*)alloc((size_t)NU * D_ * 2);
    __bf16* upv   = (__bf16*)alloc((size_t)NU * UMAXr * 2);
    __bf16* ipk   = (__bf16*)alloc((size_t)NI * IMAXr * 2);
    __bf16* A1n   = (__bf16*)alloc((size_t)NU * D_ * 2);
    __bf16* PKn   = (__bf16*)alloc((size_t)NU * D_ * 2);
    __bf16* A2n   = (__bf16*)alloc((size_t)NU * D_ * 2);
    __bf16* B1n   = (__bf16*)alloc((size_t)NI * D_ * 2);
    __bf16* PVn   = (__bf16*)alloc((size_t)NI * D_ * 2);
    __bf16* B2n   = (__bf16*)alloc((size_t)NI * D_ * 2);
    float2* mb_val = (float2*)alloc((size_t)E * 8);
    int2* u_list  = (int2*)alloc((size_t)E * 8);
    int* i_list   = (int*)alloc((size_t)E * 4);
    int* cnt_all  = (int*)alloc((size_t)NSEG * 4);
    int* off_all  = (int*)alloc((size_t)(NSEG + 1) * 4);
    int* pos_all  = (int*)alloc((size_t)NSEG * 4);
    int* parts    = (int*)alloc(1024 * 4);

    float* out = (float*)d_out;
    float* hLu = out;
    float* hSu = out + (size_t)NU * D_;
    float* hLi = out + (size_t)2 * NU * D_;
    float* hSi = out + (size_t)2 * NU * D_ + (size_t)NI * D_;

    // weight casts + combined matrices
    W4p w4; w4.p[0] = W1; w4.p[1] = W2; w4.p[2] = W1b; w4.p[3] = W2b;
    int npv = UMAXr * D_, npk = IMAXr * D_;
    cvt_small<<<(4 * 16384 + npv + npk + 255) / 256, 256, 0, stream>>>(w4, pV, pK, Wb4, pVb, pKb, npv, npk);
    prep_mats<<<128 + (UMAXr > IMAXr ? UMAXr : IMAXr), 128, 0, stream>>>(W1, W2, W3, W4, pV, pK,
                                                                         M2t, M3t, M4t, pVW2, pKW1, UMAXr, IMAXr);
    size_t nue = (size_t)NU * D_, nie = (size_t)NI * D_;
    cvt_emb<<<(int)(((nue + nie) / 4 + 255) / 256), 256, 0, stream>>>(u_emb, i_emb, ub_emb, ib_emb, nue, nie);

    // CSR build
    hipMemsetAsync(cnt_all, 0, (size_t)NSEG * 4, stream);
    hist2<<<(E + 255) / 256, 256, 0, stream>>>(edge_u, edge_i, cnt_all, NU, E);
    int nb = (NSEG + SCAN_TILE - 1) / SCAN_TILE;
    scan_phaseA<<<nb, 256, 0, stream>>>(cnt_all, parts, NSEG);
    scan_phaseB<<<1, 1024, 0, stream>>>(parts, nb, off_all, NSEG);
    scan_phaseC<<<nb, 256, 0, stream>>>(cnt_all, parts, off_all, pos_all, NSEG);
    scatter2<<<(E + 255) / 256, 256, 0, stream>>>(edge_u, edge_i, rui, riu, pos_all, u_list, i_list, NU, E);

    // transformed user vectors + positional dot tables
    int gu = (NU + 63) / 64, gi = (NI + 63) / 64;
    user_vecs<<<gu, 256, 0, stream>>>(u_emb, last_item_table, last_u_items, last_user_table, last_i_users,
                                      M2t, M3t, M4t, um_t, li_t, lu_t, NU);
    Pvk2 pv2;
    pv2.a[0] = {ub_emb, pVW2, upv, NU, UMAXr};
    pv2.a[1] = {ib_emb, pKW1, ipk, NI, IMAXr};
    gemm_pvk2<<<dim3((gu > gi ? gu : gi), 2), 256, 0, stream>>>(pv2);

    // edge passes
    user_pass<<<(NU + 3) / 4, 256, 0, stream>>>(off_all, u_list, ib_emb, um_t, li_t, lu_t,
                                                pKb, upv, mb_val, A1n, PKn, A2n, NU, UMAXr);
    item_pass<<<(NI + 3) / 4, 256, 0, stream>>>(off_all, i_list, ub_emb, pVb, ipk, mb_val,
                                                B1n, PVn, B2n, NU, NI, IMAXr, E);

    // finish projections (one launch, 4 configs)
    int fu = (NU + 255) / 256, fi = (NI + 255) / 256;
    Fin4 fa;
    fa.f[0] = {A1n, Wb4 + 2 * 16384, PKn, nullptr, hLu, NU};
    fa.f[1] = {A2n, Wb4 + 0 * 16384, nullptr, off_all, hSu, NU};
    fa.f[2] = {B1n, Wb4 + 3 * 16384, PVn, nullptr, hLi, NI};
    fa.f[3] = {B2n, Wb4 + 1 * 16384, nullptr, off_all + NU, hSi, NI};
    finish4<<<dim3((fu > fi ? fu : fi), 4), 256, 0, stream>>>(fa);
}

// Round 14
// 482.320 us; speedup vs baseline: 1.2373x; 1.0127x over previous
//
#include <hip/hip_runtime.h>
#include <hip/hip_bf16.h>
#include <math.h>

#define D_ 128
#define INV_SQRT_D 0.08838834764831845f
#define SCAN_CH 16
#define SCAN_TILE (256 * SCAN_CH)

typedef __bf16 bf16x8 __attribute__((ext_vector_type(8)));
typedef float f32x4 __attribute__((ext_vector_type(4)));

struct W4p { const float* p[4]; };

__device__ __forceinline__ void unpack8(bf16x8 v, float* f) {
    const uint32_t* u = (const uint32_t*)&v;
#pragma unroll
    for (int i = 0; i < 4; i++) {
        uint32_t w = u[i];
        f[2 * i]     = __uint_as_float(w << 16);
        f[2 * i + 1] = __uint_as_float(w & 0xffff0000u);
    }
}

__device__ __forceinline__ bf16x8 pack8(const float* f, float s) {
    bf16x8 r;
#pragma unroll
    for (int j = 0; j < 8; j++) r[j] = (__bf16)(f[j] * s);
    return r;
}

__device__ __forceinline__ float bf2f(__bf16 v) {
    return __uint_as_float((uint32_t)(*(unsigned short*)&v) << 16);
}

// ---------------- casts: weights + pV/pK in one kernel ----------------
__global__ __launch_bounds__(256) void cvt_small(W4p w, const float* __restrict__ pV, const float* __restrict__ pK,
                                                 __bf16* __restrict__ outW, __bf16* __restrict__ pVb,
                                                 __bf16* __restrict__ pKb, int npv, int npk) {
    int idx = blockIdx.x * 256 + threadIdx.x;
    if (idx < 4 * 16384) {
        outW[idx] = (__bf16)w.p[idx >> 14][idx & 16383];
    } else if (idx - 4 * 16384 < npv) {
        int j = idx - 4 * 16384;
        pVb[j] = (__bf16)pV[j];
    } else if (idx - 4 * 16384 - npv < npk) {
        int j = idx - 4 * 16384 - npv;
        pKb[j] = (__bf16)pK[j];
    }
}

__global__ __launch_bounds__(256) void cvt_emb(const float* __restrict__ u, const float* __restrict__ i,
                                               __bf16* __restrict__ ub, __bf16* __restrict__ ib,
                                               size_t nue, size_t nie) {
    size_t idx4 = ((size_t)blockIdx.x * 256 + threadIdx.x) * 4;
    if (idx4 < nue) {
        float4 v = *(const float4*)(u + idx4);
        ub[idx4] = (__bf16)v.x; ub[idx4+1] = (__bf16)v.y; ub[idx4+2] = (__bf16)v.z; ub[idx4+3] = (__bf16)v.w;
    } else if (idx4 < nue + nie) {
        size_t j = idx4 - nue;
        float4 v = *(const float4*)(i + j);
        ib[j] = (__bf16)v.x; ib[j+1] = (__bf16)v.y; ib[j+2] = (__bf16)v.z; ib[j+3] = (__bf16)v.w;
    }
}

// ---------------- combined-matrix prep ----------------
__global__ __launch_bounds__(128) void prep_mats(const float* __restrict__ W1, const float* __restrict__ W2,
                                                 const float* __restrict__ W3, const float* __restrict__ W4,
                                                 const float* __restrict__ pV, const float* __restrict__ pK,
                                                 __bf16* __restrict__ M2t, __bf16* __restrict__ M3t,
                                                 __bf16* __restrict__ M4t,
                                                 __bf16* __restrict__ pVW2, __bf16* __restrict__ pKW1,
                                                 int umax, int imax) {
    __shared__ float sh[256];
    int b = blockIdx.x, t = threadIdx.x;
    if (b < 128) {
        sh[t] = W1[t * 128 + b];
        __syncthreads();
        float m2 = 0.f, m3 = 0.f, m4 = 0.f;
        for (int k = 0; k < 128; k++) {
            float w = sh[k];
            m2 = fmaf(w, W2[k * 128 + t], m2);
            m3 = fmaf(w, W3[k * 128 + t], m3);
            m4 = fmaf(w, W4[k * 128 + t], m4);
        }
        M2t[b * 128 + t] = (__bf16)(m2 * INV_SQRT_D);
        M3t[b * 128 + t] = (__bf16)(m3 * INV_SQRT_D);
        M4t[b * 128 + t] = (__bf16)(m4 * INV_SQRT_D);
    } else {
        int r = b - 128;
        if (r < umax) sh[t] = pV[r * 128 + t];
        if (r < imax) sh[128 + t] = pK[r * 128 + t];
        __syncthreads();
        float q = 0.f, qk = 0.f;
        for (int a = 0; a < 128; a++) {
            if (r < umax) q  = fmaf(sh[a], W2[a * 128 + t], q);
            if (r < imax) qk = fmaf(sh[128 + a], W1[a * 128 + t], qk);
        }
        if (r < umax) pVW2[r * 128 + t] = (__bf16)(q * INV_SQRT_D);
        if (r < imax) pKW1[r * 128 + t] = (__bf16)(qk * INV_SQRT_D);
    }
}

// ---------------- user transformed vectors ----------------
__global__ __launch_bounds__(256) void user_vecs(const float* __restrict__ u_emb,
                                                 const float* __restrict__ lit_tab, const int* __restrict__ g_li,
                                                 const float* __restrict__ lut_tab, const int* __restrict__ g_lu,
                                                 const __bf16* __restrict__ M2t, const __bf16* __restrict__ M3t,
                                                 const __bf16* __restrict__ M4t,
                                                 __bf16* __restrict__ um_t, __bf16* __restrict__ li_t,
                                                 __bf16* __restrict__ lu_t, int rows) {
    int lane = threadIdx.x & 63;
    int wave = threadIdx.x >> 6;
    int row0 = blockIdx.x * 64 + wave * 16;
    if (row0 >= rows) return;
    int l16 = lane & 15, kh = lane >> 4;
    int ar = row0 + l16;
    int arc = ar < rows ? ar : rows - 1;
    const float* rA = u_emb + (size_t)arc * D_;
    const float* rB = lit_tab + (size_t)g_li[arc] * D_;
    const float* rC = lut_tab + (size_t)g_lu[arc] * D_;

    f32x4 aA[8] = {}, aB[8] = {}, aC[8] = {};
#pragma unroll
    for (int k0 = 0; k0 < D_; k0 += 32) {
        int kk = k0 + kh * 8;
        float4 a0 = *(const float4*)(rA + kk), a1 = *(const float4*)(rA + kk + 4);
        float4 b0 = *(const float4*)(rB + kk), b1 = *(const float4*)(rB + kk + 4);
        float4 c0 = *(const float4*)(rC + kk), c1 = *(const float4*)(rC + kk + 4);
        bf16x8 fA, fB, fC;
        fA[0]=(__bf16)a0.x; fA[1]=(__bf16)a0.y; fA[2]=(__bf16)a0.z; fA[3]=(__bf16)a0.w;
        fA[4]=(__bf16)a1.x; fA[5]=(__bf16)a1.y; fA[6]=(__bf16)a1.z; fA[7]=(__bf16)a1.w;
        fB[0]=(__bf16)b0.x; fB[1]=(__bf16)b0.y; fB[2]=(__bf16)b0.z; fB[3]=(__bf16)b0.w;
        fB[4]=(__bf16)b1.x; fB[5]=(__bf16)b1.y; fB[6]=(__bf16)b1.z; fB[7]=(__bf16)b1.w;
        fC[0]=(__bf16)c0.x; fC[1]=(__bf16)c0.y; fC[2]=(__bf16)c0.z; fC[3]=(__bf16)c0.w;
        fC[4]=(__bf16)c1.x; fC[5]=(__bf16)c1.y; fC[6]=(__bf16)c1.z; fC[7]=(__bf16)c1.w;
#pragma unroll
        for (int cb = 0; cb < 8; cb++) {
            bf16x8 w2 = *(const bf16x8*)(M2t + (size_t)(cb * 16 + l16) * D_ + kk);
            aA[cb] = __builtin_amdgcn_mfma_f32_16x16x32_bf16(fA, w2, aA[cb], 0, 0, 0);
            bf16x8 w3 = *(const bf16x8*)(M3t + (size_t)(cb * 16 + l16) * D_ + kk);
            aB[cb] = __builtin_amdgcn_mfma_f32_16x16x32_bf16(fB, w3, aB[cb], 0, 0, 0);
            bf16x8 w4 = *(const bf16x8*)(M4t + (size_t)(cb * 16 + l16) * D_ + kk);
            aC[cb] = __builtin_amdgcn_mfma_f32_16x16x32_bf16(fC, w4, aC[cb], 0, 0, 0);
        }
    }
#pragma unroll
    for (int cb = 0; cb < 8; cb++) {
#pragma unroll
        for (int j = 0; j < 4; j++) {
            int r = row0 + kh * 4 + j;
            if (r < rows) {
                um_t[(size_t)r * D_ + cb * 16 + l16] = (__bf16)aA[cb][j];
                li_t[(size_t)r * D_ + cb * 16 + l16] = (__bf16)aB[cb][j];
                lu_t[(size_t)r * D_ + cb * 16 + l16] = (__bf16)aC[cb][j];
            }
        }
    }
}

// ---------------- merged positional-dot GEMMs: Y(rows x ncols bf16) = Xb @ P^T ----------------
struct PvkA { const __bf16* X; const __bf16* P; __bf16* Y; int rows; int ncols; };
struct Pvk2 { PvkA a[2]; };
__global__ __launch_bounds__(256) void gemm_pvk2(Pvk2 p) {
    PvkA q = p.a[blockIdx.y];
    int lane = threadIdx.x & 63;
    int wave = threadIdx.x >> 6;
    int row0 = blockIdx.x * 64 + wave * 16;
    if (row0 >= q.rows) return;
    int l16 = lane & 15, kh = lane >> 4;
    int ar = row0 + l16;
    int arc = ar < q.rows ? ar : q.rows - 1;
    const __bf16* arow = q.X + (size_t)arc * D_;

    f32x4 acc[4] = {};
#pragma unroll
    for (int k0 = 0; k0 < D_; k0 += 32) {
        int kk = k0 + kh * 8;
        bf16x8 af = *(const bf16x8*)(arow + kk);
#pragma unroll
        for (int cb = 0; cb < 4; cb++) {
            int br = cb * 16 + l16;
            if (br >= q.ncols) br = q.ncols - 1;
            bf16x8 bf = *(const bf16x8*)(q.P + (size_t)br * D_ + kk);
            acc[cb] = __builtin_amdgcn_mfma_f32_16x16x32_bf16(af, bf, acc[cb], 0, 0, 0);
        }
    }
#pragma unroll
    for (int cb = 0; cb < 4; cb++) {
        int col = cb * 16 + l16;
        if (col >= q.ncols) continue;
#pragma unroll
        for (int j = 0; j < 4; j++) {
            int r = row0 + kh * 4 + j;
            if (r < q.rows) q.Y[(size_t)r * q.ncols + col] = (__bf16)acc[cb][j];
        }
    }
}

// ---------------- CSR build ----------------
__global__ __launch_bounds__(256) void hist2(const int* __restrict__ eu, const int* __restrict__ ei,
                                             int* __restrict__ cnt_all, int nu, int E) {
    int e = blockIdx.x * 256 + threadIdx.x;
    if (e < E) {
        atomicAdd(&cnt_all[eu[e]], 1);
        atomicAdd(&cnt_all[nu + ei[e]], 1);
    }
}

__global__ __launch_bounds__(256) void scan_phaseA(const int* __restrict__ cnt, int* __restrict__ part, int n) {
    __shared__ int wsum[4];
    int t = threadIdx.x, lane = t & 63, w = t >> 6;
    int i0 = blockIdx.x * SCAN_TILE + t * SCAN_CH;
    int tot = 0;
#pragma unroll
    for (int j = 0; j < SCAN_CH; j++) tot += (i0 + j < n) ? cnt[i0 + j] : 0;
#pragma unroll
    for (int d = 32; d; d >>= 1) tot += __shfl_xor(tot, d);
    if (lane == 0) wsum[w] = tot;
    __syncthreads();
    if (t == 0) part[blockIdx.x] = wsum[0] + wsum[1] + wsum[2] + wsum[3];
}

__global__ __launch_bounds__(1024) void scan_phaseB(int* __restrict__ part, int nb,
                                                    int* __restrict__ off, int n) {
    __shared__ int wsum[16];
    int t = threadIdx.x, lane = t & 63, w = t >> 6;
    int v = (t < nb) ? part[t] : 0;
    int x = v;
#pragma unroll
    for (int d = 1; d < 64; d <<= 1) {
        int y = __shfl_up(x, d);
        if (lane >= d) x += y;
    }
    if (lane == 63) wsum[w] = x;
    __syncthreads();
    int wbase = 0;
    for (int ww = 0; ww < w; ww++) wbase += wsum[ww];
    if (t < nb) part[t] = wbase + x - v;
    if (t == 1023) off[n] = wbase + x;
}

__global__ __launch_bounds__(256) void scan_phaseC(const int* __restrict__ cnt, const int* __restrict__ part,
                                                   int* __restrict__ off, int* __restrict__ pos, int n) {
    __shared__ int wsum[4];
    int t = threadIdx.x, lane = t & 63, w = t >> 6;
    int i0 = blockIdx.x * SCAN_TILE + t * SCAN_CH;
    int loc[SCAN_CH];
    int tot = 0;
#pragma unroll
    for (int j = 0; j < SCAN_CH; j++) {
        int v = (i0 + j < n) ? cnt[i0 + j] : 0;
        loc[j] = tot; tot += v;
    }
    int x = tot;
#pragma unroll
    for (int d = 1; d < 64; d <<= 1) {
        int y = __shfl_up(x, d);
        if (lane >= d) x += y;
    }
    if (lane == 63) wsum[w] = x;
    __syncthreads();
    int wbase = 0;
    for (int ww = 0; ww < w; ww++) wbase += wsum[ww];
    int excl = part[blockIdx.x] + wbase + x - tot;
#pragma unroll
    for (int j = 0; j < SCAN_CH; j++) {
        if (i0 + j < n) { off[i0 + j] = excl + loc[j]; pos[i0 + j] = excl + loc[j]; }
    }
}

// scatter packed: user list only. u_list[pu] = {it|rui<<18|riu<<24, item_slot}
__global__ __launch_bounds__(256) void scatter2(const int* __restrict__ eu, const int* __restrict__ ei,
                                                const int* __restrict__ rui, const int* __restrict__ riu,
                                                int* __restrict__ pos_all, int2* __restrict__ u_list,
                                                int nu, int E) {
    int e = blockIdx.x * 256 + threadIdx.x;
    if (e < E) {
        int u = eu[e], it = ei[e], r1 = rui[e], r2 = riu[e];
        int rbits = (r1 << 18) | (r2 << 24);
        int pi = atomicAdd(&pos_all[nu + it], 1) - E;
        int pu = atomicAdd(&pos_all[u], 1);
        u_list[pu] = make_int2(it | rbits, pi);
    }
}

// ---------------- user pass ----------------
// writes mb_rec[slot] = {d1, d3, u|rbits, 0} -- carries the item-side record for item_pass
__global__ __launch_bounds__(256) void user_pass(const int* __restrict__ off_all, const int2* __restrict__ u_list,
                                                 const __bf16* __restrict__ ib_emb,
                                                 const __bf16* __restrict__ um_t,
                                                 const __bf16* __restrict__ li_t,
                                                 const __bf16* __restrict__ lu_t,
                                                 const __bf16* __restrict__ pKb,
                                                 const __bf16* __restrict__ upv,
                                                 float4* __restrict__ mb_rec,
                                                 __bf16* __restrict__ A1n, __bf16* __restrict__ PKn,
                                                 __bf16* __restrict__ A2n, int nu, int umax) {
    int u = blockIdx.x * 4 + (threadIdx.x >> 6);
    if (u >= nu) return;
    int lane = threadIdx.x & 63;
    int g = lane >> 4, l16 = lane & 15;
    int off = off_all[u], n = off_all[u + 1] - off;
    if (n == 0) {
        if (lane < 16) {
            bf16x8 z = {};
            *(bf16x8*)(A1n + (size_t)u * D_ + l16 * 8) = z;
            *(bf16x8*)(PKn + (size_t)u * D_ + l16 * 8) = z;
            *(bf16x8*)(A2n + (size_t)u * D_ + l16 * 8) = z;
        }
        return;
    }
    float um8[8], li8[8], lu8[8];
    unpack8(((const bf16x8*)(um_t + (size_t)u * D_))[l16], um8);
    unpack8(((const bf16x8*)(li_t + (size_t)u * D_))[l16], li8);
    unpack8(((const bf16x8*)(lu_t + (size_t)u * D_))[l16], lu8);
    const __bf16* upv_row = upv + (size_t)u * umax;

    float s1 = 0.f, s2 = 0.f, a1[8] = {}, apk[8] = {}, a2[8] = {};
    for (int i = g; i < n; i += 8) {
        int2 ra = u_list[off + i];
        bool hb = (i + 4) < n;
        int2 rb = u_list[off + (hb ? i + 4 : i)];
        int itA = ra.x & 0x3FFFF, r1A = (ra.x >> 18) & 0x3F, r2A = (ra.x >> 24) & 0x3F;
        int itB = rb.x & 0x3FFFF, r1B = (rb.x >> 18) & 0x3F, r2B = (rb.x >> 24) & 0x3F;
        bf16x8 vieA = ((const bf16x8*)(ib_emb + (size_t)itA * D_))[l16];
        bf16x8 vpkA = ((const bf16x8*)(pKb + (size_t)r2A * D_))[l16];
        bf16x8 vieB = ((const bf16x8*)(ib_emb + (size_t)itB * D_))[l16];
        bf16x8 vpkB = ((const bf16x8*)(pKb + (size_t)r2B * D_))[l16];
        float fieA[8], fpkA[8], fieB[8], fpkB[8];
        unpack8(vieA, fieA); unpack8(vpkA, fpkA);
        unpack8(vieB, fieB); unpack8(vpkB, fpkB);
        float d1a = 0.f, d2a = 0.f, d3a = 0.f, d1b = 0.f, d2b = 0.f, d3b = 0.f;
#pragma unroll
        for (int j = 0; j < 8; j++) {
            d1a = fmaf(um8[j], fieA[j], d1a);
            d2a = fmaf(li8[j], fieA[j], d2a);
            d3a = fmaf(lu8[j], fieA[j], d3a);
            d1b = fmaf(um8[j], fieB[j], d1b);
            d2b = fmaf(li8[j], fieB[j], d2b);
            d3b = fmaf(lu8[j], fieB[j], d3b);
        }
#pragma unroll
        for (int d = 1; d < 16; d <<= 1) {
            d1a += __shfl_xor(d1a, d); d2a += __shfl_xor(d2a, d); d3a += __shfl_xor(d3a, d);
            d1b += __shfl_xor(d1b, d); d2b += __shfl_xor(d2b, d); d3b += __shfl_xor(d3b, d);
        }
        if (l16 == 0) {
            float uid_a = __int_as_float(u | (ra.x & 0x3FFC0000));
            mb_rec[ra.y] = make_float4(d1a, d3a, uid_a, 0.f);
            if (hb) {
                float uid_b = __int_as_float(u | (rb.x & 0x3FFC0000));
                mb_rec[rb.y] = make_float4(d1b, d3b, uid_b, 0.f);
            }
        }
        float w1a = __expf(d1a + bf2f(upv_row[r1A]));
        float w2a = __expf(d2a);
        float w1b = hb ? __expf(d1b + bf2f(upv_row[r1B])) : 0.f;
        float w2b = hb ? __expf(d2b) : 0.f;
        s1 += w1a + w1b; s2 += w2a + w2b;
#pragma unroll
        for (int j = 0; j < 8; j++) {
            a1[j]  = fmaf(w1a, fieA[j], fmaf(w1b, fieB[j], a1[j]));
            apk[j] = fmaf(w1a, fpkA[j], fmaf(w1b, fpkB[j], apk[j]));
            a2[j]  = fmaf(w2a, fieA[j], fmaf(w2b, fieB[j], a2[j]));
        }
    }
#pragma unroll
    for (int d = 16; d < 64; d <<= 1) {
        s1 += __shfl_xor(s1, d); s2 += __shfl_xor(s2, d);
#pragma unroll
        for (int j = 0; j < 8; j++) {
            a1[j]  += __shfl_xor(a1[j], d);
            apk[j] += __shfl_xor(apk[j], d);
            a2[j]  += __shfl_xor(a2[j], d);
        }
    }
    if (lane < 16) {
        float inv1 = 1.f / s1, inv2 = 1.f / s2;
        *(bf16x8*)(A1n + (size_t)u * D_ + l16 * 8) = pack8(a1, inv1);
        *(bf16x8*)(PKn + (size_t)u * D_ + l16 * 8) = pack8(apk, inv1);
        *(bf16x8*)(A2n + (size_t)u * D_ + l16 * 8) = pack8(a2, inv2);
    }
}

// ---------------- item pass: single coalesced record stream ----------------
__global__ __launch_bounds__(256) void item_pass(const int* __restrict__ off_all,
                                                 const __bf16* __restrict__ ub_emb,
                                                 const __bf16* __restrict__ pVb,
                                                 const __bf16* __restrict__ ipk,
                                                 const float4* __restrict__ mb_rec,
                                                 __bf16* __restrict__ B1n, __bf16* __restrict__ PVn,
                                                 __bf16* __restrict__ B2n, int nu, int ni, int imax, int E) {
    int it = blockIdx.x * 4 + (threadIdx.x >> 6);
    if (it >= ni) return;
    int lane = threadIdx.x & 63;
    int g = lane >> 4, l16 = lane & 15;
    int ioff = off_all[nu + it] - E, n = off_all[nu + it + 1] - E - ioff;
    if (n == 0) {
        if (lane < 16) {
            bf16x8 z = {};
            *(bf16x8*)(B1n + (size_t)it * D_ + l16 * 8) = z;
            *(bf16x8*)(PVn + (size_t)it * D_ + l16 * 8) = z;
            *(bf16x8*)(B2n + (size_t)it * D_ + l16 * 8) = z;
        }
        return;
    }
    const __bf16* ipk_row = ipk + (size_t)it * imax;

    float s1 = 0.f, s2 = 0.f, b1[8] = {}, bpv[8] = {}, b2[8] = {};
    for (int i = g; i < n; i += 8) {
        float4 ra = mb_rec[ioff + i];
        bool hb = (i + 4) < n;
        float4 rb = mb_rec[ioff + (hb ? i + 4 : i)];
        int pa = __float_as_int(ra.z), pb = __float_as_int(rb.z);
        int uA = pa & 0x3FFFF, r1A = (pa >> 18) & 0x3F, r2A = (pa >> 24) & 0x3F;
        int uB = pb & 0x3FFFF, r1B = (pb >> 18) & 0x3F, r2B = (pb >> 24) & 0x3F;
        bf16x8 vueA = ((const bf16x8*)(ub_emb + (size_t)uA * D_))[l16];
        bf16x8 vpvA = ((const bf16x8*)(pVb + (size_t)r1A * D_))[l16];
        bf16x8 vueB = ((const bf16x8*)(ub_emb + (size_t)uB * D_))[l16];
        bf16x8 vpvB = ((const bf16x8*)(pVb + (size_t)r1B * D_))[l16];
        float fueA[8], fpvA[8], fueB[8], fpvB[8];
        unpack8(vueA, fueA); unpack8(vpvA, fpvA);
        unpack8(vueB, fueB); unpack8(vpvB, fpvB);
        float w1a = __expf(ra.x + bf2f(ipk_row[r2A]));
        float w2a = __expf(ra.y);
        float w1b = hb ? __expf(rb.x + bf2f(ipk_row[r2B])) : 0.f;
        float w2b = hb ? __expf(rb.y) : 0.f;
        s1 += w1a + w1b; s2 += w2a + w2b;
#pragma unroll
        for (int j = 0; j < 8; j++) {
            b1[j]  = fmaf(w1a, fueA[j], fmaf(w1b, fueB[j], b1[j]));
            bpv[j] = fmaf(w1a, fpvA[j], fmaf(w1b, fpvB[j], bpv[j]));
            b2[j]  = fmaf(w2a, fueA[j], fmaf(w2b, fueB[j], b2[j]));
        }
    }
#pragma unroll
    for (int d = 16; d < 64; d <<= 1) {
        s1 += __shfl_xor(s1, d); s2 += __shfl_xor(s2, d);
#pragma unroll
        for (int j = 0; j < 8; j++) {
            b1[j]  += __shfl_xor(b1[j], d);
            bpv[j] += __shfl_xor(bpv[j], d);
            b2[j]  += __shfl_xor(b2[j], d);
        }
    }
    if (lane < 16) {
        float inv1 = 1.f / s1, inv2 = 1.f / s2;
        *(bf16x8*)(B1n + (size_t)it * D_ + l16 * 8) = pack8(b1, inv1);
        *(bf16x8*)(PVn + (size_t)it * D_ + l16 * 8) = pack8(bpv, inv1);
        *(bf16x8*)(B2n + (size_t)it * D_ + l16 * 8) = pack8(b2, inv2);
    }
}

// ---------------- finish GEMM (4 configs via blockIdx.y), swapped-operand direct-store epilogue ----------------
struct FinArgs { const __bf16* A; const __bf16* W; const __bf16* side; const int* offseg; float* out; int rows; };
struct Fin4 { FinArgs f[4]; };
__global__ __launch_bounds__(256) void finish4(Fin4 fa) {
    FinArgs q = fa.f[blockIdx.y];
    if (blockIdx.x * 256 >= (unsigned)q.rows) return;
    __shared__ __bf16 sW[128][136];
    int t = threadIdx.x;
#pragma unroll
    for (int it = 0; it < 8; it++) {
        int slot = it * 256 + t;
        int r = slot >> 4, c16 = (slot & 15) * 8;
        bf16x8 v = *(const bf16x8*)(q.W + (size_t)r * D_ + c16);
        *(bf16x8*)(&sW[r][c16]) = v;
    }
    __syncthreads();
    int lane = t & 63, wave = t >> 6;
    int l16 = lane & 15, kh = lane >> 4;

    for (int tt = 0; tt < 4; tt++) {
        int rowblk = blockIdx.x * 256 + (tt * 4 + wave) * 16;
        if (rowblk >= q.rows) break;
        int ar = rowblk + l16;
        bool rok = ar < q.rows;
        int arc = rok ? ar : q.rows - 1;
        const __bf16* rA = q.A + (size_t)arc * D_;
        bf16x8 b0 = *(const bf16x8*)(rA + kh * 8);
        bf16x8 b1 = *(const bf16x8*)(rA + 32 + kh * 8);
        bf16x8 b2 = *(const bf16x8*)(rA + 64 + kh * 8);
        bf16x8 b3 = *(const bf16x8*)(rA + 96 + kh * 8);
        float addv = 0.f;
        if (!q.side && rok) addv = (q.offseg[ar + 1] - q.offseg[ar]) > 0 ? 1.f : 0.f;
#pragma unroll
        for (int cc = 0; cc < 8; cc++) {
            int wr = cc * 16 + l16;
            f32x4 acc = {};
            acc = __builtin_amdgcn_mfma_f32_16x16x32_bf16(*(const bf16x8*)(&sW[wr][kh * 8]), b0, acc, 0, 0, 0);
            acc = __builtin_amdgcn_mfma_f32_16x16x32_bf16(*(const bf16x8*)(&sW[wr][32 + kh * 8]), b1, acc, 0, 0, 0);
            acc = __builtin_amdgcn_mfma_f32_16x16x32_bf16(*(const bf16x8*)(&sW[wr][64 + kh * 8]), b2, acc, 0, 0, 0);
            acc = __builtin_amdgcn_mfma_f32_16x16x32_bf16(*(const bf16x8*)(&sW[wr][96 + kh * 8]), b3, acc, 0, 0, 0);
            if (rok) {
                int col = cc * 16 + kh * 4;
                float4 v = make_float4(acc[0], acc[1], acc[2], acc[3]);
                if (q.side) {
                    ushort4 sv = *(const ushort4*)((const unsigned short*)q.side + (size_t)ar * D_ + col);
                    v.x += __uint_as_float((uint32_t)sv.x << 16);
                    v.y += __uint_as_float((uint32_t)sv.y << 16);
                    v.z += __uint_as_float((uint32_t)sv.z << 16);
                    v.w += __uint_as_float((uint32_t)sv.w << 16);
                } else {
                    v.x += addv; v.y += addv; v.z += addv; v.w += addv;
                }
                *(float4*)(q.out + (size_t)ar * D_ + col) = v;
            }
        }
    }
}

extern "C" void kernel_launch(void* const* d_in, const int* in_sizes, int n_in,
                              void* d_out, int out_size, void* d_ws, size_t ws_size,
                              hipStream_t stream) {
    (void)n_in; (void)out_size; (void)ws_size;
    const float* u_emb = (const float*)d_in[0];
    const float* i_emb = (const float*)d_in[1];
    const int* edge_u = (const int*)d_in[2];
    const int* edge_i = (const int*)d_in[3];
    const int* rui = (const int*)d_in[4];
    const int* riu = (const int*)d_in[5];
    const int* last_u_items = (const int*)d_in[6];
    const int* last_i_users = (const int*)d_in[7];
    const float* W1  = (const float*)d_in[8];
    const float* W2  = (const float*)d_in[9];
    const float* W1b = (const float*)d_in[10];
    const float* W2b = (const float*)d_in[11];
    const float* W3  = (const float*)d_in[12];
    const float* W4  = (const float*)d_in[13];
    const float* pV  = (const float*)d_in[14];
    const float* pK  = (const float*)d_in[15];
    const float* last_user_table = (const float*)d_in[16];
    const float* last_item_table = (const float*)d_in[17];

    const int NU = in_sizes[0] / D_;
    const int NI = in_sizes[1] / D_;
    const int E  = in_sizes[2];
    const int UMAXr = in_sizes[14] / D_;
    const int IMAXr = in_sizes[15] / D_;
    const int NSEG = NU + NI;

    size_t cur = 0;
    auto alloc = [&](size_t bytes) -> void* {
        void* p = (char*)d_ws + cur;
        cur += (bytes + 255) & ~(size_t)255;
        return p;
    };

    __bf16* Wb4   = (__bf16*)alloc(4 * 16384 * 2);
    __bf16* M2t   = (__bf16*)alloc(16384 * 2);
    __bf16* M3t   = (__bf16*)alloc(16384 * 2);
    __bf16* M4t   = (__bf16*)alloc(16384 * 2);
    __bf16* pVW2  = (__bf16*)alloc((size_t)UMAXr * D_ * 2);
    __bf16* pKW1  = (__bf16*)alloc((size_t)IMAXr * D_ * 2);
    __bf16* pVb   = (__bf16*)alloc((size_t)UMAXr * D_ * 2);
    __bf16* pKb   = (__bf16*)alloc((size_t)IMAXr * D_ * 2);
    __bf16* ub_emb = (__bf16*)alloc((size_t)NU * D_ * 2);
    __bf16* ib_emb = (__bf16*)alloc((size_t)NI * D_ * 2);
    __bf16* um_t  = (__bf16*)alloc((size_t)NU * D_ * 2);
    __bf16* li_t  = (__bf16*)alloc((size_t)NU * D_ * 2);
    __bf16* lu_t  = (__bf16*)alloc((size_t)NU * D_ * 2);
    __bf16* upv   = (__bf16*)alloc((size_t)NU * UMAXr * 2);
    __bf16* ipk   = (__bf16*)alloc((size_t)NI * IMAXr * 2);
    __bf16* A1n   = (__bf16*)alloc((size_t)NU * D_ * 2);
    __bf16* PKn   = (__bf16*)alloc((size_t)NU * D_ * 2);
    __bf16* A2n   = (__bf16*)alloc((size_t)NU * D_ * 2);
    __bf16* B1n   = (__bf16*)alloc((size_t)NI * D_ * 2);
    __bf16* PVn   = (__bf16*)alloc((size_t)NI * D_ * 2);
    __bf16* B2n   = (__bf16*)alloc((size_t)NI * D_ * 2);
    float4* mb_rec = (float4*)alloc((size_t)E * 16);
    int2* u_list  = (int2*)alloc((size_t)E * 8);
    int* cnt_all  = (int*)alloc((size_t)NSEG * 4);
    int* off_all  = (int*)alloc((size_t)(NSEG + 1) * 4);
    int* pos_all  = (int*)alloc((size_t)NSEG * 4);
    int* parts    = (int*)alloc(1024 * 4);

    float* out = (float*)d_out;
    float* hLu = out;
    float* hSu = out + (size_t)NU * D_;
    float* hLi = out + (size_t)2 * NU * D_;
    float* hSi = out + (size_t)2 * NU * D_ + (size_t)NI * D_;

    // weight casts + combined matrices
    W4p w4; w4.p[0] = W1; w4.p[1] = W2; w4.p[2] = W1b; w4.p[3] = W2b;
    int npv = UMAXr * D_, npk = IMAXr * D_;
    cvt_small<<<(4 * 16384 + npv + npk + 255) / 256, 256, 0, stream>>>(w4, pV, pK, Wb4, pVb, pKb, npv, npk);
    prep_mats<<<128 + (UMAXr > IMAXr ? UMAXr : IMAXr), 128, 0, stream>>>(W1, W2, W3, W4, pV, pK,
                                                                         M2t, M3t, M4t, pVW2, pKW1, UMAXr, IMAXr);
    size_t nue = (size_t)NU * D_, nie = (size_t)NI * D_;
    cvt_emb<<<(int)(((nue + nie) / 4 + 255) / 256), 256, 0, stream>>>(u_emb, i_emb, ub_emb, ib_emb, nue, nie);

    // CSR build
    hipMemsetAsync(cnt_all, 0, (size_t)NSEG * 4, stream);
    hist2<<<(E + 255) / 256, 256, 0, stream>>>(edge_u, edge_i, cnt_all, NU, E);
    int nb = (NSEG + SCAN_TILE - 1) / SCAN_TILE;
    scan_phaseA<<<nb, 256, 0, stream>>>(cnt_all, parts, NSEG);
    scan_phaseB<<<1, 1024, 0, stream>>>(parts, nb, off_all, NSEG);
    scan_phaseC<<<nb, 256, 0, stream>>>(cnt_all, parts, off_all, pos_all, NSEG);
    scatter2<<<(E + 255) / 256, 256, 0, stream>>>(edge_u, edge_i, rui, riu, pos_all, u_list, NU, E);

    // transformed user vectors + positional dot tables
    int gu = (NU + 63) / 64, gi = (NI + 63) / 64;
    user_vecs<<<gu, 256, 0, stream>>>(u_emb, last_item_table, last_u_items, last_user_table, last_i_users,
                                      M2t, M3t, M4t, um_t, li_t, lu_t, NU);
    Pvk2 pv2;
    pv2.a[0] = {ub_emb, pVW2, upv, NU, UMAXr};
    pv2.a[1] = {ib_emb, pKW1, ipk, NI, IMAXr};
    gemm_pvk2<<<dim3((gu > gi ? gu : gi), 2), 256, 0, stream>>>(pv2);

    // edge passes
    user_pass<<<(NU + 3) / 4, 256, 0, stream>>>(off_all, u_list, ib_emb, um_t, li_t, lu_t,
                                                pKb, upv, mb_rec, A1n, PKn, A2n, NU, UMAXr);
    item_pass<<<(NI + 3) / 4, 256, 0, stream>>>(off_all, ub_emb, pVb, ipk, mb_rec,
                                                B1n, PVn, B2n, NU, NI, IMAXr, E);

    // finish projections (one launch, 4 configs)
    int fu = (NU + 255) / 256, fi = (NI + 255) / 256;
    Fin4 fa;
    fa.f[0] = {A1n, Wb4 + 2 * 16384, PKn, nullptr, hLu, NU};
    fa.f[1] = {A2n, Wb4 + 0 * 16384, nullptr, off_all, hSu, NU};
    fa.f[2] = {B1n, Wb4 + 3 * 16384, PVn, nullptr, hLi, NI};
    fa.f[3] = {B2n, Wb4 + 1 * 16384, nullptr, off_all + NU, hSi, NI};
    finish4<<<dim3((fu > fi ? fu : fi), 4), 256, 0, stream>>>(fa);
}

// Round 15
// 466.923 us; speedup vs baseline: 1.2781x; 1.0330x over previous
//
#include <hip/hip_runtime.h>
#include <hip/hip_bf16.h>
#include <math.h>

#define D_ 128
#define INV_SQRT_D 0.08838834764831845f
#define SCAN_CH 16
#define SCAN_TILE (256 * SCAN_CH)

typedef __bf16 bf16x8 __attribute__((ext_vector_type(8)));
typedef float f32x4 __attribute__((ext_vector_type(4)));
typedef int i32x2 __attribute__((ext_vector_type(2)));

struct W4p { const float* p[4]; };

__device__ __forceinline__ void unpack8(bf16x8 v, float* f) {
    const uint32_t* u = (const uint32_t*)&v;
#pragma unroll
    for (int i = 0; i < 4; i++) {
        uint32_t w = u[i];
        f[2 * i]     = __uint_as_float(w << 16);
        f[2 * i + 1] = __uint_as_float(w & 0xffff0000u);
    }
}

__device__ __forceinline__ bf16x8 pack8(const float* f, float s) {
    bf16x8 r;
#pragma unroll
    for (int j = 0; j < 8; j++) r[j] = (__bf16)(f[j] * s);
    return r;
}

__device__ __forceinline__ float bf2f(__bf16 v) {
    return __uint_as_float((uint32_t)(*(unsigned short*)&v) << 16);
}

// ---------------- merged prep: weight/p-table casts + emb casts + edge histogram ----------------
struct PrepArgs {
    W4p w; const float* pV; const float* pK;
    __bf16* outW; __bf16* pVb; __bf16* pKb; int npv; int npk;
    const float* u_emb; const float* i_emb; __bf16* ub; __bf16* ib;
    size_t nue; size_t nie;
    const int* eu; const int* ei; int* cnt_all; int nu; int E;
    int wb_blocks; int eb_blocks;
};
__global__ __launch_bounds__(256) void prep_all(PrepArgs a) {
    int b = blockIdx.x;
    if (b < a.wb_blocks) {
        int idx = b * 256 + threadIdx.x;
        if (idx < 4 * 16384) {
            a.outW[idx] = (__bf16)a.w.p[idx >> 14][idx & 16383];
        } else if (idx - 4 * 16384 < a.npv) {
            int j = idx - 4 * 16384;
            a.pVb[j] = (__bf16)a.pV[j];
        } else if (idx - 4 * 16384 - a.npv < a.npk) {
            int j = idx - 4 * 16384 - a.npv;
            a.pKb[j] = (__bf16)a.pK[j];
        }
    } else if (b < a.wb_blocks + a.eb_blocks) {
        size_t idx4 = ((size_t)(b - a.wb_blocks) * 256 + threadIdx.x) * 4;
        if (idx4 < a.nue) {
            float4 v = *(const float4*)(a.u_emb + idx4);
            a.ub[idx4] = (__bf16)v.x; a.ub[idx4+1] = (__bf16)v.y; a.ub[idx4+2] = (__bf16)v.z; a.ub[idx4+3] = (__bf16)v.w;
        } else if (idx4 < a.nue + a.nie) {
            size_t j = idx4 - a.nue;
            float4 v = *(const float4*)(a.i_emb + j);
            a.ib[j] = (__bf16)v.x; a.ib[j+1] = (__bf16)v.y; a.ib[j+2] = (__bf16)v.z; a.ib[j+3] = (__bf16)v.w;
        }
    } else {
        int e = (b - a.wb_blocks - a.eb_blocks) * 256 + threadIdx.x;
        if (e < a.E) {
            atomicAdd(&a.cnt_all[a.eu[e]], 1);
            atomicAdd(&a.cnt_all[a.nu + a.ei[e]], 1);
        }
    }
}

// ---------------- combined-matrix prep ----------------
__global__ __launch_bounds__(128) void prep_mats(const float* __restrict__ W1, const float* __restrict__ W2,
                                                 const float* __restrict__ W3, const float* __restrict__ W4,
                                                 const float* __restrict__ pV, const float* __restrict__ pK,
                                                 __bf16* __restrict__ M2t, __bf16* __restrict__ M3t,
                                                 __bf16* __restrict__ M4t,
                                                 __bf16* __restrict__ pVW2, __bf16* __restrict__ pKW1,
                                                 int umax, int imax) {
    __shared__ float sh[256];
    int b = blockIdx.x, t = threadIdx.x;
    if (b < 128) {
        sh[t] = W1[t * 128 + b];
        __syncthreads();
        float m2 = 0.f, m3 = 0.f, m4 = 0.f;
        for (int k = 0; k < 128; k++) {
            float w = sh[k];
            m2 = fmaf(w, W2[k * 128 + t], m2);
            m3 = fmaf(w, W3[k * 128 + t], m3);
            m4 = fmaf(w, W4[k * 128 + t], m4);
        }
        M2t[b * 128 + t] = (__bf16)(m2 * INV_SQRT_D);
        M3t[b * 128 + t] = (__bf16)(m3 * INV_SQRT_D);
        M4t[b * 128 + t] = (__bf16)(m4 * INV_SQRT_D);
    } else {
        int r = b - 128;
        if (r < umax) sh[t] = pV[r * 128 + t];
        if (r < imax) sh[128 + t] = pK[r * 128 + t];
        __syncthreads();
        float q = 0.f, qk = 0.f;
        for (int a = 0; a < 128; a++) {
            if (r < umax) q  = fmaf(sh[a], W2[a * 128 + t], q);
            if (r < imax) qk = fmaf(sh[128 + a], W1[a * 128 + t], qk);
        }
        if (r < umax) pVW2[r * 128 + t] = (__bf16)(q * INV_SQRT_D);
        if (r < imax) pKW1[r * 128 + t] = (__bf16)(qk * INV_SQRT_D);
    }
}

// ---------------- merged: user transformed vectors (y=0) + positional-dot GEMMs (y=1,2) ----------------
struct PvkA { const __bf16* X; const __bf16* P; __bf16* Y; int rows; int ncols; };
struct VecsPvk {
    // user_vecs args
    const float* u_emb; const float* lit_tab; const int* g_li;
    const float* lut_tab; const int* g_lu;
    const __bf16* M2t; const __bf16* M3t; const __bf16* M4t;
    __bf16* um_t; __bf16* li_t; __bf16* lu_t; int nu;
    // pvk args
    PvkA a[2];
};
__global__ __launch_bounds__(256) void vecs_pvk(VecsPvk p) {
    int lane = threadIdx.x & 63;
    int wave = threadIdx.x >> 6;
    int row0 = blockIdx.x * 64 + wave * 16;
    int l16 = lane & 15, kh = lane >> 4;
    if (blockIdx.y == 0) {
        int rows = p.nu;
        if (row0 >= rows) return;
        int ar = row0 + l16;
        int arc = ar < rows ? ar : rows - 1;
        const float* rA = p.u_emb + (size_t)arc * D_;
        const float* rB = p.lit_tab + (size_t)p.g_li[arc] * D_;
        const float* rC = p.lut_tab + (size_t)p.g_lu[arc] * D_;

        f32x4 aA[8] = {}, aB[8] = {}, aC[8] = {};
#pragma unroll
        for (int k0 = 0; k0 < D_; k0 += 32) {
            int kk = k0 + kh * 8;
            float4 a0 = *(const float4*)(rA + kk), a1 = *(const float4*)(rA + kk + 4);
            float4 b0 = *(const float4*)(rB + kk), b1 = *(const float4*)(rB + kk + 4);
            float4 c0 = *(const float4*)(rC + kk), c1 = *(const float4*)(rC + kk + 4);
            bf16x8 fA, fB, fC;
            fA[0]=(__bf16)a0.x; fA[1]=(__bf16)a0.y; fA[2]=(__bf16)a0.z; fA[3]=(__bf16)a0.w;
            fA[4]=(__bf16)a1.x; fA[5]=(__bf16)a1.y; fA[6]=(__bf16)a1.z; fA[7]=(__bf16)a1.w;
            fB[0]=(__bf16)b0.x; fB[1]=(__bf16)b0.y; fB[2]=(__bf16)b0.z; fB[3]=(__bf16)b0.w;
            fB[4]=(__bf16)b1.x; fB[5]=(__bf16)b1.y; fB[6]=(__bf16)b1.z; fB[7]=(__bf16)b1.w;
            fC[0]=(__bf16)c0.x; fC[1]=(__bf16)c0.y; fC[2]=(__bf16)c0.z; fC[3]=(__bf16)c0.w;
            fC[4]=(__bf16)c1.x; fC[5]=(__bf16)c1.y; fC[6]=(__bf16)c1.z; fC[7]=(__bf16)c1.w;
#pragma unroll
            for (int cb = 0; cb < 8; cb++) {
                bf16x8 w2 = *(const bf16x8*)(p.M2t + (size_t)(cb * 16 + l16) * D_ + kk);
                aA[cb] = __builtin_amdgcn_mfma_f32_16x16x32_bf16(fA, w2, aA[cb], 0, 0, 0);
                bf16x8 w3 = *(const bf16x8*)(p.M3t + (size_t)(cb * 16 + l16) * D_ + kk);
                aB[cb] = __builtin_amdgcn_mfma_f32_16x16x32_bf16(fB, w3, aB[cb], 0, 0, 0);
                bf16x8 w4 = *(const bf16x8*)(p.M4t + (size_t)(cb * 16 + l16) * D_ + kk);
                aC[cb] = __builtin_amdgcn_mfma_f32_16x16x32_bf16(fC, w4, aC[cb], 0, 0, 0);
            }
        }
#pragma unroll
        for (int cb = 0; cb < 8; cb++) {
#pragma unroll
            for (int j = 0; j < 4; j++) {
                int r = row0 + kh * 4 + j;
                if (r < rows) {
                    p.um_t[(size_t)r * D_ + cb * 16 + l16] = (__bf16)aA[cb][j];
                    p.li_t[(size_t)r * D_ + cb * 16 + l16] = (__bf16)aB[cb][j];
                    p.lu_t[(size_t)r * D_ + cb * 16 + l16] = (__bf16)aC[cb][j];
                }
            }
        }
    } else {
        PvkA q = p.a[blockIdx.y - 1];
        if (row0 >= q.rows) return;
        int ar = row0 + l16;
        int arc = ar < q.rows ? ar : q.rows - 1;
        const __bf16* arow = q.X + (size_t)arc * D_;

        f32x4 acc[4] = {};
#pragma unroll
        for (int k0 = 0; k0 < D_; k0 += 32) {
            int kk = k0 + kh * 8;
            bf16x8 af = *(const bf16x8*)(arow + kk);
#pragma unroll
            for (int cb = 0; cb < 4; cb++) {
                int br = cb * 16 + l16;
                if (br >= q.ncols) br = q.ncols - 1;
                bf16x8 bf = *(const bf16x8*)(q.P + (size_t)br * D_ + kk);
                acc[cb] = __builtin_amdgcn_mfma_f32_16x16x32_bf16(af, bf, acc[cb], 0, 0, 0);
            }
        }
#pragma unroll
        for (int cb = 0; cb < 4; cb++) {
            int col = cb * 16 + l16;
            if (col >= q.ncols) continue;
#pragma unroll
            for (int j = 0; j < 4; j++) {
                int r = row0 + kh * 4 + j;
                if (r < q.rows) q.Y[(size_t)r * q.ncols + col] = (__bf16)acc[cb][j];
            }
        }
    }
}

// ---------------- scans ----------------
__global__ __launch_bounds__(256) void scan_phaseA(const int* __restrict__ cnt, int* __restrict__ part, int n) {
    __shared__ int wsum[4];
    int t = threadIdx.x, lane = t & 63, w = t >> 6;
    int i0 = blockIdx.x * SCAN_TILE + t * SCAN_CH;
    int tot = 0;
#pragma unroll
    for (int j = 0; j < SCAN_CH; j++) tot += (i0 + j < n) ? cnt[i0 + j] : 0;
#pragma unroll
    for (int d = 32; d; d >>= 1) tot += __shfl_xor(tot, d);
    if (lane == 0) wsum[w] = tot;
    __syncthreads();
    if (t == 0) part[blockIdx.x] = wsum[0] + wsum[1] + wsum[2] + wsum[3];
}

__global__ __launch_bounds__(1024) void scan_phaseB(int* __restrict__ part, int nb,
                                                    int* __restrict__ off, int n) {
    __shared__ int wsum[16];
    int t = threadIdx.x, lane = t & 63, w = t >> 6;
    int v = (t < nb) ? part[t] : 0;
    int x = v;
#pragma unroll
    for (int d = 1; d < 64; d <<= 1) {
        int y = __shfl_up(x, d);
        if (lane >= d) x += y;
    }
    if (lane == 63) wsum[w] = x;
    __syncthreads();
    int wbase = 0;
    for (int ww = 0; ww < w; ww++) wbase += wsum[ww];
    if (t < nb) part[t] = wbase + x - v;
    if (t == 1023) off[n] = wbase + x;
}

__global__ __launch_bounds__(256) void scan_phaseC(const int* __restrict__ cnt, const int* __restrict__ part,
                                                   int* __restrict__ off, int* __restrict__ pos, int n) {
    __shared__ int wsum[4];
    int t = threadIdx.x, lane = t & 63, w = t >> 6;
    int i0 = blockIdx.x * SCAN_TILE + t * SCAN_CH;
    int loc[SCAN_CH];
    int tot = 0;
#pragma unroll
    for (int j = 0; j < SCAN_CH; j++) {
        int v = (i0 + j < n) ? cnt[i0 + j] : 0;
        loc[j] = tot; tot += v;
    }
    int x = tot;
#pragma unroll
    for (int d = 1; d < 64; d <<= 1) {
        int y = __shfl_up(x, d);
        if (lane >= d) x += y;
    }
    if (lane == 63) wsum[w] = x;
    __syncthreads();
    int wbase = 0;
    for (int ww = 0; ww < w; ww++) wbase += wsum[ww];
    int excl = part[blockIdx.x] + wbase + x - tot;
#pragma unroll
    for (int j = 0; j < SCAN_CH; j++) {
        if (i0 + j < n) { off[i0 + j] = excl + loc[j]; pos[i0 + j] = excl + loc[j]; }
    }
}

// scatter packed: user list only. u_list[pu] = {it|rui<<18|riu<<24, item_slot} (nontemporal)
__global__ __launch_bounds__(256) void scatter2(const int* __restrict__ eu, const int* __restrict__ ei,
                                                const int* __restrict__ rui, const int* __restrict__ riu,
                                                int* __restrict__ pos_all, int* __restrict__ u_list,
                                                int nu, int E) {
    int e = blockIdx.x * 256 + threadIdx.x;
    if (e < E) {
        int u = eu[e], it = ei[e], r1 = rui[e], r2 = riu[e];
        int rbits = (r1 << 18) | (r2 << 24);
        int pi = atomicAdd(&pos_all[nu + it], 1) - E;
        int pu = atomicAdd(&pos_all[u], 1);
        i32x2 rec;
        rec[0] = it | rbits;
        rec[1] = pi;
        __builtin_nontemporal_store(rec, (i32x2*)(u_list + (size_t)pu * 2));
    }
}

// ---------------- user pass ----------------
__global__ __launch_bounds__(256) void user_pass(const int* __restrict__ off_all, const int* __restrict__ u_list,
                                                 const __bf16* __restrict__ ib_emb,
                                                 const __bf16* __restrict__ um_t,
                                                 const __bf16* __restrict__ li_t,
                                                 const __bf16* __restrict__ lu_t,
                                                 const __bf16* __restrict__ pKb,
                                                 const __bf16* __restrict__ upv,
                                                 float* __restrict__ mb_rec,
                                                 __bf16* __restrict__ A1n, __bf16* __restrict__ PKn,
                                                 __bf16* __restrict__ A2n, int nu, int umax) {
    int u = blockIdx.x * 4 + (threadIdx.x >> 6);
    if (u >= nu) return;
    int lane = threadIdx.x & 63;
    int g = lane >> 4, l16 = lane & 15;
    int off = off_all[u], n = off_all[u + 1] - off;
    if (n == 0) {
        if (lane < 16) {
            bf16x8 z = {};
            *(bf16x8*)(A1n + (size_t)u * D_ + l16 * 8) = z;
            *(bf16x8*)(PKn + (size_t)u * D_ + l16 * 8) = z;
            *(bf16x8*)(A2n + (size_t)u * D_ + l16 * 8) = z;
        }
        return;
    }
    float um8[8], li8[8], lu8[8];
    unpack8(((const bf16x8*)(um_t + (size_t)u * D_))[l16], um8);
    unpack8(((const bf16x8*)(li_t + (size_t)u * D_))[l16], li8);
    unpack8(((const bf16x8*)(lu_t + (size_t)u * D_))[l16], lu8);
    const __bf16* upv_row = upv + (size_t)u * umax;

    float s1 = 0.f, s2 = 0.f, a1[8] = {}, apk[8] = {}, a2[8] = {};
    for (int i = g; i < n; i += 8) {
        i32x2 ra = *(const i32x2*)(u_list + (size_t)(off + i) * 2);
        bool hb = (i + 4) < n;
        i32x2 rb = *(const i32x2*)(u_list + (size_t)(off + (hb ? i + 4 : i)) * 2);
        int itA = ra[0] & 0x3FFFF, r1A = (ra[0] >> 18) & 0x3F, r2A = (ra[0] >> 24) & 0x3F;
        int itB = rb[0] & 0x3FFFF, r1B = (rb[0] >> 18) & 0x3F, r2B = (rb[0] >> 24) & 0x3F;
        bf16x8 vieA = ((const bf16x8*)(ib_emb + (size_t)itA * D_))[l16];
        bf16x8 vpkA = ((const bf16x8*)(pKb + (size_t)r2A * D_))[l16];
        bf16x8 vieB = ((const bf16x8*)(ib_emb + (size_t)itB * D_))[l16];
        bf16x8 vpkB = ((const bf16x8*)(pKb + (size_t)r2B * D_))[l16];
        float fieA[8], fpkA[8], fieB[8], fpkB[8];
        unpack8(vieA, fieA); unpack8(vpkA, fpkA);
        unpack8(vieB, fieB); unpack8(vpkB, fpkB);
        float d1a = 0.f, d2a = 0.f, d3a = 0.f, d1b = 0.f, d2b = 0.f, d3b = 0.f;
#pragma unroll
        for (int j = 0; j < 8; j++) {
            d1a = fmaf(um8[j], fieA[j], d1a);
            d2a = fmaf(li8[j], fieA[j], d2a);
            d3a = fmaf(lu8[j], fieA[j], d3a);
            d1b = fmaf(um8[j], fieB[j], d1b);
            d2b = fmaf(li8[j], fieB[j], d2b);
            d3b = fmaf(lu8[j], fieB[j], d3b);
        }
#pragma unroll
        for (int d = 1; d < 16; d <<= 1) {
            d1a += __shfl_xor(d1a, d); d2a += __shfl_xor(d2a, d); d3a += __shfl_xor(d3a, d);
            d1b += __shfl_xor(d1b, d); d2b += __shfl_xor(d2b, d); d3b += __shfl_xor(d3b, d);
        }
        if (l16 == 0) {
            f32x4 recA;
            recA[0] = d1a; recA[1] = d3a;
            recA[2] = __int_as_float(u | (ra[0] & 0x3FFC0000)); recA[3] = 0.f;
            __builtin_nontemporal_store(recA, (f32x4*)(mb_rec + (size_t)ra[1] * 4));
            if (hb) {
                f32x4 recB;
                recB[0] = d1b; recB[1] = d3b;
                recB[2] = __int_as_float(u | (rb[0] & 0x3FFC0000)); recB[3] = 0.f;
                __builtin_nontemporal_store(recB, (f32x4*)(mb_rec + (size_t)rb[1] * 4));
            }
        }
        float w1a = __expf(d1a + bf2f(upv_row[r1A]));
        float w2a = __expf(d2a);
        float w1b = hb ? __expf(d1b + bf2f(upv_row[r1B])) : 0.f;
        float w2b = hb ? __expf(d2b) : 0.f;
        s1 += w1a + w1b; s2 += w2a + w2b;
#pragma unroll
        for (int j = 0; j < 8; j++) {
            a1[j]  = fmaf(w1a, fieA[j], fmaf(w1b, fieB[j], a1[j]));
            apk[j] = fmaf(w1a, fpkA[j], fmaf(w1b, fpkB[j], apk[j]));
            a2[j]  = fmaf(w2a, fieA[j], fmaf(w2b, fieB[j], a2[j]));
        }
    }
#pragma unroll
    for (int d = 16; d < 64; d <<= 1) {
        s1 += __shfl_xor(s1, d); s2 += __shfl_xor(s2, d);
#pragma unroll
        for (int j = 0; j < 8; j++) {
            a1[j]  += __shfl_xor(a1[j], d);
            apk[j] += __shfl_xor(apk[j], d);
            a2[j]  += __shfl_xor(a2[j], d);
        }
    }
    if (lane < 16) {
        float inv1 = 1.f / s1, inv2 = 1.f / s2;
        *(bf16x8*)(A1n + (size_t)u * D_ + l16 * 8) = pack8(a1, inv1);
        *(bf16x8*)(PKn + (size_t)u * D_ + l16 * 8) = pack8(apk, inv1);
        *(bf16x8*)(A2n + (size_t)u * D_ + l16 * 8) = pack8(a2, inv2);
    }
}

// ---------------- item pass: single coalesced record stream ----------------
__global__ __launch_bounds__(256) void item_pass(const int* __restrict__ off_all,
                                                 const __bf16* __restrict__ ub_emb,
                                                 const __bf16* __restrict__ pVb,
                                                 const __bf16* __restrict__ ipk,
                                                 const float4* __restrict__ mb_rec,
                                                 __bf16* __restrict__ B1n, __bf16* __restrict__ PVn,
                                                 __bf16* __restrict__ B2n, int nu, int ni, int imax, int E) {
    int it = blockIdx.x * 4 + (threadIdx.x >> 6);
    if (it >= ni) return;
    int lane = threadIdx.x & 63;
    int g = lane >> 4, l16 = lane & 15;
    int ioff = off_all[nu + it] - E, n = off_all[nu + it + 1] - E - ioff;
    if (n == 0) {
        if (lane < 16) {
            bf16x8 z = {};
            *(bf16x8*)(B1n + (size_t)it * D_ + l16 * 8) = z;
            *(bf16x8*)(PVn + (size_t)it * D_ + l16 * 8) = z;
            *(bf16x8*)(B2n + (size_t)it * D_ + l16 * 8) = z;
        }
        return;
    }
    const __bf16* ipk_row = ipk + (size_t)it * imax;

    float s1 = 0.f, s2 = 0.f, b1[8] = {}, bpv[8] = {}, b2[8] = {};
    for (int i = g; i < n; i += 8) {
        float4 ra = mb_rec[ioff + i];
        bool hb = (i + 4) < n;
        float4 rb = mb_rec[ioff + (hb ? i + 4 : i)];
        int pa = __float_as_int(ra.z), pb = __float_as_int(rb.z);
        int uA = pa & 0x3FFFF, r1A = (pa >> 18) & 0x3F, r2A = (pa >> 24) & 0x3F;
        int uB = pb & 0x3FFFF, r1B = (pb >> 18) & 0x3F, r2B = (pb >> 24) & 0x3F;
        bf16x8 vueA = ((const bf16x8*)(ub_emb + (size_t)uA * D_))[l16];
        bf16x8 vpvA = ((const bf16x8*)(pVb + (size_t)r1A * D_))[l16];
        bf16x8 vueB = ((const bf16x8*)(ub_emb + (size_t)uB * D_))[l16];
        bf16x8 vpvB = ((const bf16x8*)(pVb + (size_t)r1B * D_))[l16];
        float fueA[8], fpvA[8], fueB[8], fpvB[8];
        unpack8(vueA, fueA); unpack8(vpvA, fpvA);
        unpack8(vueB, fueB); unpack8(vpvB, fpvB);
        float w1a = __expf(ra.x + bf2f(ipk_row[r2A]));
        float w2a = __expf(ra.y);
        float w1b = hb ? __expf(rb.x + bf2f(ipk_row[r2B])) : 0.f;
        float w2b = hb ? __expf(rb.y) : 0.f;
        s1 += w1a + w1b; s2 += w2a + w2b;
#pragma unroll
        for (int j = 0; j < 8; j++) {
            b1[j]  = fmaf(w1a, fueA[j], fmaf(w1b, fueB[j], b1[j]));
            bpv[j] = fmaf(w1a, fpvA[j], fmaf(w1b, fpvB[j], bpv[j]));
            b2[j]  = fmaf(w2a, fueA[j], fmaf(w2b, fueB[j], b2[j]));
        }
    }
#pragma unroll
    for (int d = 16; d < 64; d <<= 1) {
        s1 += __shfl_xor(s1, d); s2 += __shfl_xor(s2, d);
#pragma unroll
        for (int j = 0; j < 8; j++) {
            b1[j]  += __shfl_xor(b1[j], d);
            bpv[j] += __shfl_xor(bpv[j], d);
            b2[j]  += __shfl_xor(b2[j], d);
        }
    }
    if (lane < 16) {
        float inv1 = 1.f / s1, inv2 = 1.f / s2;
        *(bf16x8*)(B1n + (size_t)it * D_ + l16 * 8) = pack8(b1, inv1);
        *(bf16x8*)(PVn + (size_t)it * D_ + l16 * 8) = pack8(bpv, inv1);
        *(bf16x8*)(B2n + (size_t)it * D_ + l16 * 8) = pack8(b2, inv2);
    }
}

// ---------------- finish GEMM (4 configs via blockIdx.y), swapped-operand direct-store epilogue ----------------
struct FinArgs { const __bf16* A; const __bf16* W; const __bf16* side; const int* offseg; float* out; int rows; };
struct Fin4 { FinArgs f[4]; };
__global__ __launch_bounds__(256) void finish4(Fin4 fa) {
    FinArgs q = fa.f[blockIdx.y];
    if (blockIdx.x * 256 >= (unsigned)q.rows) return;
    __shared__ __bf16 sW[128][136];
    int t = threadIdx.x;
#pragma unroll
    for (int it = 0; it < 8; it++) {
        int slot = it * 256 + t;
        int r = slot >> 4, c16 = (slot & 15) * 8;
        bf16x8 v = *(const bf16x8*)(q.W + (size_t)r * D_ + c16);
        *(bf16x8*)(&sW[r][c16]) = v;
    }
    __syncthreads();
    int lane = t & 63, wave = t >> 6;
    int l16 = lane & 15, kh = lane >> 4;

    for (int tt = 0; tt < 4; tt++) {
        int rowblk = blockIdx.x * 256 + (tt * 4 + wave) * 16;
        if (rowblk >= q.rows) break;
        int ar = rowblk + l16;
        bool rok = ar < q.rows;
        int arc = rok ? ar : q.rows - 1;
        const __bf16* rA = q.A + (size_t)arc * D_;
        bf16x8 b0 = *(const bf16x8*)(rA + kh * 8);
        bf16x8 b1 = *(const bf16x8*)(rA + 32 + kh * 8);
        bf16x8 b2 = *(const bf16x8*)(rA + 64 + kh * 8);
        bf16x8 b3 = *(const bf16x8*)(rA + 96 + kh * 8);
        float addv = 0.f;
        if (!q.side && rok) addv = (q.offseg[ar + 1] - q.offseg[ar]) > 0 ? 1.f : 0.f;
#pragma unroll
        for (int cc = 0; cc < 8; cc++) {
            int wr = cc * 16 + l16;
            f32x4 acc = {};
            acc = __builtin_amdgcn_mfma_f32_16x16x32_bf16(*(const bf16x8*)(&sW[wr][kh * 8]), b0, acc, 0, 0, 0);
            acc = __builtin_amdgcn_mfma_f32_16x16x32_bf16(*(const bf16x8*)(&sW[wr][32 + kh * 8]), b1, acc, 0, 0, 0);
            acc = __builtin_amdgcn_mfma_f32_16x16x32_bf16(*(const bf16x8*)(&sW[wr][64 + kh * 8]), b2, acc, 0, 0, 0);
            acc = __builtin_amdgcn_mfma_f32_16x16x32_bf16(*(const bf16x8*)(&sW[wr][96 + kh * 8]), b3, acc, 0, 0, 0);
            if (rok) {
                int col = cc * 16 + kh * 4;
                float4 v = make_float4(acc[0], acc[1], acc[2], acc[3]);
                if (q.side) {
                    ushort4 sv = *(const ushort4*)((const unsigned short*)q.side + (size_t)ar * D_ + col);
                    v.x += __uint_as_float((uint32_t)sv.x << 16);
                    v.y += __uint_as_float((uint32_t)sv.y << 16);
                    v.z += __uint_as_float((uint32_t)sv.z << 16);
                    v.w += __uint_as_float((uint32_t)sv.w << 16);
                } else {
                    v.x += addv; v.y += addv; v.z += addv; v.w += addv;
                }
                *(float4*)(q.out + (size_t)ar * D_ + col) = v;
            }
        }
    }
}

extern "C" void kernel_launch(void* const* d_in, const int* in_sizes, int n_in,
                              void* d_out, int out_size, void* d_ws, size_t ws_size,
                              hipStream_t stream) {
    (void)n_in; (void)out_size; (void)ws_size;
    const float* u_emb = (const float*)d_in[0];
    const float* i_emb = (const float*)d_in[1];
    const int* edge_u = (const int*)d_in[2];
    const int* edge_i = (const int*)d_in[3];
    const int* rui = (const int*)d_in[4];
    const int* riu = (const int*)d_in[5];
    const int* last_u_items = (const int*)d_in[6];
    const int* last_i_users = (const int*)d_in[7];
    const float* W1  = (const float*)d_in[8];
    const float* W2  = (const float*)d_in[9];
    const float* W1b = (const float*)d_in[10];
    const float* W2b = (const float*)d_in[11];
    const float* W3  = (const float*)d_in[12];
    const float* W4  = (const float*)d_in[13];
    const float* pV  = (const float*)d_in[14];
    const float* pK  = (const float*)d_in[15];
    const float* last_user_table = (const float*)d_in[16];
    const float* last_item_table = (const float*)d_in[17];

    const int NU = in_sizes[0] / D_;
    const int NI = in_sizes[1] / D_;
    const int E  = in_sizes[2];
    const int UMAXr = in_sizes[14] / D_;
    const int IMAXr = in_sizes[15] / D_;
    const int NSEG = NU + NI;

    size_t cur = 0;
    auto alloc = [&](size_t bytes) -> void* {
        void* p = (char*)d_ws + cur;
        cur += (bytes + 255) & ~(size_t)255;
        return p;
    };

    __bf16* Wb4   = (__bf16*)alloc(4 * 16384 * 2);
    __bf16* M2t   = (__bf16*)alloc(16384 * 2);
    __bf16* M3t   = (__bf16*)alloc(16384 * 2);
    __bf16* M4t   = (__bf16*)alloc(16384 * 2);
    __bf16* pVW2  = (__bf16*)alloc((size_t)UMAXr * D_ * 2);
    __bf16* pKW1  = (__bf16*)alloc((size_t)IMAXr * D_ * 2);
    __bf16* pVb   = (__bf16*)alloc((size_t)UMAXr * D_ * 2);
    __bf16* pKb   = (__bf16*)alloc((size_t)IMAXr * D_ * 2);
    __bf16* ub_emb = (__bf16*)alloc((size_t)NU * D_ * 2);
    __bf16* ib_emb = (__bf16*)alloc((size_t)NI * D_ * 2);
    __bf16* um_t  = (__bf16*)alloc((size_t)NU * D_ * 2);
    __bf16* li_t  = (__bf16*)alloc((size_t)NU * D_ * 2);
    __bf16* lu_t  = (__bf16*)alloc((size_t)NU * D_ * 2);
    __bf16* upv   = (__bf16*)alloc((size_t)NU * UMAXr * 2);
    __bf16* ipk   = (__bf16*)alloc((size_t)NI * IMAXr * 2);
    __bf16* A1n   = (__bf16*)alloc((size_t)NU * D_ * 2);
    __bf16* PKn   = (__bf16*)alloc((size_t)NU * D_ * 2);
    __bf16* A2n   = (__bf16*)alloc((size_t)NU * D_ * 2);
    __bf16* B1n   = (__bf16*)alloc((size_t)NI * D_ * 2);
    __bf16* PVn   = (__bf16*)alloc((size_t)NI * D_ * 2);
    __bf16* B2n   = (__bf16*)alloc((size_t)NI * D_ * 2);
    float* mb_rec = (float*)alloc((size_t)E * 16);
    int* u_list   = (int*)alloc((size_t)E * 8);
    int* cnt_all  = (int*)alloc((size_t)NSEG * 4);
    int* off_all  = (int*)alloc((size_t)(NSEG + 1) * 4);
    int* pos_all  = (int*)alloc((size_t)NSEG * 4);
    int* parts    = (int*)alloc(1024 * 4);

    float* out = (float*)d_out;
    float* hLu = out;
    float* hSu = out + (size_t)NU * D_;
    float* hLi = out + (size_t)2 * NU * D_;
    float* hSi = out + (size_t)2 * NU * D_ + (size_t)NI * D_;

    // zero counters first (hist merged into prep_all)
    hipMemsetAsync(cnt_all, 0, (size_t)NSEG * 4, stream);

    // merged prep: weight/p casts + emb casts + histogram
    int npv = UMAXr * D_, npk = IMAXr * D_;
    size_t nue = (size_t)NU * D_, nie = (size_t)NI * D_;
    PrepArgs pa;
    pa.w.p[0] = W1; pa.w.p[1] = W2; pa.w.p[2] = W1b; pa.w.p[3] = W2b;
    pa.pV = pV; pa.pK = pK; pa.outW = Wb4; pa.pVb = pVb; pa.pKb = pKb; pa.npv = npv; pa.npk = npk;
    pa.u_emb = u_emb; pa.i_emb = i_emb; pa.ub = ub_emb; pa.ib = ib_emb; pa.nue = nue; pa.nie = nie;
    pa.eu = edge_u; pa.ei = edge_i; pa.cnt_all = cnt_all; pa.nu = NU; pa.E = E;
    pa.wb_blocks = (4 * 16384 + npv + npk + 255) / 256;
    pa.eb_blocks = (int)(((nue + nie) / 4 + 255) / 256);
    int hb_blocks = (E + 255) / 256;
    prep_all<<<pa.wb_blocks + pa.eb_blocks + hb_blocks, 256, 0, stream>>>(pa);

    prep_mats<<<128 + (UMAXr > IMAXr ? UMAXr : IMAXr), 128, 0, stream>>>(W1, W2, W3, W4, pV, pK,
                                                                         M2t, M3t, M4t, pVW2, pKW1, UMAXr, IMAXr);

    // CSR scan chain
    int nb = (NSEG + SCAN_TILE - 1) / SCAN_TILE;
    scan_phaseA<<<nb, 256, 0, stream>>>(cnt_all, parts, NSEG);
    scan_phaseB<<<1, 1024, 0, stream>>>(parts, nb, off_all, NSEG);
    scan_phaseC<<<nb, 256, 0, stream>>>(cnt_all, parts, off_all, pos_all, NSEG);
    scatter2<<<(E + 255) / 256, 256, 0, stream>>>(edge_u, edge_i, rui, riu, pos_all, u_list, NU, E);

    // transformed user vectors + positional dot tables (one launch)
    int gu = (NU + 63) / 64, gi = (NI + 63) / 64;
    VecsPvk vp;
    vp.u_emb = u_emb; vp.lit_tab = last_item_table; vp.g_li = last_u_items;
    vp.lut_tab = last_user_table; vp.g_lu = last_i_users;
    vp.M2t = M2t; vp.M3t = M3t; vp.M4t = M4t;
    vp.um_t = um_t; vp.li_t = li_t; vp.lu_t = lu_t; vp.nu = NU;
    vp.a[0] = {ub_emb, pVW2, upv, NU, UMAXr};
    vp.a[1] = {ib_emb, pKW1, ipk, NI, IMAXr};
    vecs_pvk<<<dim3((gu > gi ? gu : gi), 3), 256, 0, stream>>>(vp);

    // edge passes
    user_pass<<<(NU + 3) / 4, 256, 0, stream>>>(off_all, u_list, ib_emb, um_t, li_t, lu_t,
                                                pKb, upv, mb_rec, A1n, PKn, A2n, NU, UMAXr);
    item_pass<<<(NI + 3) / 4, 256, 0, stream>>>(off_all, ub_emb, pVb, ipk, (const float4*)mb_rec,
                                                B1n, PVn, B2n, NU, NI, IMAXr, E);

    // finish projections (one launch, 4 configs)
    int fu = (NU + 255) / 256, fi = (NI + 255) / 256;
    Fin4 fa;
    fa.f[0] = {A1n, Wb4 + 2 * 16384, PKn, nullptr, hLu, NU};
    fa.f[1] = {A2n, Wb4 + 0 * 16384, nullptr, off_all, hSu, NU};
    fa.f[2] = {B1n, Wb4 + 3 * 16384, PVn, nullptr, hLi, NI};
    fa.f[3] = {B2n, Wb4 + 1 * 16384, nullptr, off_all + NU, hSi, NI};
    finish4<<<dim3((fu > fi ? fu : fi), 4), 256, 0, stream>>>(fa);
}